// Round 4
// baseline (694.342 us; speedup 1.0000x reference)
//
#include <hip/hip_runtime.h>

typedef unsigned short u16;
typedef unsigned int u32;
using f32x4 = __attribute__((ext_vector_type(4))) float;
using bf16x8 = __attribute__((ext_vector_type(8))) __bf16;

constexpr int Bc = 4, Tc = 2048, Dc = 2048, Hc = 16, Gc = 4, Kc = 128;
constexpr float EPSc = 1e-6f;

__device__ __forceinline__ u16 f2bf(float f) {
    u32 u = __float_as_uint(f);
    u = (u + 0x7fffu + ((u >> 16) & 1u)) >> 16;
    return (u16)u;
}
__device__ __forceinline__ float bf2f(u16 h) {
    return __uint_as_float(((u32)h) << 16);
}

// async global->LDS, 16B per lane; LDS dest must be wave-uniform base + lane*16
__device__ __forceinline__ void async_ld16(void* lds, const void* g) {
    __builtin_amdgcn_global_load_lds(
        (const __attribute__((address_space(1))) unsigned int*)g,
        (__attribute__((address_space(3))) unsigned int*)lds, 16, 0, 0);
}

// raw barrier: waits own LDS ops, does NOT drain vmcnt (prefetch stays in flight)
__device__ __forceinline__ void sync_lgkm() {
    asm volatile("s_waitcnt lgkmcnt(0)" ::: "memory");
    __builtin_amdgcn_s_barrier();
    asm volatile("" ::: "memory");
}

__device__ __forceinline__ u32 cvt_pk_bf16(float lo, float hi) {
    u32 r;
    asm("v_cvt_pk_bf16_f32 %0, %1, %2" : "=v"(r) : "v"(lo), "v"(hi));
    return r;
}

// ---------------- fp32 -> bf16 convert ----------------
__global__ __launch_bounds__(256) void cvt_f2bf(const float* __restrict__ in,
                                                u16* __restrict__ out, int n) {
    int i = (blockIdx.x * 256 + threadIdx.x) * 4;
    if (i >= n) return;
    float4 f = *(const float4*)(in + i);
    u16 r[4] = { f2bf(f.x), f2bf(f.y), f2bf(f.z), f2bf(f.w) };
    *(uint2*)(out + i) = *(uint2*)r;
}

// ------- transpose+convert: in (rows x cols) f32 -> out (cols x rows) bf16 -------
__global__ __launch_bounds__(256) void transpose_f2bf(const float* __restrict__ in,
                                                      u16* __restrict__ out,
                                                      int rows, int cols) {
    __shared__ float tile[32][33];
    int tx = threadIdx.x & 31, ty = threadIdx.x >> 5;
    int c0 = blockIdx.x * 32, r0 = blockIdx.y * 32;
#pragma unroll
    for (int j = 0; j < 4; j++)
        tile[ty + j * 8][tx] = in[(size_t)(r0 + ty + j * 8) * cols + c0 + tx];
    __syncthreads();
#pragma unroll
    for (int j = 0; j < 4; j++)
        out[(size_t)(c0 + ty + j * 8) * rows + r0 + tx] = f2bf(tile[tx][ty + j * 8]);
}

// ---------------- positions from (sorted) segment ids ----------------
__global__ void pos_kernel(const int* __restrict__ seg, int* __restrict__ pos) {
    int idx = blockIdx.x * 256 + threadIdx.x;
    if (idx >= Bc * Tc) return;
    int b = idx / Tc, t = idx - b * Tc;
    const int* s = seg + b * Tc;
    int v = s[t];
    int lo = 0, hi = t;
    while (lo < hi) { int mid = (lo + hi) >> 1; if (s[mid] < v) lo = mid + 1; else hi = mid; }
    pos[idx] = t - lo;   // t - seg_start
}

// ---------------- bf16 GEMM (m97 structure): C(MxN) = A(MxKd) * Bt(NxKd)^T ----------------
#define GBM 128
#define GBN 128
#define GBK 32

__global__ __launch_bounds__(256) void gemm_bt(const u16* __restrict__ A,
                                               const u16* __restrict__ Bt,
                                               float* __restrict__ Cf, u16* __restrict__ Cb,
                                               int M, int N, int Kd) {
    __shared__ __align__(16) u16 lA[GBM * GBK];   // unpadded: required by global_load_lds lane order
    __shared__ __align__(16) u16 lB[GBN * GBK];
    const int tid = threadIdx.x;
    const int m0 = blockIdx.y * GBM, n0 = blockIdx.x * GBN;
    const int wave = tid >> 6, lane = tid & 63;
    const int l16 = lane & 15, quad = lane >> 4;
    const int wm = (wave & 1) * 64, wn = (wave >> 1) * 64;

    const int c0 = tid, c1 = tid + 256;
    const u16* gA0 = A + (size_t)(m0 + (c0 >> 2)) * Kd + (c0 & 3) * 8;
    const u16* gA1 = A + (size_t)(m0 + (c1 >> 2)) * Kd + (c1 & 3) * 8;
    const u16* gB0 = Bt + (size_t)(n0 + (c0 >> 2)) * Kd + (c0 & 3) * 8;
    const u16* gB1 = Bt + (size_t)(n0 + (c1 >> 2)) * Kd + (c1 & 3) * 8;
    u16* sA0 = &lA[c0 * 8];
    u16* sA1 = &lA[c1 * 8];
    u16* sB0 = &lB[c0 * 8];
    u16* sB1 = &lB[c1 * 8];

    const f32x4 fz = {0.f, 0.f, 0.f, 0.f};
    f32x4 acc[4][4];
#pragma unroll
    for (int i = 0; i < 4; i++)
#pragma unroll
        for (int j = 0; j < 4; j++) acc[i][j] = fz;

    for (int k0 = 0; k0 < Kd; k0 += GBK) {
        __syncthreads();
        async_ld16(sA0, gA0 + k0);
        async_ld16(sA1, gA1 + k0);
        async_ld16(sB0, gB0 + k0);
        async_ld16(sB1, gB1 + k0);
        __syncthreads();
        bf16x8 af[4], bg[4];
#pragma unroll
        for (int i = 0; i < 4; i++) {
            af[i] = *(const bf16x8*)&lA[(wm + i * 16 + l16) * GBK + quad * 8];
            bg[i] = *(const bf16x8*)&lB[(wn + i * 16 + l16) * GBK + quad * 8];
        }
#pragma unroll
        for (int mi = 0; mi < 4; mi++)
#pragma unroll
            for (int ni = 0; ni < 4; ni++)
                acc[mi][ni] = __builtin_amdgcn_mfma_f32_16x16x32_bf16(af[mi], bg[ni], acc[mi][ni], 0, 0, 0);
    }

#pragma unroll
    for (int mi = 0; mi < 4; mi++)
#pragma unroll
        for (int ni = 0; ni < 4; ni++)
#pragma unroll
            for (int r = 0; r < 4; r++) {
                int row = m0 + wm + mi * 16 + quad * 4 + r;   // C/D: row=quad*4+reg
                int col = n0 + wn + ni * 16 + l16;            //      col=lane&15
                float v = acc[mi][ni][r];
                if (Cf) Cf[(size_t)row * N + col] = v;
                else    Cb[(size_t)row * N + col] = f2bf(v);
            }
}

// ------- merged QKV GEMM: N=3072 over [wqT;wkT;wvT]; Q->qb, K->kb, V->Vt[b][g][d][t] -------
__global__ __launch_bounds__(256) void gemm_qkv(const u16* __restrict__ A,
                                                const u16* __restrict__ Bt,
                                                u16* __restrict__ qb, u16* __restrict__ kb,
                                                u16* __restrict__ vtb, int M, int Kd) {
    __shared__ __align__(16) u16 lA[GBM * GBK];
    __shared__ __align__(16) u16 lB[GBN * GBK];
    const int tid = threadIdx.x;
    const int m0 = blockIdx.y * GBM, n0 = blockIdx.x * GBN;
    const int wave = tid >> 6, lane = tid & 63;
    const int l16 = lane & 15, quad = lane >> 4;
    const int wm = (wave & 1) * 64, wn = (wave >> 1) * 64;

    const int c0 = tid, c1 = tid + 256;
    const u16* gA0 = A + (size_t)(m0 + (c0 >> 2)) * Kd + (c0 & 3) * 8;
    const u16* gA1 = A + (size_t)(m0 + (c1 >> 2)) * Kd + (c1 & 3) * 8;
    const u16* gB0 = Bt + (size_t)(n0 + (c0 >> 2)) * Kd + (c0 & 3) * 8;
    const u16* gB1 = Bt + (size_t)(n0 + (c1 >> 2)) * Kd + (c1 & 3) * 8;
    u16* sA0 = &lA[c0 * 8];
    u16* sA1 = &lA[c1 * 8];
    u16* sB0 = &lB[c0 * 8];
    u16* sB1 = &lB[c1 * 8];

    const f32x4 fz = {0.f, 0.f, 0.f, 0.f};
    f32x4 acc[4][4];
#pragma unroll
    for (int i = 0; i < 4; i++)
#pragma unroll
        for (int j = 0; j < 4; j++) acc[i][j] = fz;

    for (int k0 = 0; k0 < Kd; k0 += GBK) {
        __syncthreads();
        async_ld16(sA0, gA0 + k0);
        async_ld16(sA1, gA1 + k0);
        async_ld16(sB0, gB0 + k0);
        async_ld16(sB1, gB1 + k0);
        __syncthreads();
        bf16x8 af[4], bg[4];
#pragma unroll
        for (int i = 0; i < 4; i++) {
            af[i] = *(const bf16x8*)&lA[(wm + i * 16 + l16) * GBK + quad * 8];
            bg[i] = *(const bf16x8*)&lB[(wn + i * 16 + l16) * GBK + quad * 8];
        }
#pragma unroll
        for (int mi = 0; mi < 4; mi++)
#pragma unroll
            for (int ni = 0; ni < 4; ni++)
                acc[mi][ni] = __builtin_amdgcn_mfma_f32_16x16x32_bf16(af[mi], bg[ni], acc[mi][ni], 0, 0, 0);
    }

    const int nbase = n0 + wn;   // 64-aligned; regions split at 2048 / 2560 (both 64-aligned)
    if (nbase < 2048) {
        // Q: qb[(b,t)][(h,d)] = [M][2048]
#pragma unroll
        for (int mi = 0; mi < 4; mi++)
#pragma unroll
            for (int ni = 0; ni < 4; ni++)
#pragma unroll
                for (int r = 0; r < 4; r++) {
                    int row = m0 + wm + mi * 16 + quad * 4 + r;
                    int col = nbase + ni * 16 + l16;
                    qb[(size_t)row * 2048 + col] = f2bf(acc[mi][ni][r]);
                }
    } else if (nbase < 2560) {
        // K: kb[(b,t)][(g,d)] = [M][512]
#pragma unroll
        for (int mi = 0; mi < 4; mi++)
#pragma unroll
            for (int ni = 0; ni < 4; ni++)
#pragma unroll
                for (int r = 0; r < 4; r++) {
                    int row = m0 + wm + mi * 16 + quad * 4 + r;
                    int col = nbase + ni * 16 + l16 - 2048;
                    kb[(size_t)row * 512 + col] = f2bf(acc[mi][ni][r]);
                }
    } else {
        // V: transposed Vt[b][g][d][t]; 4 consecutive t per lane -> 8B store
#pragma unroll
        for (int mi = 0; mi < 4; mi++)
#pragma unroll
            for (int ni = 0; ni < 4; ni++) {
                int nv = nbase + ni * 16 + l16 - 2560;
                int g = nv >> 7, d = nv & 127;
                int m = m0 + wm + mi * 16 + quad * 4;
                int b = m >> 11, t = m & 2047;
                u16 r4[4];
#pragma unroll
                for (int r = 0; r < 4; r++) r4[r] = f2bf(acc[mi][ni][r]);
                *(uint2*)&vtb[(((size_t)b * Gc + g) * Kc + d) * Tc + t] = *(uint2*)r4;
            }
    }
}

// ---------------- fused RMSNorm + RoPE, vectorized (u32 = 2 bf16 per lane) ----------------
// lane l holds dims {2l, 2l+1}; rope partner (d <-> d+64) exchanged via shfl_xor(32).
__global__ __launch_bounds__(256) void rms_rope(u16* __restrict__ X,
                                                const float* __restrict__ sc,
                                                const int* __restrict__ pos, int NH,
                                                float smul) {
    int row = blockIdx.x * 4 + (threadIdx.x >> 6);   // one wave per (b,t,head) row
    int lane = threadIdx.x & 63;
    int bt = row / NH;
    u16* xp = X + (size_t)row * Kc;
    u32 w = *(const u32*)(xp + 2 * lane);
    float a0 = bf2f((u16)(w & 0xffffu)), a1 = bf2f((u16)(w >> 16));
    float ss = a0 * a0 + a1 * a1;
#pragma unroll
    for (int m = 1; m < 64; m <<= 1) ss += __shfl_xor(ss, m, 64);
    float rn = rsqrtf(ss * (1.f / 128.f) + EPSc) * smul;   // fold attn scale into q
    float2 scv = *(const float2*)(sc + 2 * lane);
    float y0 = a0 * rn * scv.x, y1 = a1 * rn * scv.y;
    float p0 = __shfl_xor(y0, 32, 64);   // rope partner's scaled value
    float p1 = __shfl_xor(y1, 32, 64);
    int j0 = (2 * lane) & 63;            // freq index (same for lane and partner)
    float pf = (float)pos[bt];
    const float nl2 = -0.20762050593046015f;   // -log2(10000)/64
    float inv0 = exp2f((float)j0 * nl2);
    float inv1 = exp2f((float)(j0 + 1) * nl2);
    float s0, c0, s1, c1;
    sincosf(pf * inv0, &s0, &c0);
    sincosf(pf * inv1, &s1, &c1);
    float sgn = (lane < 32) ? -1.f : 1.f;      // x1*c - x2*s  |  x2*c + x1*s
    float o0 = y0 * c0 + sgn * p0 * s0;
    float o1 = y1 * c1 + sgn * p1 * s1;
    u32 outw = (u32)f2bf(o0) | ((u32)f2bf(o1) << 16);
    *(u32*)(xp + 2 * lane) = outw;
}

// ---------------- flash attention: QBLK=128, swapped-QK^T, in-register softmax ----------------
// Each wave owns TWO 16-col t-groups against the same staged K/V tile.
// Swizzle: zigzag q pairing so any CU's block set mixes heavy+light q-tiles
// (adjacent slots pair q/15-q; stride-32 slots flip) -> per-CU work ~ constant.
#define KSTR 136   // 128+8
#define VSTR 72    // 64+8

__global__ __launch_bounds__(256, 4) void flash_attn(const u16* __restrict__ Qb,
                                                     const u16* __restrict__ Kb,
                                                     const u16* __restrict__ Vt,
                                                     const int* __restrict__ seg,
                                                     const int* __restrict__ pos,
                                                     u16* __restrict__ Ob) {
    __shared__ __align__(16) u16 lK[64 * KSTR];
    __shared__ __align__(16) u16 lVt[128 * VSTR];   // V transposed: [d][s]
    __shared__ int lSeg[64];

    // XCD-aware + load-balanced decode: 1024 blocks = 8 xcd x (2 bg x 4 h x 16 q)
    const int lin = (int)blockIdx.x + 16 * ((int)blockIdx.y + 16 * (int)blockIdx.z);
    const int xcd = lin & 7, slot = lin >> 3;        // slot in [0,128)
    const int bg = xcd + 8 * (slot >> 6);            // [0,16)
    const int sub = slot & 63;
    const int b = bg >> 2, g = bg & 3;
    const int h = g * 4 + (sub >> 4);
    const int u = sub & 15;
    const int z = (u & 1) ? 15 - (u >> 1) : (u >> 1);   // zigzag: 0,15,1,14,...
    const int qi = (sub & 32) ? 15 - z : z;             // stride-32 flip
    const int q0 = qi * 128;
    const int tid = threadIdx.x;
    const int wave = tid >> 6, lane = tid & 63;
    const int l16 = lane & 15, quad = lane >> 4;

    bf16x8 qf[2][4];
#pragma unroll
    for (int gq = 0; gq < 2; gq++)
#pragma unroll
        for (int kk = 0; kk < 4; kk++)
            qf[gq][kk] = *(const bf16x8*)&Qb[((size_t)(b * Tc + q0 + gq * 64 + wave * 16 + l16) * Hc + h) * Kc + kk * 32 + quad * 8];

    int tg[2], sgt[2], ssg[2];
    bool segQ[2];
#pragma unroll
    for (int gq = 0; gq < 2; gq++) {
        tg[gq] = q0 + gq * 64 + wave * 16 + l16;
        sgt[gq] = seg[b * Tc + tg[gq]];
        segQ[gq] = (seg[b * Tc + q0 + gq * 64] == seg[b * Tc + q0 + gq * 64 + 63]);
        ssg[gq] = (q0 + gq * 64) - pos[b * Tc + q0 + gq * 64];   // exact segment starts
    }
    const int s_begin = (ssg[0] >> 6) << 6;   // tile-aligned (may include prev segment)

    float m_i[2] = {-1e30f, -1e30f}, l_i[2] = {0.f, 0.f};
    const f32x4 fz = {0.f, 0.f, 0.f, 0.f};
    f32x4 oc[2][8];   // O^T C-tiles per group
#pragma unroll
    for (int gq = 0; gq < 2; gq++)
#pragma unroll
        for (int i = 0; i < 8; i++) oc[gq][i] = fz;

    // bpermute source addrs for the P^T quad-redistribution
    const int addrA = (l16 + ((quad & 1) << 5)) << 2;   // m' = 0,1
    const int addrB = addrA + 64;                       // m' = 2,3
    const bool hiq = quad >= 2;

    // prefetch first K/V tile + seg row into registers
    uint4 kpre[4], vpre[4];
#pragma unroll
    for (int it = 0; it < 4; it++) {
        int c = tid + it * 256;
        kpre[it] = *(const uint4*)&Kb[((size_t)(b * Tc + s_begin + (c >> 4)) * Gc + g) * Kc + (c & 15) * 8];
        vpre[it] = *(const uint4*)&Vt[(((size_t)b * Gc + g) * Kc + (c >> 3)) * Tc + s_begin + (c & 7) * 8];
    }
    int segpre = (tid < 64) ? seg[b * Tc + s_begin + tid] : 0;

    const int s_end = q0 + 64;   // last tile covers group-B diagonal
    for (int s0 = s_begin; s0 <= s_end; s0 += 64) {
        sync_lgkm();   // prior iter's LDS reads complete (no vmcnt drain)
#pragma unroll
        for (int it = 0; it < 4; it++) {
            int c = tid + it * 256;
            *(uint4*)&lK[(c >> 4) * KSTR + (c & 15) * 8] = kpre[it];
        }
#pragma unroll
        for (int it = 0; it < 4; it++) {
            int c = tid + it * 256;
            *(uint4*)&lVt[(c >> 3) * VSTR + (c & 7) * 8] = vpre[it];
        }
        if (tid < 64) lSeg[tid] = segpre;
        if (s0 + 64 <= s_end) {   // prefetch next tile: stays in flight across barrier
#pragma unroll
            for (int it = 0; it < 4; it++) {
                int c = tid + it * 256;
                kpre[it] = *(const uint4*)&Kb[((size_t)(b * Tc + s0 + 64 + (c >> 4)) * Gc + g) * Kc + (c & 15) * 8];
                vpre[it] = *(const uint4*)&Vt[(((size_t)b * Gc + g) * Kc + (c >> 3)) * Tc + s0 + 64 + (c & 7) * 8];
            }
            if (tid < 64) segpre = seg[b * Tc + s0 + 64 + tid];
        }
        sync_lgkm();

        // S^T = K Q^T for both t-groups, sharing each bk read
        f32x4 sacc[2][4];
#pragma unroll
        for (int gq = 0; gq < 2; gq++)
#pragma unroll
            for (int mi = 0; mi < 4; mi++) sacc[gq][mi] = fz;
        __builtin_amdgcn_s_setprio(1);
#pragma unroll
        for (int kk = 0; kk < 4; kk++) {
#pragma unroll
            for (int mi = 0; mi < 4; mi++) {
                bf16x8 bk = *(const bf16x8*)&lK[(mi * 16 + l16) * KSTR + kk * 32 + quad * 8];
                sacc[0][mi] = __builtin_amdgcn_mfma_f32_16x16x32_bf16(bk, qf[0][kk], sacc[0][mi], 0, 0, 0);
                sacc[1][mi] = __builtin_amdgcn_mfma_f32_16x16x32_bf16(bk, qf[1][kk], sacc[1][mi], 0, 0, 0);
            }
        }
        __builtin_amdgcn_s_setprio(0);

        u32 W[2][4][2];
#pragma unroll
        for (int gq = 0; gq < 2; gq++) {
            const bool fast = segQ[gq] && (s0 >= ssg[gq]) && (s0 + 64 <= q0 + gq * 64);
            float rmax = -1e30f;
            if (fast) {
#pragma unroll
                for (int mi = 0; mi < 4; mi++)
#pragma unroll
                    for (int r = 0; r < 4; r++) rmax = fmaxf(rmax, sacc[gq][mi][r]);
            } else {
#pragma unroll
                for (int mi = 0; mi < 4; mi++) {
                    int sl = mi * 16 + quad * 4;
#pragma unroll
                    for (int r = 0; r < 4; r++) {
                        bool ok = (s0 + sl + r <= tg[gq]) && (lSeg[sl + r] == sgt[gq]);
                        float x = ok ? sacc[gq][mi][r] : -1e30f;
                        sacc[gq][mi][r] = x;
                        rmax = fmaxf(rmax, x);
                    }
                }
            }
            rmax = fmaxf(rmax, __shfl_xor(rmax, 16, 64));
            rmax = fmaxf(rmax, __shfl_xor(rmax, 32, 64));
            float mnew = fmaxf(m_i[gq], rmax);
            float alpha = __expf(m_i[gq] - mnew);
            m_i[gq] = mnew;
            float psum = 0.f;
#pragma unroll
            for (int mi = 0; mi < 4; mi++) {
                float p[4];
#pragma unroll
                for (int r = 0; r < 4; r++) {
                    float x = sacc[gq][mi][r];
                    p[r] = (x > -1e29f) ? __expf(x - m_i[gq]) : 0.f;
                    psum += p[r];
                }
                W[gq][mi][0] = cvt_pk_bf16(p[0], p[1]);
                W[gq][mi][1] = cvt_pk_bf16(p[2], p[3]);
            }
            psum += __shfl_xor(psum, 16, 64);
            psum += __shfl_xor(psum, 32, 64);
            l_i[gq] = l_i[gq] * alpha + psum;
#pragma unroll
            for (int ni = 0; ni < 8; ni++)
#pragma unroll
                for (int r = 0; r < 4; r++) oc[gq][ni][r] *= alpha;
        }

        // O^T += V^T P^T for both groups, sharing each av read
#pragma unroll
        for (int kk = 0; kk < 2; kk++) {
            bf16x8 bu[2];
#pragma unroll
            for (int gq = 0; gq < 2; gq++) {
                u32 w0a = (u32)__builtin_amdgcn_ds_bpermute(addrA, (int)W[gq][2 * kk][0]);
                u32 w0b = (u32)__builtin_amdgcn_ds_bpermute(addrA, (int)W[gq][2 * kk + 1][0]);
                u32 w1a = (u32)__builtin_amdgcn_ds_bpermute(addrA, (int)W[gq][2 * kk][1]);
                u32 w1b = (u32)__builtin_amdgcn_ds_bpermute(addrA, (int)W[gq][2 * kk + 1][1]);
                u32 w2a = (u32)__builtin_amdgcn_ds_bpermute(addrB, (int)W[gq][2 * kk][0]);
                u32 w2b = (u32)__builtin_amdgcn_ds_bpermute(addrB, (int)W[gq][2 * kk + 1][0]);
                u32 w3a = (u32)__builtin_amdgcn_ds_bpermute(addrB, (int)W[gq][2 * kk][1]);
                u32 w3b = (u32)__builtin_amdgcn_ds_bpermute(addrB, (int)W[gq][2 * kk + 1][1]);
                union { u32 w[4]; bf16x8 v; } uu;
                uu.w[0] = hiq ? w0b : w0a;
                uu.w[1] = hiq ? w1b : w1a;
                uu.w[2] = hiq ? w2b : w2a;
                uu.w[3] = hiq ? w3b : w3a;
                bu[gq] = uu.v;
            }
            __builtin_amdgcn_s_setprio(1);
#pragma unroll
            for (int ni = 0; ni < 8; ni++) {
                bf16x8 av = *(const bf16x8*)&lVt[(ni * 16 + l16) * VSTR + kk * 32 + quad * 8];
                oc[0][ni] = __builtin_amdgcn_mfma_f32_16x16x32_bf16(av, bu[0], oc[0][ni], 0, 0, 0);
                oc[1][ni] = __builtin_amdgcn_mfma_f32_16x16x32_bf16(av, bu[1], oc[1][ni], 0, 0, 0);
            }
            __builtin_amdgcn_s_setprio(0);
        }
    }

    // ---- epilogue: O^T -> O transpose via LDS (reuse lK for grpA, lVt for grpB) ----
    __syncthreads();
    float invl[2] = {1.f / l_i[0], 1.f / l_i[1]};
    const int tloc = wave * 16 + l16;
#pragma unroll
    for (int gq = 0; gq < 2; gq++) {
        u16* lO = gq ? (u16*)lVt : lK;   // both >= 64*KSTR u16
#pragma unroll
        for (int ni = 0; ni < 8; ni++) {
            u16 r4[4];
#pragma unroll
            for (int r = 0; r < 4; r++) r4[r] = f2bf(oc[gq][ni][r] * invl[gq]);
            *(uint2*)&lO[tloc * KSTR + ni * 16 + quad * 4] = *(uint2*)r4;
        }
    }
    __syncthreads();
#pragma unroll
    for (int gq = 0; gq < 2; gq++) {
        u16* lO = gq ? (u16*)lVt : lK;
#pragma unroll
        for (int j = 0; j < 4; j++) {
            int t2 = wave * 16 + j * 4 + quad;
            uint4 vv = *(const uint4*)&lO[t2 * KSTR + l16 * 8];
            *(uint4*)&Ob[((size_t)(b * Tc + q0 + gq * 64 + t2) * Hc + h) * Kc + l16 * 8] = vv;
        }
    }
}

extern "C" void kernel_launch(void* const* d_in, const int* in_sizes, int n_in,
                              void* d_out, int out_size, void* d_ws, size_t ws_size,
                              hipStream_t stream) {
    const float* hidden  = (const float*)d_in[0];
    const float* wq      = (const float*)d_in[1];
    const float* wk      = (const float*)d_in[2];
    const float* wv      = (const float*)d_in[3];
    const float* wo      = (const float*)d_in[4];
    const float* q_scale = (const float*)d_in[5];
    const float* k_scale = (const float*)d_in[6];
    const int*   segids  = (const int*)d_in[7];
    float* out = (float*)d_out;

    char* ws = (char*)d_ws;
    size_t off = 0;
    auto alloc = [&](size_t bytes) -> void* {
        void* p = ws + off;
        off += (bytes + 255) & ~(size_t)255;
        return p;
    };
    u16* hbf  = (u16*)alloc((size_t)Bc * Tc * Dc * 2);        // hidden bf16
    u16* wqT  = (u16*)alloc((size_t)Hc * Kc * Dc * 2);        // (2048 x 2048) \  adjacent:
    u16* wkT  = (u16*)alloc((size_t)Gc * Kc * Dc * 2);        // (512 x 2048)   } one 3072-row B^T
    u16* wvT  = (u16*)alloc((size_t)Gc * Kc * Dc * 2);        // (512 x 2048)  /
    u16* woT  = (u16*)alloc((size_t)Dc * Hc * Kc * 2);        // (2048 x 2048)
    u16* qb   = (u16*)alloc((size_t)Bc * Tc * Hc * Kc * 2);
    u16* kb   = (u16*)alloc((size_t)Bc * Tc * Gc * Kc * 2);
    u16* vtb  = (u16*)alloc((size_t)Bc * Gc * Kc * Tc * 2);   // V^T [b][g][d][t]
    u16* attn = (u16*)alloc((size_t)Bc * Tc * Hc * Kc * 2);
    int* posb = (int*)alloc((size_t)Bc * Tc * 4);
    (void)ws_size; (void)in_sizes; (void)n_in; (void)out_size;

    const int M = Bc * Tc;   // 8192
    const float qsc = 0.08838834764831845f;   // K^-0.5 folded into q rms_rope

    cvt_f2bf<<<(Bc * Tc * Dc) / 1024, 256, 0, stream>>>(hidden, hbf, Bc * Tc * Dc);
    transpose_f2bf<<<dim3(64, 64), 256, 0, stream>>>(wq, wqT, Dc, Hc * Kc);
    transpose_f2bf<<<dim3(16, 64), 256, 0, stream>>>(wk, wkT, Dc, Gc * Kc);
    transpose_f2bf<<<dim3(16, 64), 256, 0, stream>>>(wv, wvT, Dc, Gc * Kc);
    transpose_f2bf<<<dim3(64, 64), 256, 0, stream>>>(wo, woT, Hc * Kc, Dc);
    pos_kernel<<<(Bc * Tc) / 256, 256, 0, stream>>>(segids, posb);

    // merged Q+K+V projection: N = 3072 over adjacent [wqT; wkT; wvT]
    gemm_qkv<<<dim3(3072 / GBN, M / GBM), 256, 0, stream>>>(hbf, wqT, qb, kb, vtb, M, Dc);

    rms_rope<<<(M * Hc) / 4, 256, 0, stream>>>(qb, q_scale, posb, Hc, qsc);
    rms_rope<<<(M * Gc) / 4, 256, 0, stream>>>(kb, k_scale, posb, Gc, 1.0f);

    flash_attn<<<dim3(Tc / 128, Hc, Bc), 256, 0, stream>>>(qb, kb, vtb, segids, posb, attn);

    gemm_bt<<<dim3(Dc / GBN, M / GBM), 256, 0, stream>>>(attn, woT, out, nullptr, M, Dc, Hc * Kc);
}

// Round 5
// 588.865 us; speedup vs baseline: 1.1791x; 1.1791x over previous
//
#include <hip/hip_runtime.h>

typedef unsigned short u16;
typedef unsigned int u32;
using f32x4 = __attribute__((ext_vector_type(4))) float;
using bf16x8 = __attribute__((ext_vector_type(8))) __bf16;

constexpr int Bc = 4, Tc = 2048, Dc = 2048, Hc = 16, Gc = 4, Kc = 128;
constexpr float EPSc = 1e-6f;

__device__ __forceinline__ u16 f2bf(float f) {
    u32 u = __float_as_uint(f);
    u = (u + 0x7fffu + ((u >> 16) & 1u)) >> 16;
    return (u16)u;
}
__device__ __forceinline__ float bf2f(u16 h) {
    return __uint_as_float(((u32)h) << 16);
}

// async global->LDS, 16B per lane; LDS dest must be wave-uniform base + lane*16
__device__ __forceinline__ void async_ld16(void* lds, const void* g) {
    __builtin_amdgcn_global_load_lds(
        (const __attribute__((address_space(1))) unsigned int*)g,
        (__attribute__((address_space(3))) unsigned int*)lds, 16, 0, 0);
}

// raw barrier: waits own LDS ops, does NOT drain vmcnt (prefetch stays in flight)
__device__ __forceinline__ void sync_lgkm() {
    asm volatile("s_waitcnt lgkmcnt(0)" ::: "memory");
    __builtin_amdgcn_s_barrier();
    asm volatile("" ::: "memory");
}

__device__ __forceinline__ u32 cvt_pk_bf16(float lo, float hi) {
    u32 r;
    asm("v_cvt_pk_bf16_f32 %0, %1, %2" : "=v"(r) : "v"(lo), "v"(hi));
    return r;
}

// ---------------- fp32 -> bf16 convert ----------------
__global__ __launch_bounds__(256) void cvt_f2bf(const float* __restrict__ in,
                                                u16* __restrict__ out, int n) {
    int i = (blockIdx.x * 256 + threadIdx.x) * 4;
    if (i >= n) return;
    float4 f = *(const float4*)(in + i);
    u16 r[4] = { f2bf(f.x), f2bf(f.y), f2bf(f.z), f2bf(f.w) };
    *(uint2*)(out + i) = *(uint2*)r;
}

// ------- transpose+convert: in (rows x cols) f32 -> out (cols x rows) bf16 -------
__global__ __launch_bounds__(256) void transpose_f2bf(const float* __restrict__ in,
                                                      u16* __restrict__ out,
                                                      int rows, int cols) {
    __shared__ float tile[32][33];
    int tx = threadIdx.x & 31, ty = threadIdx.x >> 5;
    int c0 = blockIdx.x * 32, r0 = blockIdx.y * 32;
#pragma unroll
    for (int j = 0; j < 4; j++)
        tile[ty + j * 8][tx] = in[(size_t)(r0 + ty + j * 8) * cols + c0 + tx];
    __syncthreads();
#pragma unroll
    for (int j = 0; j < 4; j++)
        out[(size_t)(c0 + ty + j * 8) * rows + r0 + tx] = f2bf(tile[tx][ty + j * 8]);
}

// ---------------- positions from (sorted) segment ids ----------------
__global__ void pos_kernel(const int* __restrict__ seg, int* __restrict__ pos) {
    int idx = blockIdx.x * 256 + threadIdx.x;
    if (idx >= Bc * Tc) return;
    int b = idx / Tc, t = idx - b * Tc;
    const int* s = seg + b * Tc;
    int v = s[t];
    int lo = 0, hi = t;
    while (lo < hi) { int mid = (lo + hi) >> 1; if (s[mid] < v) lo = mid + 1; else hi = mid; }
    pos[idx] = t - lo;   // t - seg_start
}

// ---------------- bf16 GEMM (m97 structure): C(MxN) = A(MxKd) * Bt(NxKd)^T ----------------
#define GBM 128
#define GBN 128
#define GBK 32

__global__ __launch_bounds__(256) void gemm_bt(const u16* __restrict__ A,
                                               const u16* __restrict__ Bt,
                                               float* __restrict__ Cf, u16* __restrict__ Cb,
                                               int M, int N, int Kd) {
    __shared__ __align__(16) u16 lA[GBM * GBK];   // unpadded: required by global_load_lds lane order
    __shared__ __align__(16) u16 lB[GBN * GBK];
    const int tid = threadIdx.x;
    const int m0 = blockIdx.y * GBM, n0 = blockIdx.x * GBN;
    const int wave = tid >> 6, lane = tid & 63;
    const int l16 = lane & 15, quad = lane >> 4;
    const int wm = (wave & 1) * 64, wn = (wave >> 1) * 64;

    const int c0 = tid, c1 = tid + 256;
    const u16* gA0 = A + (size_t)(m0 + (c0 >> 2)) * Kd + (c0 & 3) * 8;
    const u16* gA1 = A + (size_t)(m0 + (c1 >> 2)) * Kd + (c1 & 3) * 8;
    const u16* gB0 = Bt + (size_t)(n0 + (c0 >> 2)) * Kd + (c0 & 3) * 8;
    const u16* gB1 = Bt + (size_t)(n0 + (c1 >> 2)) * Kd + (c1 & 3) * 8;
    u16* sA0 = &lA[c0 * 8];
    u16* sA1 = &lA[c1 * 8];
    u16* sB0 = &lB[c0 * 8];
    u16* sB1 = &lB[c1 * 8];

    const f32x4 fz = {0.f, 0.f, 0.f, 0.f};
    f32x4 acc[4][4];
#pragma unroll
    for (int i = 0; i < 4; i++)
#pragma unroll
        for (int j = 0; j < 4; j++) acc[i][j] = fz;

    for (int k0 = 0; k0 < Kd; k0 += GBK) {
        __syncthreads();
        async_ld16(sA0, gA0 + k0);
        async_ld16(sA1, gA1 + k0);
        async_ld16(sB0, gB0 + k0);
        async_ld16(sB1, gB1 + k0);
        __syncthreads();
        bf16x8 af[4], bg[4];
#pragma unroll
        for (int i = 0; i < 4; i++) {
            af[i] = *(const bf16x8*)&lA[(wm + i * 16 + l16) * GBK + quad * 8];
            bg[i] = *(const bf16x8*)&lB[(wn + i * 16 + l16) * GBK + quad * 8];
        }
#pragma unroll
        for (int mi = 0; mi < 4; mi++)
#pragma unroll
            for (int ni = 0; ni < 4; ni++)
                acc[mi][ni] = __builtin_amdgcn_mfma_f32_16x16x32_bf16(af[mi], bg[ni], acc[mi][ni], 0, 0, 0);
    }

#pragma unroll
    for (int mi = 0; mi < 4; mi++)
#pragma unroll
        for (int ni = 0; ni < 4; ni++)
#pragma unroll
            for (int r = 0; r < 4; r++) {
                int row = m0 + wm + mi * 16 + quad * 4 + r;   // C/D: row=quad*4+reg
                int col = n0 + wn + ni * 16 + l16;            //      col=lane&15
                float v = acc[mi][ni][r];
                if (Cf) Cf[(size_t)row * N + col] = v;
                else    Cb[(size_t)row * N + col] = f2bf(v);
            }
}

// ------- merged QKV GEMM: N=3072 over [wqT;wkT;wvT]; Q->qb, K->kb, V->Vt[b][g][d][t] -------
__global__ __launch_bounds__(256) void gemm_qkv(const u16* __restrict__ A,
                                                const u16* __restrict__ Bt,
                                                u16* __restrict__ qb, u16* __restrict__ kb,
                                                u16* __restrict__ vtb, int M, int Kd) {
    __shared__ __align__(16) u16 lA[GBM * GBK];
    __shared__ __align__(16) u16 lB[GBN * GBK];
    const int tid = threadIdx.x;
    const int m0 = blockIdx.y * GBM, n0 = blockIdx.x * GBN;
    const int wave = tid >> 6, lane = tid & 63;
    const int l16 = lane & 15, quad = lane >> 4;
    const int wm = (wave & 1) * 64, wn = (wave >> 1) * 64;

    const int c0 = tid, c1 = tid + 256;
    const u16* gA0 = A + (size_t)(m0 + (c0 >> 2)) * Kd + (c0 & 3) * 8;
    const u16* gA1 = A + (size_t)(m0 + (c1 >> 2)) * Kd + (c1 & 3) * 8;
    const u16* gB0 = Bt + (size_t)(n0 + (c0 >> 2)) * Kd + (c0 & 3) * 8;
    const u16* gB1 = Bt + (size_t)(n0 + (c1 >> 2)) * Kd + (c1 & 3) * 8;
    u16* sA0 = &lA[c0 * 8];
    u16* sA1 = &lA[c1 * 8];
    u16* sB0 = &lB[c0 * 8];
    u16* sB1 = &lB[c1 * 8];

    const f32x4 fz = {0.f, 0.f, 0.f, 0.f};
    f32x4 acc[4][4];
#pragma unroll
    for (int i = 0; i < 4; i++)
#pragma unroll
        for (int j = 0; j < 4; j++) acc[i][j] = fz;

    for (int k0 = 0; k0 < Kd; k0 += GBK) {
        __syncthreads();
        async_ld16(sA0, gA0 + k0);
        async_ld16(sA1, gA1 + k0);
        async_ld16(sB0, gB0 + k0);
        async_ld16(sB1, gB1 + k0);
        __syncthreads();
        bf16x8 af[4], bg[4];
#pragma unroll
        for (int i = 0; i < 4; i++) {
            af[i] = *(const bf16x8*)&lA[(wm + i * 16 + l16) * GBK + quad * 8];
            bg[i] = *(const bf16x8*)&lB[(wn + i * 16 + l16) * GBK + quad * 8];
        }
#pragma unroll
        for (int mi = 0; mi < 4; mi++)
#pragma unroll
            for (int ni = 0; ni < 4; ni++)
                acc[mi][ni] = __builtin_amdgcn_mfma_f32_16x16x32_bf16(af[mi], bg[ni], acc[mi][ni], 0, 0, 0);
    }

    const int nbase = n0 + wn;   // 64-aligned; regions split at 2048 / 2560 (both 64-aligned)
    if (nbase < 2048) {
        // Q: qb[(b,t)][(h,d)] = [M][2048]
#pragma unroll
        for (int mi = 0; mi < 4; mi++)
#pragma unroll
            for (int ni = 0; ni < 4; ni++)
#pragma unroll
                for (int r = 0; r < 4; r++) {
                    int row = m0 + wm + mi * 16 + quad * 4 + r;
                    int col = nbase + ni * 16 + l16;
                    qb[(size_t)row * 2048 + col] = f2bf(acc[mi][ni][r]);
                }
    } else if (nbase < 2560) {
        // K: kb[(b,t)][(g,d)] = [M][512]
#pragma unroll
        for (int mi = 0; mi < 4; mi++)
#pragma unroll
            for (int ni = 0; ni < 4; ni++)
#pragma unroll
                for (int r = 0; r < 4; r++) {
                    int row = m0 + wm + mi * 16 + quad * 4 + r;
                    int col = nbase + ni * 16 + l16 - 2048;
                    kb[(size_t)row * 512 + col] = f2bf(acc[mi][ni][r]);
                }
    } else {
        // V: transposed Vt[b][g][d][t]; 4 consecutive t per lane -> 8B store
#pragma unroll
        for (int mi = 0; mi < 4; mi++)
#pragma unroll
            for (int ni = 0; ni < 4; ni++) {
                int nv = nbase + ni * 16 + l16 - 2560;
                int g = nv >> 7, d = nv & 127;
                int m = m0 + wm + mi * 16 + quad * 4;
                int b = m >> 11, t = m & 2047;
                u16 r4[4];
#pragma unroll
                for (int r = 0; r < 4; r++) r4[r] = f2bf(acc[mi][ni][r]);
                *(uint2*)&vtb[(((size_t)b * Gc + g) * Kc + d) * Tc + t] = *(uint2*)r4;
            }
    }
}

// ---------------- fused RMSNorm + RoPE, vectorized (u32 = 2 bf16 per lane) ----------------
// lane l holds dims {2l, 2l+1}; rope partner (d <-> d+64) exchanged via shfl_xor(32).
__global__ __launch_bounds__(256) void rms_rope(u16* __restrict__ X,
                                                const float* __restrict__ sc,
                                                const int* __restrict__ pos, int NH,
                                                float smul) {
    int row = blockIdx.x * 4 + (threadIdx.x >> 6);   // one wave per (b,t,head) row
    int lane = threadIdx.x & 63;
    int bt = row / NH;
    u16* xp = X + (size_t)row * Kc;
    u32 w = *(const u32*)(xp + 2 * lane);
    float a0 = bf2f((u16)(w & 0xffffu)), a1 = bf2f((u16)(w >> 16));
    float ss = a0 * a0 + a1 * a1;
#pragma unroll
    for (int m = 1; m < 64; m <<= 1) ss += __shfl_xor(ss, m, 64);
    float rn = rsqrtf(ss * (1.f / 128.f) + EPSc) * smul;   // fold attn scale into q
    float2 scv = *(const float2*)(sc + 2 * lane);
    float y0 = a0 * rn * scv.x, y1 = a1 * rn * scv.y;
    float p0 = __shfl_xor(y0, 32, 64);   // rope partner's scaled value
    float p1 = __shfl_xor(y1, 32, 64);
    int j0 = (2 * lane) & 63;            // freq index (same for lane and partner)
    float pf = (float)pos[bt];
    const float nl2 = -0.20762050593046015f;   // -log2(10000)/64
    float inv0 = exp2f((float)j0 * nl2);
    float inv1 = exp2f((float)(j0 + 1) * nl2);
    float s0, c0, s1, c1;
    sincosf(pf * inv0, &s0, &c0);
    sincosf(pf * inv1, &s1, &c1);
    float sgn = (lane < 32) ? -1.f : 1.f;      // x1*c - x2*s  |  x2*c + x1*s
    float o0 = y0 * c0 + sgn * p0 * s0;
    float o1 = y1 * c1 + sgn * p1 * s1;
    u32 outw = (u32)f2bf(o0) | ((u32)f2bf(o1) << 16);
    *(u32*)(xp + 2 * lane) = outw;
}

// ---------------- flash attention: QBLK=128, swapped-QK^T, in-register softmax ----------------
// Each wave owns TWO 16-col t-groups against the same staged K/V tile.
// Swizzle: zigzag q pairing so any CU's block set mixes heavy+light q-tiles.
// launch_bounds (256,2): DO NOT raise to (256,4) -- it forces VGPR<=~64 and the
// oc/qf/prefetch state (~130 regs) spills to scratch (r4: 800MB HBM traffic, 224us).
// With 108 VGPR and 36.3KB LDS the HW still co-resides 4 blocks/CU.
#define KSTR 136   // 128+8
#define VSTR 72    // 64+8

__global__ __launch_bounds__(256, 2) void flash_attn(const u16* __restrict__ Qb,
                                                     const u16* __restrict__ Kb,
                                                     const u16* __restrict__ Vt,
                                                     const int* __restrict__ seg,
                                                     const int* __restrict__ pos,
                                                     u16* __restrict__ Ob) {
    __shared__ __align__(16) u16 lK[64 * KSTR];
    __shared__ __align__(16) u16 lVt[128 * VSTR];   // V transposed: [d][s]
    __shared__ int lSeg[64];

    // XCD-aware + load-balanced decode: 1024 blocks = 8 xcd x (2 bg x 4 h x 16 q)
    const int lin = (int)blockIdx.x + 16 * ((int)blockIdx.y + 16 * (int)blockIdx.z);
    const int xcd = lin & 7, slot = lin >> 3;        // slot in [0,128)
    const int bg = xcd + 8 * (slot >> 6);            // [0,16)
    const int sub = slot & 63;
    const int b = bg >> 2, g = bg & 3;
    const int h = g * 4 + (sub >> 4);
    const int u = sub & 15;
    const int z = (u & 1) ? 15 - (u >> 1) : (u >> 1);   // zigzag: 0,15,1,14,...
    const int qi = (sub & 32) ? 15 - z : z;             // stride-32 flip
    const int q0 = qi * 128;
    const int tid = threadIdx.x;
    const int wave = tid >> 6, lane = tid & 63;
    const int l16 = lane & 15, quad = lane >> 4;

    bf16x8 qf[2][4];
#pragma unroll
    for (int gq = 0; gq < 2; gq++)
#pragma unroll
        for (int kk = 0; kk < 4; kk++)
            qf[gq][kk] = *(const bf16x8*)&Qb[((size_t)(b * Tc + q0 + gq * 64 + wave * 16 + l16) * Hc + h) * Kc + kk * 32 + quad * 8];

    int tg[2], sgt[2], ssg[2];
    bool segQ[2];
#pragma unroll
    for (int gq = 0; gq < 2; gq++) {
        tg[gq] = q0 + gq * 64 + wave * 16 + l16;
        sgt[gq] = seg[b * Tc + tg[gq]];
        segQ[gq] = (seg[b * Tc + q0 + gq * 64] == seg[b * Tc + q0 + gq * 64 + 63]);
        ssg[gq] = (q0 + gq * 64) - pos[b * Tc + q0 + gq * 64];   // exact segment starts
    }
    const int s_begin = (ssg[0] >> 6) << 6;   // tile-aligned (may include prev segment)

    float m_i[2] = {-1e30f, -1e30f}, l_i[2] = {0.f, 0.f};
    const f32x4 fz = {0.f, 0.f, 0.f, 0.f};
    f32x4 oc[2][8];   // O^T C-tiles per group
#pragma unroll
    for (int gq = 0; gq < 2; gq++)
#pragma unroll
        for (int i = 0; i < 8; i++) oc[gq][i] = fz;

    // bpermute source addrs for the P^T quad-redistribution
    const int addrA = (l16 + ((quad & 1) << 5)) << 2;   // m' = 0,1
    const int addrB = addrA + 64;                       // m' = 2,3
    const bool hiq = quad >= 2;

    // prefetch first K/V tile + seg row into registers
    uint4 kpre[4], vpre[4];
#pragma unroll
    for (int it = 0; it < 4; it++) {
        int c = tid + it * 256;
        kpre[it] = *(const uint4*)&Kb[((size_t)(b * Tc + s_begin + (c >> 4)) * Gc + g) * Kc + (c & 15) * 8];
        vpre[it] = *(const uint4*)&Vt[(((size_t)b * Gc + g) * Kc + (c >> 3)) * Tc + s_begin + (c & 7) * 8];
    }
    int segpre = (tid < 64) ? seg[b * Tc + s_begin + tid] : 0;

    const int s_end = q0 + 64;   // last tile covers group-B diagonal
    for (int s0 = s_begin; s0 <= s_end; s0 += 64) {
        sync_lgkm();   // prior iter's LDS reads complete (no vmcnt drain)
#pragma unroll
        for (int it = 0; it < 4; it++) {
            int c = tid + it * 256;
            *(uint4*)&lK[(c >> 4) * KSTR + (c & 15) * 8] = kpre[it];
        }
#pragma unroll
        for (int it = 0; it < 4; it++) {
            int c = tid + it * 256;
            *(uint4*)&lVt[(c >> 3) * VSTR + (c & 7) * 8] = vpre[it];
        }
        if (tid < 64) lSeg[tid] = segpre;
        if (s0 + 64 <= s_end) {   // prefetch next tile: stays in flight across barrier
#pragma unroll
            for (int it = 0; it < 4; it++) {
                int c = tid + it * 256;
                kpre[it] = *(const uint4*)&Kb[((size_t)(b * Tc + s0 + 64 + (c >> 4)) * Gc + g) * Kc + (c & 15) * 8];
                vpre[it] = *(const uint4*)&Vt[(((size_t)b * Gc + g) * Kc + (c >> 3)) * Tc + s0 + 64 + (c & 7) * 8];
            }
            if (tid < 64) segpre = seg[b * Tc + s0 + 64 + tid];
        }
        sync_lgkm();

        // S^T = K Q^T for both t-groups, sharing each bk read
        f32x4 sacc[2][4];
#pragma unroll
        for (int gq = 0; gq < 2; gq++)
#pragma unroll
            for (int mi = 0; mi < 4; mi++) sacc[gq][mi] = fz;
        __builtin_amdgcn_s_setprio(1);
#pragma unroll
        for (int kk = 0; kk < 4; kk++) {
#pragma unroll
            for (int mi = 0; mi < 4; mi++) {
                bf16x8 bk = *(const bf16x8*)&lK[(mi * 16 + l16) * KSTR + kk * 32 + quad * 8];
                sacc[0][mi] = __builtin_amdgcn_mfma_f32_16x16x32_bf16(bk, qf[0][kk], sacc[0][mi], 0, 0, 0);
                sacc[1][mi] = __builtin_amdgcn_mfma_f32_16x16x32_bf16(bk, qf[1][kk], sacc[1][mi], 0, 0, 0);
            }
        }
        __builtin_amdgcn_s_setprio(0);

        u32 W[2][4][2];
#pragma unroll
        for (int gq = 0; gq < 2; gq++) {
            const bool fast = segQ[gq] && (s0 >= ssg[gq]) && (s0 + 64 <= q0 + gq * 64);
            float rmax = -1e30f;
            if (fast) {
#pragma unroll
                for (int mi = 0; mi < 4; mi++)
#pragma unroll
                    for (int r = 0; r < 4; r++) rmax = fmaxf(rmax, sacc[gq][mi][r]);
            } else {
#pragma unroll
                for (int mi = 0; mi < 4; mi++) {
                    int sl = mi * 16 + quad * 4;
#pragma unroll
                    for (int r = 0; r < 4; r++) {
                        bool ok = (s0 + sl + r <= tg[gq]) && (lSeg[sl + r] == sgt[gq]);
                        float x = ok ? sacc[gq][mi][r] : -1e30f;
                        sacc[gq][mi][r] = x;
                        rmax = fmaxf(rmax, x);
                    }
                }
            }
            rmax = fmaxf(rmax, __shfl_xor(rmax, 16, 64));
            rmax = fmaxf(rmax, __shfl_xor(rmax, 32, 64));
            float mnew = fmaxf(m_i[gq], rmax);
            float alpha = __expf(m_i[gq] - mnew);
            m_i[gq] = mnew;
            float psum = 0.f;
#pragma unroll
            for (int mi = 0; mi < 4; mi++) {
                float p[4];
#pragma unroll
                for (int r = 0; r < 4; r++) {
                    float x = sacc[gq][mi][r];
                    p[r] = (x > -1e29f) ? __expf(x - m_i[gq]) : 0.f;
                    psum += p[r];
                }
                W[gq][mi][0] = cvt_pk_bf16(p[0], p[1]);
                W[gq][mi][1] = cvt_pk_bf16(p[2], p[3]);
            }
            psum += __shfl_xor(psum, 16, 64);
            psum += __shfl_xor(psum, 32, 64);
            l_i[gq] = l_i[gq] * alpha + psum;
#pragma unroll
            for (int ni = 0; ni < 8; ni++)
#pragma unroll
                for (int r = 0; r < 4; r++) oc[gq][ni][r] *= alpha;
        }

        // O^T += V^T P^T for both groups, sharing each av read
#pragma unroll
        for (int kk = 0; kk < 2; kk++) {
            bf16x8 bu[2];
#pragma unroll
            for (int gq = 0; gq < 2; gq++) {
                u32 w0a = (u32)__builtin_amdgcn_ds_bpermute(addrA, (int)W[gq][2 * kk][0]);
                u32 w0b = (u32)__builtin_amdgcn_ds_bpermute(addrA, (int)W[gq][2 * kk + 1][0]);
                u32 w1a = (u32)__builtin_amdgcn_ds_bpermute(addrA, (int)W[gq][2 * kk][1]);
                u32 w1b = (u32)__builtin_amdgcn_ds_bpermute(addrA, (int)W[gq][2 * kk + 1][1]);
                u32 w2a = (u32)__builtin_amdgcn_ds_bpermute(addrB, (int)W[gq][2 * kk][0]);
                u32 w2b = (u32)__builtin_amdgcn_ds_bpermute(addrB, (int)W[gq][2 * kk + 1][0]);
                u32 w3a = (u32)__builtin_amdgcn_ds_bpermute(addrB, (int)W[gq][2 * kk][1]);
                u32 w3b = (u32)__builtin_amdgcn_ds_bpermute(addrB, (int)W[gq][2 * kk + 1][1]);
                union { u32 w[4]; bf16x8 v; } uu;
                uu.w[0] = hiq ? w0b : w0a;
                uu.w[1] = hiq ? w1b : w1a;
                uu.w[2] = hiq ? w2b : w2a;
                uu.w[3] = hiq ? w3b : w3a;
                bu[gq] = uu.v;
            }
            __builtin_amdgcn_s_setprio(1);
#pragma unroll
            for (int ni = 0; ni < 8; ni++) {
                bf16x8 av = *(const bf16x8*)&lVt[(ni * 16 + l16) * VSTR + kk * 32 + quad * 8];
                oc[0][ni] = __builtin_amdgcn_mfma_f32_16x16x32_bf16(av, bu[0], oc[0][ni], 0, 0, 0);
                oc[1][ni] = __builtin_amdgcn_mfma_f32_16x16x32_bf16(av, bu[1], oc[1][ni], 0, 0, 0);
            }
            __builtin_amdgcn_s_setprio(0);
        }
    }

    // ---- epilogue: O^T -> O transpose via LDS (reuse lK for grpA, lVt for grpB) ----
    __syncthreads();
    float invl[2] = {1.f / l_i[0], 1.f / l_i[1]};
    const int tloc = wave * 16 + l16;
#pragma unroll
    for (int gq = 0; gq < 2; gq++) {
        u16* lO = gq ? (u16*)lVt : lK;   // both >= 64*KSTR u16
#pragma unroll
        for (int ni = 0; ni < 8; ni++) {
            u16 r4[4];
#pragma unroll
            for (int r = 0; r < 4; r++) r4[r] = f2bf(oc[gq][ni][r] * invl[gq]);
            *(uint2*)&lO[tloc * KSTR + ni * 16 + quad * 4] = *(uint2*)r4;
        }
    }
    __syncthreads();
#pragma unroll
    for (int gq = 0; gq < 2; gq++) {
        u16* lO = gq ? (u16*)lVt : lK;
#pragma unroll
        for (int j = 0; j < 4; j++) {
            int t2 = wave * 16 + j * 4 + quad;
            uint4 vv = *(const uint4*)&lO[t2 * KSTR + l16 * 8];
            *(uint4*)&Ob[((size_t)(b * Tc + q0 + gq * 64 + t2) * Hc + h) * Kc + l16 * 8] = vv;
        }
    }
}

extern "C" void kernel_launch(void* const* d_in, const int* in_sizes, int n_in,
                              void* d_out, int out_size, void* d_ws, size_t ws_size,
                              hipStream_t stream) {
    const float* hidden  = (const float*)d_in[0];
    const float* wq      = (const float*)d_in[1];
    const float* wk      = (const float*)d_in[2];
    const float* wv      = (const float*)d_in[3];
    const float* wo      = (const float*)d_in[4];
    const float* q_scale = (const float*)d_in[5];
    const float* k_scale = (const float*)d_in[6];
    const int*   segids  = (const int*)d_in[7];
    float* out = (float*)d_out;

    char* ws = (char*)d_ws;
    size_t off = 0;
    auto alloc = [&](size_t bytes) -> void* {
        void* p = ws + off;
        off += (bytes + 255) & ~(size_t)255;
        return p;
    };
    u16* hbf  = (u16*)alloc((size_t)Bc * Tc * Dc * 2);        // hidden bf16
    u16* wqT  = (u16*)alloc((size_t)Hc * Kc * Dc * 2);        // (2048 x 2048) \  adjacent:
    u16* wkT  = (u16*)alloc((size_t)Gc * Kc * Dc * 2);        // (512 x 2048)   } one 3072-row B^T
    u16* wvT  = (u16*)alloc((size_t)Gc * Kc * Dc * 2);        // (512 x 2048)  /
    u16* woT  = (u16*)alloc((size_t)Dc * Hc * Kc * 2);        // (2048 x 2048)
    u16* qb   = (u16*)alloc((size_t)Bc * Tc * Hc * Kc * 2);
    u16* kb   = (u16*)alloc((size_t)Bc * Tc * Gc * Kc * 2);
    u16* vtb  = (u16*)alloc((size_t)Bc * Gc * Kc * Tc * 2);   // V^T [b][g][d][t]
    u16* attn = (u16*)alloc((size_t)Bc * Tc * Hc * Kc * 2);
    int* posb = (int*)alloc((size_t)Bc * Tc * 4);
    (void)ws_size; (void)in_sizes; (void)n_in; (void)out_size;

    const int M = Bc * Tc;   // 8192
    const float qsc = 0.08838834764831845f;   // K^-0.5 folded into q rms_rope

    cvt_f2bf<<<(Bc * Tc * Dc) / 1024, 256, 0, stream>>>(hidden, hbf, Bc * Tc * Dc);
    transpose_f2bf<<<dim3(64, 64), 256, 0, stream>>>(wq, wqT, Dc, Hc * Kc);
    transpose_f2bf<<<dim3(16, 64), 256, 0, stream>>>(wk, wkT, Dc, Gc * Kc);
    transpose_f2bf<<<dim3(16, 64), 256, 0, stream>>>(wv, wvT, Dc, Gc * Kc);
    transpose_f2bf<<<dim3(64, 64), 256, 0, stream>>>(wo, woT, Hc * Kc, Dc);
    pos_kernel<<<(Bc * Tc) / 256, 256, 0, stream>>>(segids, posb);

    // merged Q+K+V projection: N = 3072 over adjacent [wqT; wkT; wvT]
    gemm_qkv<<<dim3(3072 / GBN, M / GBM), 256, 0, stream>>>(hbf, wqT, qb, kb, vtb, M, Dc);

    rms_rope<<<(M * Hc) / 4, 256, 0, stream>>>(qb, q_scale, posb, Hc, qsc);
    rms_rope<<<(M * Gc) / 4, 256, 0, stream>>>(kb, k_scale, posb, Gc, 1.0f);

    flash_attn<<<dim3(Tc / 128, Hc, Bc), 256, 0, stream>>>(qb, kb, vtb, segids, posb, attn);

    gemm_bt<<<dim3(Dc / GBN, M / GBM), 256, 0, stream>>>(attn, woT, out, nullptr, M, Dc, Hc * Kc);
}

// Round 6
// 539.272 us; speedup vs baseline: 1.2876x; 1.0920x over previous
//
#include <hip/hip_runtime.h>

typedef unsigned short u16;
typedef unsigned int u32;
using f32x4 = __attribute__((ext_vector_type(4))) float;
using bf16x8 = __attribute__((ext_vector_type(8))) __bf16;

constexpr int Bc = 4, Tc = 2048, Dc = 2048, Hc = 16, Gc = 4, Kc = 128;
constexpr float EPSc = 1e-6f;

__device__ __forceinline__ u16 f2bf(float f) {
    u32 u = __float_as_uint(f);
    u = (u + 0x7fffu + ((u >> 16) & 1u)) >> 16;
    return (u16)u;
}
__device__ __forceinline__ float bf2f(u16 h) {
    return __uint_as_float(((u32)h) << 16);
}

// async global->LDS, 16B per lane; LDS dest must be wave-uniform base + lane*16
__device__ __forceinline__ void async_ld16(void* lds, const void* g) {
    __builtin_amdgcn_global_load_lds(
        (const __attribute__((address_space(1))) unsigned int*)g,
        (__attribute__((address_space(3))) unsigned int*)lds, 16, 0, 0);
}

// raw barrier: waits own LDS ops, does NOT drain vmcnt (prefetch stays in flight)
__device__ __forceinline__ void sync_lgkm() {
    asm volatile("s_waitcnt lgkmcnt(0)" ::: "memory");
    __builtin_amdgcn_s_barrier();
    asm volatile("" ::: "memory");
}

__device__ __forceinline__ void raw_barrier() {
    asm volatile("" ::: "memory");
    __builtin_amdgcn_s_barrier();
    asm volatile("" ::: "memory");
}

__device__ __forceinline__ u32 cvt_pk_bf16(float lo, float hi) {
    u32 r;
    asm("v_cvt_pk_bf16_f32 %0, %1, %2" : "=v"(r) : "v"(lo), "v"(hi));
    return r;
}

// ---------------- fp32 -> bf16 convert ----------------
__global__ __launch_bounds__(256) void cvt_f2bf(const float* __restrict__ in,
                                                u16* __restrict__ out, int n) {
    int i = (blockIdx.x * 256 + threadIdx.x) * 4;
    if (i >= n) return;
    float4 f = *(const float4*)(in + i);
    u16 r[4] = { f2bf(f.x), f2bf(f.y), f2bf(f.z), f2bf(f.w) };
    *(uint2*)(out + i) = *(uint2*)r;
}

// ------- transpose+convert: in (rows x cols) f32 -> out (cols x rows) bf16 -------
__global__ __launch_bounds__(256) void transpose_f2bf(const float* __restrict__ in,
                                                      u16* __restrict__ out,
                                                      int rows, int cols) {
    __shared__ float tile[32][33];
    int tx = threadIdx.x & 31, ty = threadIdx.x >> 5;
    int c0 = blockIdx.x * 32, r0 = blockIdx.y * 32;
#pragma unroll
    for (int j = 0; j < 4; j++)
        tile[ty + j * 8][tx] = in[(size_t)(r0 + ty + j * 8) * cols + c0 + tx];
    __syncthreads();
#pragma unroll
    for (int j = 0; j < 4; j++)
        out[(size_t)(c0 + ty + j * 8) * rows + r0 + tx] = f2bf(tile[tx][ty + j * 8]);
}

// ---------------- positions from (sorted) segment ids ----------------
__global__ void pos_kernel(const int* __restrict__ seg, int* __restrict__ pos) {
    int idx = blockIdx.x * 256 + threadIdx.x;
    if (idx >= Bc * Tc) return;
    int b = idx / Tc, t = idx - b * Tc;
    const int* s = seg + b * Tc;
    int v = s[t];
    int lo = 0, hi = t;
    while (lo < hi) { int mid = (lo + hi) >> 1; if (s[mid] < v) lo = mid + 1; else hi = mid; }
    pos[idx] = t - lo;   // t - seg_start
}

// ======== 256x256 8-phase GEMM (m201 structure): C(MxN) = A(MxKd)*Bt(NxKd)^T ========
// 512 thr / 8 waves (2M x 4N); BK=64; LDS 128KB = 2 buf x (A[2][128][64] + B[2][128][64]).
// st_16x32 swizzle: linear gload_lds dest + inverse-swizzled global SOURCE + swizzled
// ds_read (rule: both-sides-or-neither). Counted vmcnt(6) at phases 4/8 only.
// Per iteration: 2 K-tiles (E=buf0 even, O=buf1 odd), 8 phases, 16 MFMA/phase.
// Stage plan (2 x 8KB chunks/phase, each strictly after that chunk's last read):
//   p1:O.A0b,A1b(ktO) p2:E.B0ab(ktE) p3:E.B1ab p4:E.A0a,A1a p5:E.A0b,A1b
//   p6:O.B0ab(ktO2) p7:O.B1ab p8:O.A0a,A1a
// mode 0: QKV split epilogue (qb/kb/vtb); mode 1: float C.
__global__ __launch_bounds__(512, 1) void gemm256(const u16* __restrict__ A,
                                                  const u16* __restrict__ Bt,
                                                  float* __restrict__ Cf,
                                                  u16* __restrict__ qb, u16* __restrict__ kb,
                                                  u16* __restrict__ vtb,
                                                  int N, int Kd, int mode) {
    __shared__ __align__(16) u16 lds[2][4][8192];   // [buf][A0,A1,B0,B1][16KB region]
    const int tid = threadIdx.x;
    const int wave = tid >> 6, lane = tid & 63;
    const int l16 = lane & 15, quad = lane >> 4;
    const int wr = wave >> 2, wc = wave & 3;
    const int m0 = blockIdx.y * 256, n0 = blockIdx.x * 256;

    // staging source (inverse-swizzled): this thread fills chunk-local bytes [tid*16, +16)
    const int x = tid * 16;
    const int y0 = x ^ (((x >> 9) & 1) << 5);
    const int rowc = y0 >> 7;            // row within 64-row chunk
    const int cu = (y0 & 127) >> 1;      // u16 col offset within k-tile
    const int x2 = x >> 1;               // u16 dest index within chunk
    const u16* ptrR[4];
    ptrR[0] = A + (size_t)(m0 + rowc) * Kd + cu;
    ptrR[1] = A + (size_t)(m0 + 128 + rowc) * Kd + cu;
    ptrR[2] = Bt + (size_t)(n0 + rowc) * Kd + cu;
    ptrR[3] = Bt + (size_t)(n0 + 128 + rowc) * Kd + cu;

    auto STG = [&](int buf, int reg, int c, int kt) {
        async_ld16(&lds[buf][reg][c * 4096 + x2], ptrR[reg] + (size_t)c * 64 * Kd + kt * 64);
    };

    const f32x4 fz = {0.f, 0.f, 0.f, 0.f};
    f32x4 acc[8][4];
#pragma unroll
    for (int i = 0; i < 8; i++)
#pragma unroll
        for (int j = 0; j < 4; j++) acc[i][j] = fz;

    bf16x8 afr[2][2], bfr[4][2];
    auto LDB_ALL = [&](int buf) {
#pragma unroll
        for (int ni = 0; ni < 4; ni++)
#pragma unroll
            for (int ks = 0; ks < 2; ks++) {
                int y = ((wc & 1) * 64 + ni * 16 + l16) * 128 + ks * 64 + quad * 16;
                bfr[ni][ks] = *(const bf16x8*)&lds[buf][2 + (wc >> 1)][(y ^ (((y >> 9) & 1) << 5)) >> 1];
            }
    };
    auto LDA2 = [&](int buf, int mp) {
#pragma unroll
        for (int i = 0; i < 2; i++)
#pragma unroll
            for (int ks = 0; ks < 2; ks++) {
                int y = (mp * 32 + i * 16 + l16) * 128 + ks * 64 + quad * 16;
                afr[i][ks] = *(const bf16x8*)&lds[buf][wr][(y ^ (((y >> 9) & 1) << 5)) >> 1];
            }
    };
    auto MFMA2 = [&](int mp) {
        __builtin_amdgcn_s_setprio(1);
#pragma unroll
        for (int i = 0; i < 2; i++)
#pragma unroll
            for (int ni = 0; ni < 4; ni++)
#pragma unroll
                for (int ks = 0; ks < 2; ks++)
                    acc[mp * 2 + i][ni] = __builtin_amdgcn_mfma_f32_16x16x32_bf16(
                        afr[i][ks], bfr[ni][ks], acc[mp * 2 + i][ni], 0, 0, 0);
        __builtin_amdgcn_s_setprio(0);
    };

    // ---- prologue: E(kt0) fully + O(kt1) B-chunks & A?a (14 loads) ----
    STG(0, 2, 0, 0); STG(0, 2, 1, 0); STG(0, 3, 0, 0); STG(0, 3, 1, 0);
    STG(0, 0, 0, 0); STG(0, 1, 0, 0); STG(0, 0, 1, 0); STG(0, 1, 1, 0);
    STG(1, 2, 0, 1); STG(1, 2, 1, 1); STG(1, 3, 0, 1); STG(1, 3, 1, 1);
    STG(1, 0, 0, 1); STG(1, 1, 0, 1);
    asm volatile("s_waitcnt vmcnt(6)" ::: "memory");
    raw_barrier();

    const int NIT = Kd >> 7;   // 2 k-tiles (of 64) per iteration
    for (int j = 0; j < NIT; j++) {
        const int ktO = 2 * j + 1;
        const int ktE = (2 * j + 2) & (2 * NIT - 1);
        const int ktO2 = (2 * j + 3) & (2 * NIT - 1);
        // p1
        LDB_ALL(0); LDA2(0, 0); STG(1, 0, 1, ktO); STG(1, 1, 1, ktO);
        raw_barrier(); MFMA2(0); raw_barrier();
        // p2
        LDA2(0, 1); STG(0, 2, 0, ktE); STG(0, 2, 1, ktE);
        raw_barrier(); MFMA2(1); raw_barrier();
        // p3
        LDA2(0, 2); STG(0, 3, 0, ktE); STG(0, 3, 1, ktE);
        raw_barrier(); MFMA2(2); raw_barrier();
        // p4
        LDA2(0, 3); STG(0, 0, 0, ktE); STG(0, 1, 0, ktE);
        raw_barrier(); MFMA2(3);
        asm volatile("s_waitcnt vmcnt(6)" ::: "memory"); raw_barrier();
        // p5
        LDB_ALL(1); LDA2(1, 0); STG(0, 0, 1, ktE); STG(0, 1, 1, ktE);
        raw_barrier(); MFMA2(0); raw_barrier();
        // p6
        LDA2(1, 1); STG(1, 2, 0, ktO2); STG(1, 2, 1, ktO2);
        raw_barrier(); MFMA2(1); raw_barrier();
        // p7
        LDA2(1, 2); STG(1, 3, 0, ktO2); STG(1, 3, 1, ktO2);
        raw_barrier(); MFMA2(2); raw_barrier();
        // p8
        LDA2(1, 3); STG(1, 0, 0, ktO2); STG(1, 1, 0, ktO2);
        raw_barrier(); MFMA2(3);
        asm volatile("s_waitcnt vmcnt(6)" ::: "memory"); raw_barrier();
    }
    asm volatile("s_waitcnt vmcnt(0)" ::: "memory");

    // ---- epilogue ----
    if (mode == 1) {
#pragma unroll
        for (int am = 0; am < 8; am++)
#pragma unroll
            for (int ni = 0; ni < 4; ni++)
#pragma unroll
                for (int r = 0; r < 4; r++) {
                    int row = m0 + wr * 128 + am * 16 + quad * 4 + r;
                    int col = n0 + wc * 64 + ni * 16 + l16;
                    Cf[(size_t)row * N + col] = acc[am][ni][r];
                }
    } else if (n0 < 2048) {            // Q
#pragma unroll
        for (int am = 0; am < 8; am++)
#pragma unroll
            for (int ni = 0; ni < 4; ni++)
#pragma unroll
                for (int r = 0; r < 4; r++) {
                    int row = m0 + wr * 128 + am * 16 + quad * 4 + r;
                    int col = n0 + wc * 64 + ni * 16 + l16;
                    qb[(size_t)row * 2048 + col] = f2bf(acc[am][ni][r]);
                }
    } else if (n0 < 2560) {            // K
#pragma unroll
        for (int am = 0; am < 8; am++)
#pragma unroll
            for (int ni = 0; ni < 4; ni++)
#pragma unroll
                for (int r = 0; r < 4; r++) {
                    int row = m0 + wr * 128 + am * 16 + quad * 4 + r;
                    int col = n0 + wc * 64 + ni * 16 + l16 - 2048;
                    kb[(size_t)row * 512 + col] = f2bf(acc[am][ni][r]);
                }
    } else {                           // V -> Vt[b][g][d][t]
#pragma unroll
        for (int am = 0; am < 8; am++)
#pragma unroll
            for (int ni = 0; ni < 4; ni++) {
                int nv = n0 + wc * 64 + ni * 16 + l16 - 2560;
                int g = nv >> 7, d = nv & 127;
                int m = m0 + wr * 128 + am * 16 + quad * 4;
                int b = m >> 11, t = m & 2047;
                u16 r4[4];
#pragma unroll
                for (int r = 0; r < 4; r++) r4[r] = f2bf(acc[am][ni][r]);
                *(uint2*)&vtb[(((size_t)b * Gc + g) * Kc + d) * Tc + t] = *(uint2*)r4;
            }
    }
}

// ---------------- fused RMSNorm + RoPE, vectorized (u32 = 2 bf16 per lane) ----------------
__global__ __launch_bounds__(256) void rms_rope(u16* __restrict__ X,
                                                const float* __restrict__ sc,
                                                const int* __restrict__ pos, int NH,
                                                float smul) {
    int row = blockIdx.x * 4 + (threadIdx.x >> 6);   // one wave per (b,t,head) row
    int lane = threadIdx.x & 63;
    int bt = row / NH;
    u16* xp = X + (size_t)row * Kc;
    u32 w = *(const u32*)(xp + 2 * lane);
    float a0 = bf2f((u16)(w & 0xffffu)), a1 = bf2f((u16)(w >> 16));
    float ss = a0 * a0 + a1 * a1;
#pragma unroll
    for (int m = 1; m < 64; m <<= 1) ss += __shfl_xor(ss, m, 64);
    float rn = rsqrtf(ss * (1.f / 128.f) + EPSc) * smul;   // fold attn scale into q
    float2 scv = *(const float2*)(sc + 2 * lane);
    float y0 = a0 * rn * scv.x, y1 = a1 * rn * scv.y;
    float p0 = __shfl_xor(y0, 32, 64);   // rope partner's scaled value
    float p1 = __shfl_xor(y1, 32, 64);
    int j0 = (2 * lane) & 63;            // freq index (same for lane and partner)
    float pf = (float)pos[bt];
    const float nl2 = -0.20762050593046015f;   // -log2(10000)/64
    float inv0 = exp2f((float)j0 * nl2);
    float inv1 = exp2f((float)(j0 + 1) * nl2);
    float s0, c0, s1, c1;
    sincosf(pf * inv0, &s0, &c0);
    sincosf(pf * inv1, &s1, &c1);
    float sgn = (lane < 32) ? -1.f : 1.f;      // x1*c - x2*s  |  x2*c + x1*s
    float o0 = y0 * c0 + sgn * p0 * s0;
    float o1 = y1 * c1 + sgn * p1 * s1;
    u32 outw = (u32)f2bf(o0) | ((u32)f2bf(o1) << 16);
    *(u32*)(xp + 2 * lane) = outw;
}

// ---------------- flash attention: QBLK=128, swapped-QK^T, in-register softmax ----------------
// launch_bounds (256,2): DO NOT raise to (256,4) -- it forces VGPR<=~64 and the
// oc/qf/prefetch state (~130 regs) spills to scratch (r4: 800MB HBM traffic, 224us).
#define KSTR 136   // 128+8
#define VSTR 72    // 64+8

__global__ __launch_bounds__(256, 2) void flash_attn(const u16* __restrict__ Qb,
                                                     const u16* __restrict__ Kb,
                                                     const u16* __restrict__ Vt,
                                                     const int* __restrict__ seg,
                                                     const int* __restrict__ pos,
                                                     u16* __restrict__ Ob) {
    __shared__ __align__(16) u16 lK[64 * KSTR];
    __shared__ __align__(16) u16 lVt[128 * VSTR];   // V transposed: [d][s]
    __shared__ int lSeg[64];

    // XCD-aware + load-balanced decode: 1024 blocks = 8 xcd x (2 bg x 4 h x 16 q)
    const int lin = (int)blockIdx.x + 16 * ((int)blockIdx.y + 16 * (int)blockIdx.z);
    const int xcd = lin & 7, slot = lin >> 3;        // slot in [0,128)
    const int bg = xcd + 8 * (slot >> 6);            // [0,16)
    const int sub = slot & 63;
    const int b = bg >> 2, g = bg & 3;
    const int h = g * 4 + (sub >> 4);
    const int u = sub & 15;
    const int z = (u & 1) ? 15 - (u >> 1) : (u >> 1);   // zigzag: 0,15,1,14,...
    const int qi = (sub & 32) ? 15 - z : z;             // stride-32 flip
    const int q0 = qi * 128;
    const int tid = threadIdx.x;
    const int wave = tid >> 6, lane = tid & 63;
    const int l16 = lane & 15, quad = lane >> 4;

    bf16x8 qf[2][4];
#pragma unroll
    for (int gq = 0; gq < 2; gq++)
#pragma unroll
        for (int kk = 0; kk < 4; kk++)
            qf[gq][kk] = *(const bf16x8*)&Qb[((size_t)(b * Tc + q0 + gq * 64 + wave * 16 + l16) * Hc + h) * Kc + kk * 32 + quad * 8];

    int tg[2], sgt[2], ssg[2];
    bool segQ[2];
#pragma unroll
    for (int gq = 0; gq < 2; gq++) {
        tg[gq] = q0 + gq * 64 + wave * 16 + l16;
        sgt[gq] = seg[b * Tc + tg[gq]];
        segQ[gq] = (seg[b * Tc + q0 + gq * 64] == seg[b * Tc + q0 + gq * 64 + 63]);
        ssg[gq] = (q0 + gq * 64) - pos[b * Tc + q0 + gq * 64];   // exact segment starts
    }
    const int s_begin = (ssg[0] >> 6) << 6;   // tile-aligned (may include prev segment)

    float m_i[2] = {-1e30f, -1e30f}, l_i[2] = {0.f, 0.f};
    const f32x4 fz = {0.f, 0.f, 0.f, 0.f};
    f32x4 oc[2][8];   // O^T C-tiles per group
#pragma unroll
    for (int gq = 0; gq < 2; gq++)
#pragma unroll
        for (int i = 0; i < 8; i++) oc[gq][i] = fz;

    // bpermute source addrs for the P^T quad-redistribution
    const int addrA = (l16 + ((quad & 1) << 5)) << 2;   // m' = 0,1
    const int addrB = addrA + 64;                       // m' = 2,3
    const bool hiq = quad >= 2;

    // prefetch first K/V tile + seg row into registers
    uint4 kpre[4], vpre[4];
#pragma unroll
    for (int it = 0; it < 4; it++) {
        int c = tid + it * 256;
        kpre[it] = *(const uint4*)&Kb[((size_t)(b * Tc + s_begin + (c >> 4)) * Gc + g) * Kc + (c & 15) * 8];
        vpre[it] = *(const uint4*)&Vt[(((size_t)b * Gc + g) * Kc + (c >> 3)) * Tc + s_begin + (c & 7) * 8];
    }
    int segpre = (tid < 64) ? seg[b * Tc + s_begin + tid] : 0;

    const int s_end = q0 + 64;   // last tile covers group-B diagonal
    for (int s0 = s_begin; s0 <= s_end; s0 += 64) {
        sync_lgkm();   // prior iter's LDS reads complete (no vmcnt drain)
#pragma unroll
        for (int it = 0; it < 4; it++) {
            int c = tid + it * 256;
            *(uint4*)&lK[(c >> 4) * KSTR + (c & 15) * 8] = kpre[it];
        }
#pragma unroll
        for (int it = 0; it < 4; it++) {
            int c = tid + it * 256;
            *(uint4*)&lVt[(c >> 3) * VSTR + (c & 7) * 8] = vpre[it];
        }
        if (tid < 64) lSeg[tid] = segpre;
        if (s0 + 64 <= s_end) {   // prefetch next tile: stays in flight across barrier
#pragma unroll
            for (int it = 0; it < 4; it++) {
                int c = tid + it * 256;
                kpre[it] = *(const uint4*)&Kb[((size_t)(b * Tc + s0 + 64 + (c >> 4)) * Gc + g) * Kc + (c & 15) * 8];
                vpre[it] = *(const uint4*)&Vt[(((size_t)b * Gc + g) * Kc + (c >> 3)) * Tc + s0 + 64 + (c & 7) * 8];
            }
            if (tid < 64) segpre = seg[b * Tc + s0 + 64 + tid];
        }
        sync_lgkm();

        // S^T = K Q^T for both t-groups, sharing each bk read
        f32x4 sacc[2][4];
#pragma unroll
        for (int gq = 0; gq < 2; gq++)
#pragma unroll
            for (int mi = 0; mi < 4; mi++) sacc[gq][mi] = fz;
        __builtin_amdgcn_s_setprio(1);
#pragma unroll
        for (int kk = 0; kk < 4; kk++) {
#pragma unroll
            for (int mi = 0; mi < 4; mi++) {
                bf16x8 bk = *(const bf16x8*)&lK[(mi * 16 + l16) * KSTR + kk * 32 + quad * 8];
                sacc[0][mi] = __builtin_amdgcn_mfma_f32_16x16x32_bf16(bk, qf[0][kk], sacc[0][mi], 0, 0, 0);
                sacc[1][mi] = __builtin_amdgcn_mfma_f32_16x16x32_bf16(bk, qf[1][kk], sacc[1][mi], 0, 0, 0);
            }
        }
        __builtin_amdgcn_s_setprio(0);

        u32 W[2][4][2];
#pragma unroll
        for (int gq = 0; gq < 2; gq++) {
            const bool fast = segQ[gq] && (s0 >= ssg[gq]) && (s0 + 64 <= q0 + gq * 64);
            float rmax = -1e30f;
            if (fast) {
#pragma unroll
                for (int mi = 0; mi < 4; mi++)
#pragma unroll
                    for (int r = 0; r < 4; r++) rmax = fmaxf(rmax, sacc[gq][mi][r]);
            } else {
#pragma unroll
                for (int mi = 0; mi < 4; mi++) {
                    int sl = mi * 16 + quad * 4;
#pragma unroll
                    for (int r = 0; r < 4; r++) {
                        bool ok = (s0 + sl + r <= tg[gq]) && (lSeg[sl + r] == sgt[gq]);
                        float x = ok ? sacc[gq][mi][r] : -1e30f;
                        sacc[gq][mi][r] = x;
                        rmax = fmaxf(rmax, x);
                    }
                }
            }
            rmax = fmaxf(rmax, __shfl_xor(rmax, 16, 64));
            rmax = fmaxf(rmax, __shfl_xor(rmax, 32, 64));
            float mnew = fmaxf(m_i[gq], rmax);
            float alpha = __expf(m_i[gq] - mnew);
            m_i[gq] = mnew;
            float psum = 0.f;
#pragma unroll
            for (int mi = 0; mi < 4; mi++) {
                float p[4];
#pragma unroll
                for (int r = 0; r < 4; r++) {
                    float x = sacc[gq][mi][r];
                    p[r] = (x > -1e29f) ? __expf(x - m_i[gq]) : 0.f;
                    psum += p[r];
                }
                W[gq][mi][0] = cvt_pk_bf16(p[0], p[1]);
                W[gq][mi][1] = cvt_pk_bf16(p[2], p[3]);
            }
            psum += __shfl_xor(psum, 16, 64);
            psum += __shfl_xor(psum, 32, 64);
            l_i[gq] = l_i[gq] * alpha + psum;
#pragma unroll
            for (int ni = 0; ni < 8; ni++)
#pragma unroll
                for (int r = 0; r < 4; r++) oc[gq][ni][r] *= alpha;
        }

        // O^T += V^T P^T for both groups, sharing each av read
#pragma unroll
        for (int kk = 0; kk < 2; kk++) {
            bf16x8 bu[2];
#pragma unroll
            for (int gq = 0; gq < 2; gq++) {
                u32 w0a = (u32)__builtin_amdgcn_ds_bpermute(addrA, (int)W[gq][2 * kk][0]);
                u32 w0b = (u32)__builtin_amdgcn_ds_bpermute(addrA, (int)W[gq][2 * kk + 1][0]);
                u32 w1a = (u32)__builtin_amdgcn_ds_bpermute(addrA, (int)W[gq][2 * kk][1]);
                u32 w1b = (u32)__builtin_amdgcn_ds_bpermute(addrA, (int)W[gq][2 * kk + 1][1]);
                u32 w2a = (u32)__builtin_amdgcn_ds_bpermute(addrB, (int)W[gq][2 * kk][0]);
                u32 w2b = (u32)__builtin_amdgcn_ds_bpermute(addrB, (int)W[gq][2 * kk + 1][0]);
                u32 w3a = (u32)__builtin_amdgcn_ds_bpermute(addrB, (int)W[gq][2 * kk][1]);
                u32 w3b = (u32)__builtin_amdgcn_ds_bpermute(addrB, (int)W[gq][2 * kk + 1][1]);
                union { u32 w[4]; bf16x8 v; } uu;
                uu.w[0] = hiq ? w0b : w0a;
                uu.w[1] = hiq ? w1b : w1a;
                uu.w[2] = hiq ? w2b : w2a;
                uu.w[3] = hiq ? w3b : w3a;
                bu[gq] = uu.v;
            }
            __builtin_amdgcn_s_setprio(1);
#pragma unroll
            for (int ni = 0; ni < 8; ni++) {
                bf16x8 av = *(const bf16x8*)&lVt[(ni * 16 + l16) * VSTR + kk * 32 + quad * 8];
                oc[0][ni] = __builtin_amdgcn_mfma_f32_16x16x32_bf16(av, bu[0], oc[0][ni], 0, 0, 0);
                oc[1][ni] = __builtin_amdgcn_mfma_f32_16x16x32_bf16(av, bu[1], oc[1][ni], 0, 0, 0);
            }
            __builtin_amdgcn_s_setprio(0);
        }
    }

    // ---- epilogue: O^T -> O transpose via LDS (reuse lK for grpA, lVt for grpB) ----
    __syncthreads();
    float invl[2] = {1.f / l_i[0], 1.f / l_i[1]};
    const int tloc = wave * 16 + l16;
#pragma unroll
    for (int gq = 0; gq < 2; gq++) {
        u16* lO = gq ? (u16*)lVt : lK;   // both >= 64*KSTR u16
#pragma unroll
        for (int ni = 0; ni < 8; ni++) {
            u16 r4[4];
#pragma unroll
            for (int r = 0; r < 4; r++) r4[r] = f2bf(oc[gq][ni][r] * invl[gq]);
            *(uint2*)&lO[tloc * KSTR + ni * 16 + quad * 4] = *(uint2*)r4;
        }
    }
    __syncthreads();
#pragma unroll
    for (int gq = 0; gq < 2; gq++) {
        u16* lO = gq ? (u16*)lVt : lK;
#pragma unroll
        for (int j = 0; j < 4; j++) {
            int t2 = wave * 16 + j * 4 + quad;
            uint4 vv = *(const uint4*)&lO[t2 * KSTR + l16 * 8];
            *(uint4*)&Ob[((size_t)(b * Tc + q0 + gq * 64 + t2) * Hc + h) * Kc + l16 * 8] = vv;
        }
    }
}

extern "C" void kernel_launch(void* const* d_in, const int* in_sizes, int n_in,
                              void* d_out, int out_size, void* d_ws, size_t ws_size,
                              hipStream_t stream) {
    const float* hidden  = (const float*)d_in[0];
    const float* wq      = (const float*)d_in[1];
    const float* wk      = (const float*)d_in[2];
    const float* wv      = (const float*)d_in[3];
    const float* wo      = (const float*)d_in[4];
    const float* q_scale = (const float*)d_in[5];
    const float* k_scale = (const float*)d_in[6];
    const int*   segids  = (const int*)d_in[7];
    float* out = (float*)d_out;

    char* ws = (char*)d_ws;
    size_t off = 0;
    auto alloc = [&](size_t bytes) -> void* {
        void* p = ws + off;
        off += (bytes + 255) & ~(size_t)255;
        return p;
    };
    u16* hbf  = (u16*)alloc((size_t)Bc * Tc * Dc * 2);        // hidden bf16
    u16* wqT  = (u16*)alloc((size_t)Hc * Kc * Dc * 2);        // (2048 x 2048) \  adjacent:
    u16* wkT  = (u16*)alloc((size_t)Gc * Kc * Dc * 2);        // (512 x 2048)   } one 3072-row B^T
    u16* wvT  = (u16*)alloc((size_t)Gc * Kc * Dc * 2);        // (512 x 2048)  /
    u16* woT  = (u16*)alloc((size_t)Dc * Hc * Kc * 2);        // (2048 x 2048)
    u16* qb   = (u16*)alloc((size_t)Bc * Tc * Hc * Kc * 2);
    u16* kb   = (u16*)alloc((size_t)Bc * Tc * Gc * Kc * 2);
    u16* vtb  = (u16*)alloc((size_t)Bc * Gc * Kc * Tc * 2);   // V^T [b][g][d][t]
    u16* attn = (u16*)alloc((size_t)Bc * Tc * Hc * Kc * 2);
    int* posb = (int*)alloc((size_t)Bc * Tc * 4);
    (void)ws_size; (void)in_sizes; (void)n_in; (void)out_size;

    const int M = Bc * Tc;   // 8192
    const float qsc = 0.08838834764831845f;   // K^-0.5 folded into q rms_rope

    cvt_f2bf<<<(Bc * Tc * Dc) / 1024, 256, 0, stream>>>(hidden, hbf, Bc * Tc * Dc);
    transpose_f2bf<<<dim3(64, 64), 256, 0, stream>>>(wq, wqT, Dc, Hc * Kc);
    transpose_f2bf<<<dim3(16, 64), 256, 0, stream>>>(wk, wkT, Dc, Gc * Kc);
    transpose_f2bf<<<dim3(16, 64), 256, 0, stream>>>(wv, wvT, Dc, Gc * Kc);
    transpose_f2bf<<<dim3(64, 64), 256, 0, stream>>>(wo, woT, Hc * Kc, Dc);
    pos_kernel<<<(Bc * Tc) / 256, 256, 0, stream>>>(segids, posb);

    // merged Q+K+V projection: N = 3072 over adjacent [wqT; wkT; wvT] (256^2 8-phase)
    gemm256<<<dim3(3072 / 256, M / 256), 512, 0, stream>>>(hbf, wqT, nullptr, qb, kb, vtb, 3072, Dc, 0);

    rms_rope<<<(M * Hc) / 4, 256, 0, stream>>>(qb, q_scale, posb, Hc, qsc);
    rms_rope<<<(M * Gc) / 4, 256, 0, stream>>>(kb, k_scale, posb, Gc, 1.0f);

    flash_attn<<<dim3(Tc / 128, Hc, Bc), 256, 0, stream>>>(qb, kb, vtb, segids, posb, attn);

    // output projection: out = attn x woT^T (256^2 8-phase, float C)
    gemm256<<<dim3(Dc / 256, M / 256), 512, 0, stream>>>(attn, woT, out, nullptr, nullptr, nullptr, Dc, Hc * Kc, 1);
}

// Round 7
// 459.816 us; speedup vs baseline: 1.5100x; 1.1728x over previous
//
#include <hip/hip_runtime.h>

typedef unsigned short u16;
typedef unsigned int u32;
using f32x4 = __attribute__((ext_vector_type(4))) float;
using bf16x8 = __attribute__((ext_vector_type(8))) __bf16;

constexpr int Bc = 4, Tc = 2048, Dc = 2048, Hc = 16, Gc = 4, Kc = 128;
constexpr float EPSc = 1e-6f;

__device__ __forceinline__ u16 f2bf(float f) {
    u32 u = __float_as_uint(f);
    u = (u + 0x7fffu + ((u >> 16) & 1u)) >> 16;
    return (u16)u;
}
__device__ __forceinline__ float bf2f(u16 h) {
    return __uint_as_float(((u32)h) << 16);
}

// async global->LDS, 16B per lane; LDS dest must be wave-uniform base + lane*16
__device__ __forceinline__ void async_ld16(void* lds, const void* g) {
    __builtin_amdgcn_global_load_lds(
        (const __attribute__((address_space(1))) unsigned int*)g,
        (__attribute__((address_space(3))) unsigned int*)lds, 16, 0, 0);
}

__device__ __forceinline__ void raw_barrier() {
    asm volatile("" ::: "memory");
    __builtin_amdgcn_s_barrier();
    asm volatile("" ::: "memory");
}

__device__ __forceinline__ u32 cvt_pk_bf16(float lo, float hi) {
    u32 r;
    asm("v_cvt_pk_bf16_f32 %0, %1, %2" : "=v"(r) : "v"(lo), "v"(hi));
    return r;
}

// ---------------- fp32 -> bf16 convert ----------------
__global__ __launch_bounds__(256) void cvt_f2bf(const float* __restrict__ in,
                                                u16* __restrict__ out, int n) {
    int i = (blockIdx.x * 256 + threadIdx.x) * 4;
    if (i >= n) return;
    float4 f = *(const float4*)(in + i);
    u16 r[4] = { f2bf(f.x), f2bf(f.y), f2bf(f.z), f2bf(f.w) };
    *(uint2*)(out + i) = *(uint2*)r;
}

// ------- transpose+convert: in (rows x cols) f32 -> out (cols x rows) bf16 -------
__global__ __launch_bounds__(256) void transpose_f2bf(const float* __restrict__ in,
                                                      u16* __restrict__ out,
                                                      int rows, int cols) {
    __shared__ float tile[32][33];
    int tx = threadIdx.x & 31, ty = threadIdx.x >> 5;
    int c0 = blockIdx.x * 32, r0 = blockIdx.y * 32;
#pragma unroll
    for (int j = 0; j < 4; j++)
        tile[ty + j * 8][tx] = in[(size_t)(r0 + ty + j * 8) * cols + c0 + tx];
    __syncthreads();
#pragma unroll
    for (int j = 0; j < 4; j++)
        out[(size_t)(c0 + ty + j * 8) * rows + r0 + tx] = f2bf(tile[tx][ty + j * 8]);
}

// ---------------- positions from (sorted) segment ids ----------------
__global__ void pos_kernel(const int* __restrict__ seg, int* __restrict__ pos) {
    int idx = blockIdx.x * 256 + threadIdx.x;
    if (idx >= Bc * Tc) return;
    int b = idx / Tc, t = idx - b * Tc;
    const int* s = seg + b * Tc;
    int v = s[t];
    int lo = 0, hi = t;
    while (lo < hi) { int mid = (lo + hi) >> 1; if (s[mid] < v) lo = mid + 1; else hi = mid; }
    pos[idx] = t - lo;   // t - seg_start
}

// ======== 256x256 8-phase GEMM (m201 structure): C(MxN) = A(MxKd)*Bt(NxKd)^T ========
__global__ __launch_bounds__(512, 1) void gemm256(const u16* __restrict__ A,
                                                  const u16* __restrict__ Bt,
                                                  float* __restrict__ Cf,
                                                  u16* __restrict__ qb, u16* __restrict__ kb,
                                                  u16* __restrict__ vtb,
                                                  int N, int Kd, int mode) {
    __shared__ __align__(16) u16 lds[2][4][8192];   // [buf][A0,A1,B0,B1][16KB region]
    const int tid = threadIdx.x;
    const int wave = tid >> 6, lane = tid & 63;
    const int l16 = lane & 15, quad = lane >> 4;
    const int wr = wave >> 2, wc = wave & 3;
    const int m0 = blockIdx.y * 256, n0 = blockIdx.x * 256;

    // staging source (inverse-swizzled): this thread fills chunk-local bytes [tid*16, +16)
    const int x = tid * 16;
    const int y0 = x ^ (((x >> 9) & 1) << 5);
    const int rowc = y0 >> 7;            // row within 64-row chunk
    const int cu = (y0 & 127) >> 1;      // u16 col offset within k-tile
    const int x2 = x >> 1;               // u16 dest index within chunk
    const u16* ptrR[4];
    ptrR[0] = A + (size_t)(m0 + rowc) * Kd + cu;
    ptrR[1] = A + (size_t)(m0 + 128 + rowc) * Kd + cu;
    ptrR[2] = Bt + (size_t)(n0 + rowc) * Kd + cu;
    ptrR[3] = Bt + (size_t)(n0 + 128 + rowc) * Kd + cu;

    auto STG = [&](int buf, int reg, int c, int kt) {
        async_ld16(&lds[buf][reg][c * 4096 + x2], ptrR[reg] + (size_t)c * 64 * Kd + kt * 64);
    };

    const f32x4 fz = {0.f, 0.f, 0.f, 0.f};
    f32x4 acc[8][4];
#pragma unroll
    for (int i = 0; i < 8; i++)
#pragma unroll
        for (int j = 0; j < 4; j++) acc[i][j] = fz;

    bf16x8 afr[2][2], bfr[4][2];
    auto LDB_ALL = [&](int buf) {
#pragma unroll
        for (int ni = 0; ni < 4; ni++)
#pragma unroll
            for (int ks = 0; ks < 2; ks++) {
                int y = ((wc & 1) * 64 + ni * 16 + l16) * 128 + ks * 64 + quad * 16;
                bfr[ni][ks] = *(const bf16x8*)&lds[buf][2 + (wc >> 1)][(y ^ (((y >> 9) & 1) << 5)) >> 1];
            }
    };
    auto LDA2 = [&](int buf, int mp) {
#pragma unroll
        for (int i = 0; i < 2; i++)
#pragma unroll
            for (int ks = 0; ks < 2; ks++) {
                int y = (mp * 32 + i * 16 + l16) * 128 + ks * 64 + quad * 16;
                afr[i][ks] = *(const bf16x8*)&lds[buf][wr][(y ^ (((y >> 9) & 1) << 5)) >> 1];
            }
    };
    auto MFMA2 = [&](int mp) {
        __builtin_amdgcn_s_setprio(1);
#pragma unroll
        for (int i = 0; i < 2; i++)
#pragma unroll
            for (int ni = 0; ni < 4; ni++)
#pragma unroll
                for (int ks = 0; ks < 2; ks++)
                    acc[mp * 2 + i][ni] = __builtin_amdgcn_mfma_f32_16x16x32_bf16(
                        afr[i][ks], bfr[ni][ks], acc[mp * 2 + i][ni], 0, 0, 0);
        __builtin_amdgcn_s_setprio(0);
    };

    // ---- prologue: E(kt0) fully + O(kt1) B-chunks & A?a (14 loads) ----
    STG(0, 2, 0, 0); STG(0, 2, 1, 0); STG(0, 3, 0, 0); STG(0, 3, 1, 0);
    STG(0, 0, 0, 0); STG(0, 1, 0, 0); STG(0, 0, 1, 0); STG(0, 1, 1, 0);
    STG(1, 2, 0, 1); STG(1, 2, 1, 1); STG(1, 3, 0, 1); STG(1, 3, 1, 1);
    STG(1, 0, 0, 1); STG(1, 1, 0, 1);
    asm volatile("s_waitcnt vmcnt(6)" ::: "memory");
    raw_barrier();

    const int NIT = Kd >> 7;   // 2 k-tiles (of 64) per iteration
    for (int j = 0; j < NIT; j++) {
        const int ktO = 2 * j + 1;
        const int ktE = (2 * j + 2) & (2 * NIT - 1);
        const int ktO2 = (2 * j + 3) & (2 * NIT - 1);
        // p1
        LDB_ALL(0); LDA2(0, 0); STG(1, 0, 1, ktO); STG(1, 1, 1, ktO);
        raw_barrier(); MFMA2(0); raw_barrier();
        // p2
        LDA2(0, 1); STG(0, 2, 0, ktE); STG(0, 2, 1, ktE);
        raw_barrier(); MFMA2(1); raw_barrier();
        // p3
        LDA2(0, 2); STG(0, 3, 0, ktE); STG(0, 3, 1, ktE);
        raw_barrier(); MFMA2(2); raw_barrier();
        // p4
        LDA2(0, 3); STG(0, 0, 0, ktE); STG(0, 1, 0, ktE);
        raw_barrier(); MFMA2(3);
        asm volatile("s_waitcnt vmcnt(6)" ::: "memory"); raw_barrier();
        // p5
        LDB_ALL(1); LDA2(1, 0); STG(0, 0, 1, ktE); STG(0, 1, 1, ktE);
        raw_barrier(); MFMA2(0); raw_barrier();
        // p6
        LDA2(1, 1); STG(1, 2, 0, ktO2); STG(1, 2, 1, ktO2);
        raw_barrier(); MFMA2(1); raw_barrier();
        // p7
        LDA2(1, 2); STG(1, 3, 0, ktO2); STG(1, 3, 1, ktO2);
        raw_barrier(); MFMA2(2); raw_barrier();
        // p8
        LDA2(1, 3); STG(1, 0, 0, ktO2); STG(1, 1, 0, ktO2);
        raw_barrier(); MFMA2(3);
        asm volatile("s_waitcnt vmcnt(6)" ::: "memory"); raw_barrier();
    }
    asm volatile("s_waitcnt vmcnt(0)" ::: "memory");

    // ---- epilogue ----
    if (mode == 1) {
#pragma unroll
        for (int am = 0; am < 8; am++)
#pragma unroll
            for (int ni = 0; ni < 4; ni++)
#pragma unroll
                for (int r = 0; r < 4; r++) {
                    int row = m0 + wr * 128 + am * 16 + quad * 4 + r;
                    int col = n0 + wc * 64 + ni * 16 + l16;
                    Cf[(size_t)row * N + col] = acc[am][ni][r];
                }
    } else if (n0 < 2048) {            // Q
#pragma unroll
        for (int am = 0; am < 8; am++)
#pragma unroll
            for (int ni = 0; ni < 4; ni++)
#pragma unroll
                for (int r = 0; r < 4; r++) {
                    int row = m0 + wr * 128 + am * 16 + quad * 4 + r;
                    int col = n0 + wc * 64 + ni * 16 + l16;
                    qb[(size_t)row * 2048 + col] = f2bf(acc[am][ni][r]);
                }
    } else if (n0 < 2560) {            // K
#pragma unroll
        for (int am = 0; am < 8; am++)
#pragma unroll
            for (int ni = 0; ni < 4; ni++)
#pragma unroll
                for (int r = 0; r < 4; r++) {
                    int row = m0 + wr * 128 + am * 16 + quad * 4 + r;
                    int col = n0 + wc * 64 + ni * 16 + l16 - 2048;
                    kb[(size_t)row * 512 + col] = f2bf(acc[am][ni][r]);
                }
    } else {                           // V -> Vt[b][g][d][t]
#pragma unroll
        for (int am = 0; am < 8; am++)
#pragma unroll
            for (int ni = 0; ni < 4; ni++) {
                int nv = n0 + wc * 64 + ni * 16 + l16 - 2560;
                int g = nv >> 7, d = nv & 127;
                int m = m0 + wr * 128 + am * 16 + quad * 4;
                int b = m >> 11, t = m & 2047;
                u16 r4[4];
#pragma unroll
                for (int r = 0; r < 4; r++) r4[r] = f2bf(acc[am][ni][r]);
                *(uint2*)&vtb[(((size_t)b * Gc + g) * Kc + d) * Tc + t] = *(uint2*)r4;
            }
    }
}

// ---------------- fused RMSNorm + RoPE, vectorized (u32 = 2 bf16 per lane) ----------------
__global__ __launch_bounds__(256) void rms_rope(u16* __restrict__ X,
                                                const float* __restrict__ sc,
                                                const int* __restrict__ pos, int NH,
                                                float smul) {
    int row = blockIdx.x * 4 + (threadIdx.x >> 6);   // one wave per (b,t,head) row
    int lane = threadIdx.x & 63;
    int bt = row / NH;
    u16* xp = X + (size_t)row * Kc;
    u32 w = *(const u32*)(xp + 2 * lane);
    float a0 = bf2f((u16)(w & 0xffffu)), a1 = bf2f((u16)(w >> 16));
    float ss = a0 * a0 + a1 * a1;
#pragma unroll
    for (int m = 1; m < 64; m <<= 1) ss += __shfl_xor(ss, m, 64);
    float rn = rsqrtf(ss * (1.f / 128.f) + EPSc) * smul;   // fold attn scale into q
    float2 scv = *(const float2*)(sc + 2 * lane);
    float y0 = a0 * rn * scv.x, y1 = a1 * rn * scv.y;
    float p0 = __shfl_xor(y0, 32, 64);   // rope partner's scaled value
    float p1 = __shfl_xor(y1, 32, 64);
    int j0 = (2 * lane) & 63;            // freq index (same for lane and partner)
    float pf = (float)pos[bt];
    const float nl2 = -0.20762050593046015f;   // -log2(10000)/64
    float inv0 = exp2f((float)j0 * nl2);
    float inv1 = exp2f((float)(j0 + 1) * nl2);
    float s0, c0, s1, c1;
    sincosf(pf * inv0, &s0, &c0);
    sincosf(pf * inv1, &s1, &c1);
    float sgn = (lane < 32) ? -1.f : 1.f;      // x1*c - x2*s  |  x2*c + x1*s
    float o0 = y0 * c0 + sgn * p0 * s0;
    float o1 = y1 * c1 + sgn * p1 * s1;
    u32 outw = (u32)f2bf(o0) | ((u32)f2bf(o1) << 16);
    *(u32*)(xp + 2 * lane) = outw;
}

// ---------------- flash attention v2: gload_lds double-buffer, 1 barrier/tile ----------------
// QBLK=128 (2 t-groups/wave), swapped-QK^T, in-register softmax, defer-max (THR=8).
// K[64][128] and V^T[128][64] staged DIRECTLY via global_load_lds into double
// buffers; XOR-swizzle (byte ^= (row&7)<<4) via inverse-swizzled global SOURCE +
// swizzled ds_read (linear LDS dest as gload_lds requires). Masking needs no seg
// reads: seg sorted => same_seg(s,t) && s<=t  <=>  tstart(t) <= s <= t.
// Per tile: vmcnt(0) on loads issued a full tile earlier + ONE barrier.
__global__ __launch_bounds__(256, 2) void flash_attn(const u16* __restrict__ Qb,
                                                     const u16* __restrict__ Kb,
                                                     const u16* __restrict__ Vt,
                                                     const int* __restrict__ pos,
                                                     u16* __restrict__ Ob) {
    __shared__ __align__(16) u16 lK[2][64 * 128];
    __shared__ __align__(16) u16 lVt[2][128 * 64];   // [d][s] swizzled

    // XCD-aware + load-balanced decode: 1024 blocks = 8 xcd x (2 bg x 4 h x 16 q)
    const int lin = (int)blockIdx.x + 16 * ((int)blockIdx.y + 16 * (int)blockIdx.z);
    const int xcd = lin & 7, slot = lin >> 3;        // slot in [0,128)
    const int bg = xcd + 8 * (slot >> 6);            // [0,16)
    const int sub = slot & 63;
    const int b = bg >> 2, g = bg & 3;
    const int h = g * 4 + (sub >> 4);
    const int u = sub & 15;
    const int z = (u & 1) ? 15 - (u >> 1) : (u >> 1);   // zigzag: 0,15,1,14,...
    const int qi = (sub & 32) ? 15 - z : z;             // stride-32 flip
    const int q0 = qi * 128;
    const int tid = threadIdx.x;
    const int wave = tid >> 6, lane = tid & 63;
    const int l16 = lane & 15, quad = lane >> 4;

    bf16x8 qf[2][4];
#pragma unroll
    for (int gq = 0; gq < 2; gq++)
#pragma unroll
        for (int kk = 0; kk < 4; kk++)
            qf[gq][kk] = *(const bf16x8*)&Qb[((size_t)(b * Tc + q0 + gq * 64 + wave * 16 + l16) * Hc + h) * Kc + kk * 32 + quad * 8];

    int tg[2], tstart[2], tsmax[2];
#pragma unroll
    for (int gq = 0; gq < 2; gq++) {
        tg[gq] = q0 + gq * 64 + wave * 16 + l16;
        tstart[gq] = tg[gq] - pos[b * Tc + tg[gq]];
        int v = tstart[gq];   // wave-max over the 16 rows (l16 lanes)
        v = max(v, __shfl_xor(v, 1, 64));
        v = max(v, __shfl_xor(v, 2, 64));
        v = max(v, __shfl_xor(v, 4, 64));
        v = max(v, __shfl_xor(v, 8, 64));
        tsmax[gq] = v;
    }
    const int s_begin = ((q0 - pos[b * Tc + q0]) >> 6) << 6;

    // staging source pointers (inverse-swizzled). Per thread, 4 K + 4 V chunks.
    // K chunk i: dest bytes x = i*4096 + tid*16 -> row=x>>8, colb=(x&255)^((row&7)<<4)
    const u16* pK[4];
    const u16* pV[4];
#pragma unroll
    for (int i = 0; i < 4; i++) {
        int rowK = i * 16 + (tid >> 4);
        int cbK = ((tid & 15) * 16) ^ ((rowK & 7) << 4);
        pK[i] = Kb + ((size_t)(b * Tc + rowK) * Gc + g) * Kc + (cbK >> 1);
        int dV = i * 32 + (tid >> 3);
        int cbV = ((tid & 7) * 16) ^ ((dV & 7) << 4);
        pV[i] = Vt + (((size_t)b * Gc + g) * Kc + dV) * Tc + (cbV >> 1);
    }
    const int x2 = tid * 8;   // u16 dest idx within 4KB chunk region

    auto STAGE = [&](int buf, int s0) {
#pragma unroll
        for (int i = 0; i < 4; i++)
            async_ld16(&lK[buf][i * 2048 + x2], pK[i] + (size_t)s0 * (Gc * Kc));
#pragma unroll
        for (int i = 0; i < 4; i++)
            async_ld16(&lVt[buf][i * 2048 + x2], pV[i] + s0);
    };

    float m_i[2] = {-1e30f, -1e30f}, l_i[2] = {0.f, 0.f};
    const f32x4 fz = {0.f, 0.f, 0.f, 0.f};
    f32x4 oc[2][8];
#pragma unroll
    for (int gq = 0; gq < 2; gq++)
#pragma unroll
        for (int i = 0; i < 8; i++) oc[gq][i] = fz;

    // bpermute source addrs for the P^T quad-redistribution
    const int addrA = (l16 + ((quad & 1) << 5)) << 2;   // m' = 0,1
    const int addrB = addrA + 64;                       // m' = 2,3
    const bool hiq = quad >= 2;

    STAGE(0, s_begin);   // prologue

    const int s_end = q0 + 64;
    int buf = 0;
    for (int s0 = s_begin; s0 <= s_end; s0 += 64, buf ^= 1) {
        asm volatile("s_waitcnt vmcnt(0)" ::: "memory");   // this tile's loads landed
        raw_barrier();                                      // ... in all waves
        if (s0 + 64 <= s_end) STAGE(buf ^ 1, s0 + 64);      // next tile (post-barrier: WAR-safe)

        // S^T = K Q^T for both t-groups, sharing each bk read
        f32x4 sacc[2][4];
#pragma unroll
        for (int gq = 0; gq < 2; gq++)
#pragma unroll
            for (int mi = 0; mi < 4; mi++) sacc[gq][mi] = fz;
        __builtin_amdgcn_s_setprio(1);
#pragma unroll
        for (int kk = 0; kk < 4; kk++) {
#pragma unroll
            for (int mi = 0; mi < 4; mi++) {
                int row = mi * 16 + l16;
                int byt = row * 256 + ((kk * 64 + quad * 16) ^ ((row & 7) << 4));
                bf16x8 bk = *(const bf16x8*)&lK[buf][byt >> 1];
                sacc[0][mi] = __builtin_amdgcn_mfma_f32_16x16x32_bf16(bk, qf[0][kk], sacc[0][mi], 0, 0, 0);
                sacc[1][mi] = __builtin_amdgcn_mfma_f32_16x16x32_bf16(bk, qf[1][kk], sacc[1][mi], 0, 0, 0);
            }
        }
        __builtin_amdgcn_s_setprio(0);

        u32 W[2][4][2];
#pragma unroll
        for (int gq = 0; gq < 2; gq++) {
            const bool fast = (s0 >= tsmax[gq]) && (s0 + 64 <= q0 + gq * 64);
            float rmax = -1e30f;
            if (fast) {
#pragma unroll
                for (int mi = 0; mi < 4; mi++)
#pragma unroll
                    for (int r = 0; r < 4; r++) rmax = fmaxf(rmax, sacc[gq][mi][r]);
            } else {
#pragma unroll
                for (int mi = 0; mi < 4; mi++) {
                    int sl = s0 + mi * 16 + quad * 4;
#pragma unroll
                    for (int r = 0; r < 4; r++) {
                        bool ok = (sl + r <= tg[gq]) && (sl + r >= tstart[gq]);
                        float x = ok ? sacc[gq][mi][r] : -1e30f;
                        sacc[gq][mi][r] = x;
                        rmax = fmaxf(rmax, x);
                    }
                }
            }
            rmax = fmaxf(rmax, __shfl_xor(rmax, 16, 64));
            rmax = fmaxf(rmax, __shfl_xor(rmax, 32, 64));

            // defer-max: only rescale when some row's max grew past m + THR
            if (!__all(rmax <= m_i[gq] + 8.f)) {
                float mnew = fmaxf(m_i[gq], rmax);
                float alpha = __expf(m_i[gq] - mnew);
                m_i[gq] = mnew;
                l_i[gq] *= alpha;
#pragma unroll
                for (int ni = 0; ni < 8; ni++)
#pragma unroll
                    for (int r = 0; r < 4; r++) oc[gq][ni][r] *= alpha;
            }
            float psum = 0.f;
#pragma unroll
            for (int mi = 0; mi < 4; mi++) {
                float p[4];
#pragma unroll
                for (int r = 0; r < 4; r++) {
                    float x = sacc[gq][mi][r];
                    p[r] = (x > -1e29f) ? __expf(x - m_i[gq]) : 0.f;
                    psum += p[r];
                }
                W[gq][mi][0] = cvt_pk_bf16(p[0], p[1]);
                W[gq][mi][1] = cvt_pk_bf16(p[2], p[3]);
            }
            psum += __shfl_xor(psum, 16, 64);
            psum += __shfl_xor(psum, 32, 64);
            l_i[gq] += psum;
        }

        // O^T += V^T P^T for both groups, sharing each av read
#pragma unroll
        for (int kk = 0; kk < 2; kk++) {
            bf16x8 bu[2];
#pragma unroll
            for (int gq = 0; gq < 2; gq++) {
                u32 w0a = (u32)__builtin_amdgcn_ds_bpermute(addrA, (int)W[gq][2 * kk][0]);
                u32 w0b = (u32)__builtin_amdgcn_ds_bpermute(addrA, (int)W[gq][2 * kk + 1][0]);
                u32 w1a = (u32)__builtin_amdgcn_ds_bpermute(addrA, (int)W[gq][2 * kk][1]);
                u32 w1b = (u32)__builtin_amdgcn_ds_bpermute(addrA, (int)W[gq][2 * kk + 1][1]);
                u32 w2a = (u32)__builtin_amdgcn_ds_bpermute(addrB, (int)W[gq][2 * kk][0]);
                u32 w2b = (u32)__builtin_amdgcn_ds_bpermute(addrB, (int)W[gq][2 * kk + 1][0]);
                u32 w3a = (u32)__builtin_amdgcn_ds_bpermute(addrB, (int)W[gq][2 * kk][1]);
                u32 w3b = (u32)__builtin_amdgcn_ds_bpermute(addrB, (int)W[gq][2 * kk + 1][1]);
                union { u32 w[4]; bf16x8 v; } uu;
                uu.w[0] = hiq ? w0b : w0a;
                uu.w[1] = hiq ? w1b : w1a;
                uu.w[2] = hiq ? w2b : w2a;
                uu.w[3] = hiq ? w3b : w3a;
                bu[gq] = uu.v;
            }
            __builtin_amdgcn_s_setprio(1);
#pragma unroll
            for (int ni = 0; ni < 8; ni++) {
                int d = ni * 16 + l16;
                int byt = d * 128 + ((kk * 64 + quad * 16) ^ ((d & 7) << 4));
                bf16x8 av = *(const bf16x8*)&lVt[buf][byt >> 1];
                oc[0][ni] = __builtin_amdgcn_mfma_f32_16x16x32_bf16(av, bu[0], oc[0][ni], 0, 0, 0);
                oc[1][ni] = __builtin_amdgcn_mfma_f32_16x16x32_bf16(av, bu[1], oc[1][ni], 0, 0, 0);
            }
            __builtin_amdgcn_s_setprio(0);
        }
    }

    // ---- epilogue: O^T -> O transpose via LDS (reuse lK for grpA, lVt for grpB) ----
#define KSTR 136
    __syncthreads();
    float invl[2] = {1.f / l_i[0], 1.f / l_i[1]};
    const int tloc = wave * 16 + l16;
#pragma unroll
    for (int gq = 0; gq < 2; gq++) {
        u16* lO = gq ? (u16*)lVt : (u16*)lK;   // each region is 16384 u16 >= 64*KSTR
#pragma unroll
        for (int ni = 0; ni < 8; ni++) {
            u16 r4[4];
#pragma unroll
            for (int r = 0; r < 4; r++) r4[r] = f2bf(oc[gq][ni][r] * invl[gq]);
            *(uint2*)&lO[tloc * KSTR + ni * 16 + quad * 4] = *(uint2*)r4;
        }
    }
    __syncthreads();
#pragma unroll
    for (int gq = 0; gq < 2; gq++) {
        u16* lO = gq ? (u16*)lVt : (u16*)lK;
#pragma unroll
        for (int j = 0; j < 4; j++) {
            int t2 = wave * 16 + j * 4 + quad;
            uint4 vv = *(const uint4*)&lO[t2 * KSTR + l16 * 8];
            *(uint4*)&Ob[((size_t)(b * Tc + q0 + gq * 64 + t2) * Hc + h) * Kc + l16 * 8] = vv;
        }
    }
}

extern "C" void kernel_launch(void* const* d_in, const int* in_sizes, int n_in,
                              void* d_out, int out_size, void* d_ws, size_t ws_size,
                              hipStream_t stream) {
    const float* hidden  = (const float*)d_in[0];
    const float* wq      = (const float*)d_in[1];
    const float* wk      = (const float*)d_in[2];
    const float* wv      = (const float*)d_in[3];
    const float* wo      = (const float*)d_in[4];
    const float* q_scale = (const float*)d_in[5];
    const float* k_scale = (const float*)d_in[6];
    const int*   segids  = (const int*)d_in[7];
    float* out = (float*)d_out;

    char* ws = (char*)d_ws;
    size_t off = 0;
    auto alloc = [&](size_t bytes) -> void* {
        void* p = ws + off;
        off += (bytes + 255) & ~(size_t)255;
        return p;
    };
    u16* hbf  = (u16*)alloc((size_t)Bc * Tc * Dc * 2);        // hidden bf16
    u16* wqT  = (u16*)alloc((size_t)Hc * Kc * Dc * 2);        // (2048 x 2048) \  adjacent:
    u16* wkT  = (u16*)alloc((size_t)Gc * Kc * Dc * 2);        // (512 x 2048)   } one 3072-row B^T
    u16* wvT  = (u16*)alloc((size_t)Gc * Kc * Dc * 2);        // (512 x 2048)  /
    u16* woT  = (u16*)alloc((size_t)Dc * Hc * Kc * 2);        // (2048 x 2048)
    u16* qb   = (u16*)alloc((size_t)Bc * Tc * Hc * Kc * 2);
    u16* kb   = (u16*)alloc((size_t)Bc * Tc * Gc * Kc * 2);
    u16* vtb  = (u16*)alloc((size_t)Bc * Gc * Kc * Tc * 2);   // V^T [b][g][d][t]
    u16* attn = (u16*)alloc((size_t)Bc * Tc * Hc * Kc * 2);
    int* posb = (int*)alloc((size_t)Bc * Tc * 4);
    (void)ws_size; (void)in_sizes; (void)n_in; (void)out_size;

    const int M = Bc * Tc;   // 8192
    const float qsc = 0.08838834764831845f;   // K^-0.5 folded into q rms_rope

    cvt_f2bf<<<(Bc * Tc * Dc) / 1024, 256, 0, stream>>>(hidden, hbf, Bc * Tc * Dc);
    transpose_f2bf<<<dim3(64, 64), 256, 0, stream>>>(wq, wqT, Dc, Hc * Kc);
    transpose_f2bf<<<dim3(16, 64), 256, 0, stream>>>(wk, wkT, Dc, Gc * Kc);
    transpose_f2bf<<<dim3(16, 64), 256, 0, stream>>>(wv, wvT, Dc, Gc * Kc);
    transpose_f2bf<<<dim3(64, 64), 256, 0, stream>>>(wo, woT, Hc * Kc, Dc);
    pos_kernel<<<(Bc * Tc) / 256, 256, 0, stream>>>(segids, posb);

    // merged Q+K+V projection: N = 3072 over adjacent [wqT; wkT; wvT] (256^2 8-phase)
    gemm256<<<dim3(3072 / 256, M / 256), 512, 0, stream>>>(hbf, wqT, nullptr, qb, kb, vtb, 3072, Dc, 0);

    rms_rope<<<(M * Hc) / 4, 256, 0, stream>>>(qb, q_scale, posb, Hc, qsc);
    rms_rope<<<(M * Gc) / 4, 256, 0, stream>>>(kb, k_scale, posb, Gc, 1.0f);

    flash_attn<<<dim3(Tc / 128, Hc, Bc), 256, 0, stream>>>(qb, kb, vtb, posb, attn);

    // output projection: out = attn x woT^T (256^2 8-phase, float C)
    gemm256<<<dim3(Dc / 256, M / 256), 512, 0, stream>>>(attn, woT, out, nullptr, nullptr, nullptr, Dc, Hc * Kc, 1);
}

// Round 8
// 438.120 us; speedup vs baseline: 1.5848x; 1.0495x over previous
//
#include <hip/hip_runtime.h>

typedef unsigned short u16;
typedef unsigned int u32;
using f32x4 = __attribute__((ext_vector_type(4))) float;
using bf16x8 = __attribute__((ext_vector_type(8))) __bf16;

constexpr int Bc = 4, Tc = 2048, Dc = 2048, Hc = 16, Gc = 4, Kc = 128;
constexpr float EPSc = 1e-6f;

__device__ __forceinline__ u16 f2bf(float f) {
    u32 u = __float_as_uint(f);
    u = (u + 0x7fffu + ((u >> 16) & 1u)) >> 16;
    return (u16)u;
}
__device__ __forceinline__ float bf2f(u16 h) {
    return __uint_as_float(((u32)h) << 16);
}

// async global->LDS, 16B per lane; LDS dest must be wave-uniform base + lane*16
__device__ __forceinline__ void async_ld16(void* lds, const void* g) {
    __builtin_amdgcn_global_load_lds(
        (const __attribute__((address_space(1))) unsigned int*)g,
        (__attribute__((address_space(3))) unsigned int*)lds, 16, 0, 0);
}

__device__ __forceinline__ void raw_barrier() {
    asm volatile("" ::: "memory");
    __builtin_amdgcn_s_barrier();
    asm volatile("" ::: "memory");
}

__device__ __forceinline__ u32 cvt_pk_bf16(float lo, float hi) {
    u32 r;
    asm("v_cvt_pk_bf16_f32 %0, %1, %2" : "=v"(r) : "v"(lo), "v"(hi));
    return r;
}

// ---------------- fp32 -> bf16 convert ----------------
__global__ __launch_bounds__(256) void cvt_f2bf(const float* __restrict__ in,
                                                u16* __restrict__ out, int n) {
    int i = (blockIdx.x * 256 + threadIdx.x) * 4;
    if (i >= n) return;
    float4 f = *(const float4*)(in + i);
    u16 r[4] = { f2bf(f.x), f2bf(f.y), f2bf(f.z), f2bf(f.w) };
    *(uint2*)(out + i) = *(uint2*)r;
}

// ------- transpose+convert: in (rows x cols) f32 -> out (cols x rows) bf16 -------
__global__ __launch_bounds__(256) void transpose_f2bf(const float* __restrict__ in,
                                                      u16* __restrict__ out,
                                                      int rows, int cols) {
    __shared__ float tile[32][33];
    int tx = threadIdx.x & 31, ty = threadIdx.x >> 5;
    int c0 = blockIdx.x * 32, r0 = blockIdx.y * 32;
#pragma unroll
    for (int j = 0; j < 4; j++)
        tile[ty + j * 8][tx] = in[(size_t)(r0 + ty + j * 8) * cols + c0 + tx];
    __syncthreads();
#pragma unroll
    for (int j = 0; j < 4; j++)
        out[(size_t)(c0 + ty + j * 8) * rows + r0 + tx] = f2bf(tile[tx][ty + j * 8]);
}

// ---------------- positions from (sorted) segment ids ----------------
__global__ void pos_kernel(const int* __restrict__ seg, int* __restrict__ pos) {
    int idx = blockIdx.x * 256 + threadIdx.x;
    if (idx >= Bc * Tc) return;
    int b = idx / Tc, t = idx - b * Tc;
    const int* s = seg + b * Tc;
    int v = s[t];
    int lo = 0, hi = t;
    while (lo < hi) { int mid = (lo + hi) >> 1; if (s[mid] < v) lo = mid + 1; else hi = mid; }
    pos[idx] = t - lo;   // t - seg_start
}

// ======== 256x256 8-phase GEMM (m201 structure): C(MxN) = A(MxKd)*Bt(NxKd)^T ========
// Swizzle: byte ^= ((row&7)<<4) (G4 formula; involution, row bits >=7 untouched).
// Prev round used bit9->bit5 XOR: only 2-way spread -> 8-way ds_read conflict
// (9.4M SQ_LDS_BANK_CONFLICT, MfmaUtil 32%). This one: 8 slots, 2 lanes/bank = free.
// XCD swizzle: contiguous chunk per XCD, col-major within chunk (A-panels L2-resident).
__global__ __launch_bounds__(512, 1) void gemm256(const u16* __restrict__ A,
                                                  const u16* __restrict__ Bt,
                                                  float* __restrict__ Cf,
                                                  u16* __restrict__ qb, u16* __restrict__ kb,
                                                  u16* __restrict__ vtb,
                                                  int N, int Kd, int mode) {
    __shared__ __align__(16) u16 lds[2][4][8192];   // [buf][A0,A1,B0,B1][16KB region]
    const int tid = threadIdx.x;
    const int wave = tid >> 6, lane = tid & 63;
    const int l16 = lane & 15, quad = lane >> 4;
    const int wr = wave >> 2, wc = wave & 3;

    // XCD-aware block remap: chunk per XCD, col-major inside (requires nwg%8==0, cpx%nx==0)
    const int nx = gridDim.x;
    const int nwg = nx * gridDim.y;
    const int lin = (int)blockIdx.y * nx + (int)blockIdx.x;
    const int cpx = nwg >> 3;
    const int rpc = cpx / nx;                      // chunk rows (4 for both launches)
    const int xcd = lin & 7, loc = lin >> 3;
    const int by = xcd * rpc + (loc % rpc);
    const int bx = loc / rpc;
    const int m0 = by * 256, n0 = bx * 256;

    // staging source (inverse-swizzled; same XOR as read side -> involution)
    const int rowc = tid >> 3;                             // row within 64-row chunk
    const int cb = ((tid & 7) * 16) ^ ((rowc & 7) << 4);   // swizzled byte col in 128B row
    const int cu = cb >> 1;
    const int x2 = tid * 8;                                // u16 dest idx within chunk
    const u16* ptrR[4];
    ptrR[0] = A + (size_t)(m0 + rowc) * Kd + cu;
    ptrR[1] = A + (size_t)(m0 + 128 + rowc) * Kd + cu;
    ptrR[2] = Bt + (size_t)(n0 + rowc) * Kd + cu;
    ptrR[3] = Bt + (size_t)(n0 + 128 + rowc) * Kd + cu;

    auto STG = [&](int buf, int reg, int c, int kt) {
        async_ld16(&lds[buf][reg][c * 4096 + x2], ptrR[reg] + (size_t)c * 64 * Kd + kt * 64);
    };

    const f32x4 fz = {0.f, 0.f, 0.f, 0.f};
    f32x4 acc[8][4];
#pragma unroll
    for (int i = 0; i < 8; i++)
#pragma unroll
        for (int j = 0; j < 4; j++) acc[i][j] = fz;

    bf16x8 afr[2][2], bfr[4][2];
    auto LDB_ALL = [&](int buf) {
#pragma unroll
        for (int ni = 0; ni < 4; ni++)
#pragma unroll
            for (int ks = 0; ks < 2; ks++) {
                int row = (wc & 1) * 64 + ni * 16 + l16;
                int y = row * 128 + ks * 64 + quad * 16;
                bfr[ni][ks] = *(const bf16x8*)&lds[buf][2 + (wc >> 1)][(y ^ ((row & 7) << 4)) >> 1];
            }
    };
    auto LDA2 = [&](int buf, int mp) {
#pragma unroll
        for (int i = 0; i < 2; i++)
#pragma unroll
            for (int ks = 0; ks < 2; ks++) {
                int row = mp * 32 + i * 16 + l16;
                int y = row * 128 + ks * 64 + quad * 16;
                afr[i][ks] = *(const bf16x8*)&lds[buf][wr][(y ^ ((row & 7) << 4)) >> 1];
            }
    };
    auto MFMA2 = [&](int mp) {
        __builtin_amdgcn_s_setprio(1);
#pragma unroll
        for (int i = 0; i < 2; i++)
#pragma unroll
            for (int ni = 0; ni < 4; ni++)
#pragma unroll
                for (int ks = 0; ks < 2; ks++)
                    acc[mp * 2 + i][ni] = __builtin_amdgcn_mfma_f32_16x16x32_bf16(
                        afr[i][ks], bfr[ni][ks], acc[mp * 2 + i][ni], 0, 0, 0);
        __builtin_amdgcn_s_setprio(0);
    };

    // ---- prologue: E(kt0) fully + O(kt1) B-chunks & A?a (14 loads) ----
    STG(0, 2, 0, 0); STG(0, 2, 1, 0); STG(0, 3, 0, 0); STG(0, 3, 1, 0);
    STG(0, 0, 0, 0); STG(0, 1, 0, 0); STG(0, 0, 1, 0); STG(0, 1, 1, 0);
    STG(1, 2, 0, 1); STG(1, 2, 1, 1); STG(1, 3, 0, 1); STG(1, 3, 1, 1);
    STG(1, 0, 0, 1); STG(1, 1, 0, 1);
    asm volatile("s_waitcnt vmcnt(6)" ::: "memory");
    raw_barrier();

    const int NIT = Kd >> 7;   // 2 k-tiles (of 64) per iteration
    for (int j = 0; j < NIT; j++) {
        const int ktO = 2 * j + 1;
        const int ktE = (2 * j + 2) & (2 * NIT - 1);
        const int ktO2 = (2 * j + 3) & (2 * NIT - 1);
        // p1
        LDB_ALL(0); LDA2(0, 0); STG(1, 0, 1, ktO); STG(1, 1, 1, ktO);
        raw_barrier(); MFMA2(0); raw_barrier();
        // p2
        LDA2(0, 1); STG(0, 2, 0, ktE); STG(0, 2, 1, ktE);
        raw_barrier(); MFMA2(1); raw_barrier();
        // p3
        LDA2(0, 2); STG(0, 3, 0, ktE); STG(0, 3, 1, ktE);
        raw_barrier(); MFMA2(2); raw_barrier();
        // p4
        LDA2(0, 3); STG(0, 0, 0, ktE); STG(0, 1, 0, ktE);
        raw_barrier(); MFMA2(3);
        asm volatile("s_waitcnt vmcnt(6)" ::: "memory"); raw_barrier();
        // p5
        LDB_ALL(1); LDA2(1, 0); STG(0, 0, 1, ktE); STG(0, 1, 1, ktE);
        raw_barrier(); MFMA2(0); raw_barrier();
        // p6
        LDA2(1, 1); STG(1, 2, 0, ktO2); STG(1, 2, 1, ktO2);
        raw_barrier(); MFMA2(1); raw_barrier();
        // p7
        LDA2(1, 2); STG(1, 3, 0, ktO2); STG(1, 3, 1, ktO2);
        raw_barrier(); MFMA2(2); raw_barrier();
        // p8
        LDA2(1, 3); STG(1, 0, 0, ktO2); STG(1, 1, 0, ktO2);
        raw_barrier(); MFMA2(3);
        asm volatile("s_waitcnt vmcnt(6)" ::: "memory"); raw_barrier();
    }
    asm volatile("s_waitcnt vmcnt(0)" ::: "memory");

    // ---- epilogue ----
    if (mode == 1) {
#pragma unroll
        for (int am = 0; am < 8; am++)
#pragma unroll
            for (int ni = 0; ni < 4; ni++)
#pragma unroll
                for (int r = 0; r < 4; r++) {
                    int row = m0 + wr * 128 + am * 16 + quad * 4 + r;
                    int col = n0 + wc * 64 + ni * 16 + l16;
                    Cf[(size_t)row * N + col] = acc[am][ni][r];
                }
    } else if (n0 < 2048) {            // Q
#pragma unroll
        for (int am = 0; am < 8; am++)
#pragma unroll
            for (int ni = 0; ni < 4; ni++)
#pragma unroll
                for (int r = 0; r < 4; r++) {
                    int row = m0 + wr * 128 + am * 16 + quad * 4 + r;
                    int col = n0 + wc * 64 + ni * 16 + l16;
                    qb[(size_t)row * 2048 + col] = f2bf(acc[am][ni][r]);
                }
    } else if (n0 < 2560) {            // K
#pragma unroll
        for (int am = 0; am < 8; am++)
#pragma unroll
            for (int ni = 0; ni < 4; ni++)
#pragma unroll
                for (int r = 0; r < 4; r++) {
                    int row = m0 + wr * 128 + am * 16 + quad * 4 + r;
                    int col = n0 + wc * 64 + ni * 16 + l16 - 2048;
                    kb[(size_t)row * 512 + col] = f2bf(acc[am][ni][r]);
                }
    } else {                           // V -> Vt[b][g][d][t]
#pragma unroll
        for (int am = 0; am < 8; am++)
#pragma unroll
            for (int ni = 0; ni < 4; ni++) {
                int nv = n0 + wc * 64 + ni * 16 + l16 - 2560;
                int g = nv >> 7, d = nv & 127;
                int m = m0 + wr * 128 + am * 16 + quad * 4;
                int b = m >> 11, t = m & 2047;
                u16 r4[4];
#pragma unroll
                for (int r = 0; r < 4; r++) r4[r] = f2bf(acc[am][ni][r]);
                *(uint2*)&vtb[(((size_t)b * Gc + g) * Kc + d) * Tc + t] = *(uint2*)r4;
            }
    }
}

// ---------------- fused RMSNorm + RoPE, vectorized (u32 = 2 bf16 per lane) ----------------
__global__ __launch_bounds__(256) void rms_rope(u16* __restrict__ X,
                                                const float* __restrict__ sc,
                                                const int* __restrict__ pos, int NH,
                                                float smul) {
    int row = blockIdx.x * 4 + (threadIdx.x >> 6);   // one wave per (b,t,head) row
    int lane = threadIdx.x & 63;
    int bt = row / NH;
    u16* xp = X + (size_t)row * Kc;
    u32 w = *(const u32*)(xp + 2 * lane);
    float a0 = bf2f((u16)(w & 0xffffu)), a1 = bf2f((u16)(w >> 16));
    float ss = a0 * a0 + a1 * a1;
#pragma unroll
    for (int m = 1; m < 64; m <<= 1) ss += __shfl_xor(ss, m, 64);
    float rn = rsqrtf(ss * (1.f / 128.f) + EPSc) * smul;   // fold attn scale into q
    float2 scv = *(const float2*)(sc + 2 * lane);
    float y0 = a0 * rn * scv.x, y1 = a1 * rn * scv.y;
    float p0 = __shfl_xor(y0, 32, 64);   // rope partner's scaled value
    float p1 = __shfl_xor(y1, 32, 64);
    int j0 = (2 * lane) & 63;            // freq index (same for lane and partner)
    float pf = (float)pos[bt];
    const float nl2 = -0.20762050593046015f;   // -log2(10000)/64
    float inv0 = exp2f((float)j0 * nl2);
    float inv1 = exp2f((float)(j0 + 1) * nl2);
    float s0, c0, s1, c1;
    sincosf(pf * inv0, &s0, &c0);
    sincosf(pf * inv1, &s1, &c1);
    float sgn = (lane < 32) ? -1.f : 1.f;      // x1*c - x2*s  |  x2*c + x1*s
    float o0 = y0 * c0 + sgn * p0 * s0;
    float o1 = y1 * c1 + sgn * p1 * s1;
    u32 outw = (u32)f2bf(o0) | ((u32)f2bf(o1) << 16);
    *(u32*)(xp + 2 * lane) = outw;
}

// ---------------- flash attention v2: gload_lds double-buffer, 1 barrier/tile ----------------
__global__ __launch_bounds__(256, 2) void flash_attn(const u16* __restrict__ Qb,
                                                     const u16* __restrict__ Kb,
                                                     const u16* __restrict__ Vt,
                                                     const int* __restrict__ pos,
                                                     u16* __restrict__ Ob) {
    __shared__ __align__(16) u16 lK[2][64 * 128];
    __shared__ __align__(16) u16 lVt[2][128 * 64];   // [d][s] swizzled

    // XCD-aware + load-balanced decode: 1024 blocks = 8 xcd x (2 bg x 4 h x 16 q)
    const int lin = (int)blockIdx.x + 16 * ((int)blockIdx.y + 16 * (int)blockIdx.z);
    const int xcd = lin & 7, slot = lin >> 3;        // slot in [0,128)
    const int bg = xcd + 8 * (slot >> 6);            // [0,16)
    const int sub = slot & 63;
    const int b = bg >> 2, g = bg & 3;
    const int h = g * 4 + (sub >> 4);
    const int u = sub & 15;
    const int z = (u & 1) ? 15 - (u >> 1) : (u >> 1);   // zigzag: 0,15,1,14,...
    const int qi = (sub & 32) ? 15 - z : z;             // stride-32 flip
    const int q0 = qi * 128;
    const int tid = threadIdx.x;
    const int wave = tid >> 6, lane = tid & 63;
    const int l16 = lane & 15, quad = lane >> 4;

    bf16x8 qf[2][4];
#pragma unroll
    for (int gq = 0; gq < 2; gq++)
#pragma unroll
        for (int kk = 0; kk < 4; kk++)
            qf[gq][kk] = *(const bf16x8*)&Qb[((size_t)(b * Tc + q0 + gq * 64 + wave * 16 + l16) * Hc + h) * Kc + kk * 32 + quad * 8];

    int tg[2], tstart[2], tsmax[2];
#pragma unroll
    for (int gq = 0; gq < 2; gq++) {
        tg[gq] = q0 + gq * 64 + wave * 16 + l16;
        tstart[gq] = tg[gq] - pos[b * Tc + tg[gq]];
        int v = tstart[gq];   // wave-max over the 16 rows (l16 lanes)
        v = max(v, __shfl_xor(v, 1, 64));
        v = max(v, __shfl_xor(v, 2, 64));
        v = max(v, __shfl_xor(v, 4, 64));
        v = max(v, __shfl_xor(v, 8, 64));
        tsmax[gq] = v;
    }
    const int s_begin = ((q0 - pos[b * Tc + q0]) >> 6) << 6;

    // staging source pointers (inverse-swizzled). Per thread, 4 K + 4 V chunks.
    const u16* pK[4];
    const u16* pV[4];
#pragma unroll
    for (int i = 0; i < 4; i++) {
        int rowK = i * 16 + (tid >> 4);
        int cbK = ((tid & 15) * 16) ^ ((rowK & 7) << 4);
        pK[i] = Kb + ((size_t)(b * Tc + rowK) * Gc + g) * Kc + (cbK >> 1);
        int dV = i * 32 + (tid >> 3);
        int cbV = ((tid & 7) * 16) ^ ((dV & 7) << 4);
        pV[i] = Vt + (((size_t)b * Gc + g) * Kc + dV) * Tc + (cbV >> 1);
    }
    const int x2 = tid * 8;   // u16 dest idx within 4KB chunk region

    auto STAGE = [&](int buf, int s0) {
#pragma unroll
        for (int i = 0; i < 4; i++)
            async_ld16(&lK[buf][i * 2048 + x2], pK[i] + (size_t)s0 * (Gc * Kc));
#pragma unroll
        for (int i = 0; i < 4; i++)
            async_ld16(&lVt[buf][i * 2048 + x2], pV[i] + s0);
    };

    float m_i[2] = {-1e30f, -1e30f}, l_i[2] = {0.f, 0.f};
    const f32x4 fz = {0.f, 0.f, 0.f, 0.f};
    f32x4 oc[2][8];
#pragma unroll
    for (int gq = 0; gq < 2; gq++)
#pragma unroll
        for (int i = 0; i < 8; i++) oc[gq][i] = fz;

    // bpermute source addrs for the P^T quad-redistribution
    const int addrA = (l16 + ((quad & 1) << 5)) << 2;   // m' = 0,1
    const int addrB = addrA + 64;                       // m' = 2,3
    const bool hiq = quad >= 2;

    STAGE(0, s_begin);   // prologue

    const int s_end = q0 + 64;
    int buf = 0;
    for (int s0 = s_begin; s0 <= s_end; s0 += 64, buf ^= 1) {
        asm volatile("s_waitcnt vmcnt(0)" ::: "memory");   // this tile's loads landed
        raw_barrier();                                      // ... in all waves
        if (s0 + 64 <= s_end) STAGE(buf ^ 1, s0 + 64);      // next tile (post-barrier: WAR-safe)

        // S^T = K Q^T for both t-groups, sharing each bk read
        f32x4 sacc[2][4];
#pragma unroll
        for (int gq = 0; gq < 2; gq++)
#pragma unroll
            for (int mi = 0; mi < 4; mi++) sacc[gq][mi] = fz;
        __builtin_amdgcn_s_setprio(1);
#pragma unroll
        for (int kk = 0; kk < 4; kk++) {
#pragma unroll
            for (int mi = 0; mi < 4; mi++) {
                int row = mi * 16 + l16;
                int byt = row * 256 + ((kk * 64 + quad * 16) ^ ((row & 7) << 4));
                bf16x8 bk = *(const bf16x8*)&lK[buf][byt >> 1];
                sacc[0][mi] = __builtin_amdgcn_mfma_f32_16x16x32_bf16(bk, qf[0][kk], sacc[0][mi], 0, 0, 0);
                sacc[1][mi] = __builtin_amdgcn_mfma_f32_16x16x32_bf16(bk, qf[1][kk], sacc[1][mi], 0, 0, 0);
            }
        }
        __builtin_amdgcn_s_setprio(0);

        u32 W[2][4][2];
#pragma unroll
        for (int gq = 0; gq < 2; gq++) {
            const bool fast = (s0 >= tsmax[gq]) && (s0 + 64 <= q0 + gq * 64);
            float rmax = -1e30f;
            if (fast) {
#pragma unroll
                for (int mi = 0; mi < 4; mi++)
#pragma unroll
                    for (int r = 0; r < 4; r++) rmax = fmaxf(rmax, sacc[gq][mi][r]);
            } else {
#pragma unroll
                for (int mi = 0; mi < 4; mi++) {
                    int sl = s0 + mi * 16 + quad * 4;
#pragma unroll
                    for (int r = 0; r < 4; r++) {
                        bool ok = (sl + r <= tg[gq]) && (sl + r >= tstart[gq]);
                        float x = ok ? sacc[gq][mi][r] : -1e30f;
                        sacc[gq][mi][r] = x;
                        rmax = fmaxf(rmax, x);
                    }
                }
            }
            rmax = fmaxf(rmax, __shfl_xor(rmax, 16, 64));
            rmax = fmaxf(rmax, __shfl_xor(rmax, 32, 64));

            // defer-max: only rescale when some row's max grew past m + THR
            if (!__all(rmax <= m_i[gq] + 8.f)) {
                float mnew = fmaxf(m_i[gq], rmax);
                float alpha = __expf(m_i[gq] - mnew);
                m_i[gq] = mnew;
                l_i[gq] *= alpha;
#pragma unroll
                for (int ni = 0; ni < 8; ni++)
#pragma unroll
                    for (int r = 0; r < 4; r++) oc[gq][ni][r] *= alpha;
            }
            float psum = 0.f;
#pragma unroll
            for (int mi = 0; mi < 4; mi++) {
                float p[4];
#pragma unroll
                for (int r = 0; r < 4; r++) {
                    float x = sacc[gq][mi][r];
                    p[r] = (x > -1e29f) ? __expf(x - m_i[gq]) : 0.f;
                    psum += p[r];
                }
                W[gq][mi][0] = cvt_pk_bf16(p[0], p[1]);
                W[gq][mi][1] = cvt_pk_bf16(p[2], p[3]);
            }
            psum += __shfl_xor(psum, 16, 64);
            psum += __shfl_xor(psum, 32, 64);
            l_i[gq] += psum;
        }

        // O^T += V^T P^T for both groups, sharing each av read
#pragma unroll
        for (int kk = 0; kk < 2; kk++) {
            bf16x8 bu[2];
#pragma unroll
            for (int gq = 0; gq < 2; gq++) {
                u32 w0a = (u32)__builtin_amdgcn_ds_bpermute(addrA, (int)W[gq][2 * kk][0]);
                u32 w0b = (u32)__builtin_amdgcn_ds_bpermute(addrA, (int)W[gq][2 * kk + 1][0]);
                u32 w1a = (u32)__builtin_amdgcn_ds_bpermute(addrA, (int)W[gq][2 * kk][1]);
                u32 w1b = (u32)__builtin_amdgcn_ds_bpermute(addrA, (int)W[gq][2 * kk + 1][1]);
                u32 w2a = (u32)__builtin_amdgcn_ds_bpermute(addrB, (int)W[gq][2 * kk][0]);
                u32 w2b = (u32)__builtin_amdgcn_ds_bpermute(addrB, (int)W[gq][2 * kk + 1][0]);
                u32 w3a = (u32)__builtin_amdgcn_ds_bpermute(addrB, (int)W[gq][2 * kk][1]);
                u32 w3b = (u32)__builtin_amdgcn_ds_bpermute(addrB, (int)W[gq][2 * kk + 1][1]);
                union { u32 w[4]; bf16x8 v; } uu;
                uu.w[0] = hiq ? w0b : w0a;
                uu.w[1] = hiq ? w1b : w1a;
                uu.w[2] = hiq ? w2b : w2a;
                uu.w[3] = hiq ? w3b : w3a;
                bu[gq] = uu.v;
            }
            __builtin_amdgcn_s_setprio(1);
#pragma unroll
            for (int ni = 0; ni < 8; ni++) {
                int d = ni * 16 + l16;
                int byt = d * 128 + ((kk * 64 + quad * 16) ^ ((d & 7) << 4));
                bf16x8 av = *(const bf16x8*)&lVt[buf][byt >> 1];
                oc[0][ni] = __builtin_amdgcn_mfma_f32_16x16x32_bf16(av, bu[0], oc[0][ni], 0, 0, 0);
                oc[1][ni] = __builtin_amdgcn_mfma_f32_16x16x32_bf16(av, bu[1], oc[1][ni], 0, 0, 0);
            }
            __builtin_amdgcn_s_setprio(0);
        }
    }

    // ---- epilogue: O^T -> O transpose via LDS (reuse lK for grpA, lVt for grpB) ----
#define KSTR 136
    __syncthreads();
    float invl[2] = {1.f / l_i[0], 1.f / l_i[1]};
    const int tloc = wave * 16 + l16;
#pragma unroll
    for (int gq = 0; gq < 2; gq++) {
        u16* lO = gq ? (u16*)lVt : (u16*)lK;   // each region is 16384 u16 >= 64*KSTR
#pragma unroll
        for (int ni = 0; ni < 8; ni++) {
            u16 r4[4];
#pragma unroll
            for (int r = 0; r < 4; r++) r4[r] = f2bf(oc[gq][ni][r] * invl[gq]);
            *(uint2*)&lO[tloc * KSTR + ni * 16 + quad * 4] = *(uint2*)r4;
        }
    }
    __syncthreads();
#pragma unroll
    for (int gq = 0; gq < 2; gq++) {
        u16* lO = gq ? (u16*)lVt : (u16*)lK;
#pragma unroll
        for (int j = 0; j < 4; j++) {
            int t2 = wave * 16 + j * 4 + quad;
            uint4 vv = *(const uint4*)&lO[t2 * KSTR + l16 * 8];
            *(uint4*)&Ob[((size_t)(b * Tc + q0 + gq * 64 + t2) * Hc + h) * Kc + l16 * 8] = vv;
        }
    }
}

extern "C" void kernel_launch(void* const* d_in, const int* in_sizes, int n_in,
                              void* d_out, int out_size, void* d_ws, size_t ws_size,
                              hipStream_t stream) {
    const float* hidden  = (const float*)d_in[0];
    const float* wq      = (const float*)d_in[1];
    const float* wk      = (const float*)d_in[2];
    const float* wv      = (const float*)d_in[3];
    const float* wo      = (const float*)d_in[4];
    const float* q_scale = (const float*)d_in[5];
    const float* k_scale = (const float*)d_in[6];
    const int*   segids  = (const int*)d_in[7];
    float* out = (float*)d_out;

    char* ws = (char*)d_ws;
    size_t off = 0;
    auto alloc = [&](size_t bytes) -> void* {
        void* p = ws + off;
        off += (bytes + 255) & ~(size_t)255;
        return p;
    };
    u16* hbf  = (u16*)alloc((size_t)Bc * Tc * Dc * 2);        // hidden bf16
    u16* wqT  = (u16*)alloc((size_t)Hc * Kc * Dc * 2);        // (2048 x 2048) \  adjacent:
    u16* wkT  = (u16*)alloc((size_t)Gc * Kc * Dc * 2);        // (512 x 2048)   } one 3072-row B^T
    u16* wvT  = (u16*)alloc((size_t)Gc * Kc * Dc * 2);        // (512 x 2048)  /
    u16* woT  = (u16*)alloc((size_t)Dc * Hc * Kc * 2);        // (2048 x 2048)
    u16* qb   = (u16*)alloc((size_t)Bc * Tc * Hc * Kc * 2);
    u16* kb   = (u16*)alloc((size_t)Bc * Tc * Gc * Kc * 2);
    u16* vtb  = (u16*)alloc((size_t)Bc * Gc * Kc * Tc * 2);   // V^T [b][g][d][t]
    u16* attn = (u16*)alloc((size_t)Bc * Tc * Hc * Kc * 2);
    int* posb = (int*)alloc((size_t)Bc * Tc * 4);
    (void)ws_size; (void)in_sizes; (void)n_in; (void)out_size;

    const int M = Bc * Tc;   // 8192
    const float qsc = 0.08838834764831845f;   // K^-0.5 folded into q rms_rope

    cvt_f2bf<<<(Bc * Tc * Dc) / 1024, 256, 0, stream>>>(hidden, hbf, Bc * Tc * Dc);
    transpose_f2bf<<<dim3(64, 64), 256, 0, stream>>>(wq, wqT, Dc, Hc * Kc);
    transpose_f2bf<<<dim3(16, 64), 256, 0, stream>>>(wk, wkT, Dc, Gc * Kc);
    transpose_f2bf<<<dim3(16, 64), 256, 0, stream>>>(wv, wvT, Dc, Gc * Kc);
    transpose_f2bf<<<dim3(64, 64), 256, 0, stream>>>(wo, woT, Hc * Kc, Dc);
    pos_kernel<<<(Bc * Tc) / 256, 256, 0, stream>>>(segids, posb);

    // merged Q+K+V projection: N = 3072 over adjacent [wqT; wkT; wvT] (256^2 8-phase)
    gemm256<<<dim3(3072 / 256, M / 256), 512, 0, stream>>>(hbf, wqT, nullptr, qb, kb, vtb, 3072, Dc, 0);

    rms_rope<<<(M * Hc) / 4, 256, 0, stream>>>(qb, q_scale, posb, Hc, qsc);
    rms_rope<<<(M * Gc) / 4, 256, 0, stream>>>(kb, k_scale, posb, Gc, 1.0f);

    flash_attn<<<dim3(Tc / 128, Hc, Bc), 256, 0, stream>>>(qb, kb, vtb, posb, attn);

    // output projection: out = attn x woT^T (256^2 8-phase, float C)
    gemm256<<<dim3(Dc / 256, M / 256), 512, 0, stream>>>(attn, woT, out, nullptr, nullptr, nullptr, Dc, Hc * Kc, 1);
}

// Round 9
// 437.723 us; speedup vs baseline: 1.5863x; 1.0009x over previous
//
#include <hip/hip_runtime.h>

typedef unsigned short u16;
typedef unsigned int u32;
using f32x4 = __attribute__((ext_vector_type(4))) float;
using bf16x8 = __attribute__((ext_vector_type(8))) __bf16;

constexpr int Bc = 4, Tc = 2048, Dc = 2048, Hc = 16, Gc = 4, Kc = 128;
constexpr float EPSc = 1e-6f;

__device__ __forceinline__ u16 f2bf(float f) {
    u32 u = __float_as_uint(f);
    u = (u + 0x7fffu + ((u >> 16) & 1u)) >> 16;
    return (u16)u;
}
__device__ __forceinline__ float bf2f(u16 h) {
    return __uint_as_float(((u32)h) << 16);
}

// async global->LDS, 16B per lane; LDS dest must be wave-uniform base + lane*16
__device__ __forceinline__ void async_ld16(void* lds, const void* g) {
    __builtin_amdgcn_global_load_lds(
        (const __attribute__((address_space(1))) unsigned int*)g,
        (__attribute__((address_space(3))) unsigned int*)lds, 16, 0, 0);
}

__device__ __forceinline__ void raw_barrier() {
    asm volatile("" ::: "memory");
    __builtin_amdgcn_s_barrier();
    asm volatile("" ::: "memory");
}

__device__ __forceinline__ u32 cvt_pk_bf16(float lo, float hi) {
    u32 r;
    asm("v_cvt_pk_bf16_f32 %0, %1, %2" : "=v"(r) : "v"(lo), "v"(hi));
    return r;
}

// ---------------- fp32 -> bf16 convert ----------------
__global__ __launch_bounds__(256) void cvt_f2bf(const float* __restrict__ in,
                                                u16* __restrict__ out, int n) {
    int i = (blockIdx.x * 256 + threadIdx.x) * 4;
    if (i >= n) return;
    float4 f = *(const float4*)(in + i);
    u16 r[4] = { f2bf(f.x), f2bf(f.y), f2bf(f.z), f2bf(f.w) };
    *(uint2*)(out + i) = *(uint2*)r;
}

// ------- transpose+convert: in (rows x cols) f32 -> out (cols x rows) bf16 -------
__global__ __launch_bounds__(256) void transpose_f2bf(const float* __restrict__ in,
                                                      u16* __restrict__ out,
                                                      int rows, int cols) {
    __shared__ float tile[32][33];
    int tx = threadIdx.x & 31, ty = threadIdx.x >> 5;
    int c0 = blockIdx.x * 32, r0 = blockIdx.y * 32;
#pragma unroll
    for (int j = 0; j < 4; j++)
        tile[ty + j * 8][tx] = in[(size_t)(r0 + ty + j * 8) * cols + c0 + tx];
    __syncthreads();
#pragma unroll
    for (int j = 0; j < 4; j++)
        out[(size_t)(c0 + ty + j * 8) * rows + r0 + tx] = f2bf(tile[tx][ty + j * 8]);
}

// ------- merged wq/wk/wv transpose: outputs contiguous [3072][2048] bf16 -------
__global__ __launch_bounds__(256) void transpose_qkv_w(const float* __restrict__ wq,
                                                       const float* __restrict__ wk,
                                                       const float* __restrict__ wv,
                                                       u16* __restrict__ out) {
    __shared__ float tile[32][33];
    int tx = threadIdx.x & 31, ty = threadIdx.x >> 5;
    int c0 = blockIdx.x * 32, r0 = blockIdx.y * 32;   // c0: combined col 0..3071
    const float* in;
    int stride, cc0;
    if (c0 < 2048)      { in = wq; stride = 2048; cc0 = c0; }
    else if (c0 < 2560) { in = wk; stride = 512;  cc0 = c0 - 2048; }
    else                { in = wv; stride = 512;  cc0 = c0 - 2560; }
#pragma unroll
    for (int j = 0; j < 4; j++)
        tile[ty + j * 8][tx] = in[(size_t)(r0 + ty + j * 8) * stride + cc0 + tx];
    __syncthreads();
#pragma unroll
    for (int j = 0; j < 4; j++)
        out[(size_t)(c0 + ty + j * 8) * 2048 + r0 + tx] = f2bf(tile[tx][ty + j * 8]);
}

// ---------------- positions from (sorted) segment ids ----------------
__global__ void pos_kernel(const int* __restrict__ seg, int* __restrict__ pos) {
    int idx = blockIdx.x * 256 + threadIdx.x;
    if (idx >= Bc * Tc) return;
    int b = idx / Tc, t = idx - b * Tc;
    const int* s = seg + b * Tc;
    int v = s[t];
    int lo = 0, hi = t;
    while (lo < hi) { int mid = (lo + hi) >> 1; if (s[mid] < v) lo = mid + 1; else hi = mid; }
    pos[idx] = t - lo;   // t - seg_start
}

// ======== 256xBN 8-phase GEMM (m201 structure): C(MxN) = A(MxKd)*Bt(NxKd)^T ========
// NI = per-wave ni count; BN = NI*64 (4 -> 256, 3 -> 192). NI=3 exists so the QKV
// launch (N=3072) gives 512 blocks = exactly 2 full rounds on 256 CUs (r8: 384
// blocks = 1.5 rounds, 25% dispatch tail). vmcnt(NI+2) re-derived for both.
// Swizzle: byte ^= ((row&7)<<4) both sides (r8: conflicts = 0).
template<int NI>
__global__ __launch_bounds__(512, 1) void gemm256(const u16* __restrict__ A,
                                                  const u16* __restrict__ Bt,
                                                  float* __restrict__ Cf,
                                                  u16* __restrict__ qb, u16* __restrict__ kb,
                                                  u16* __restrict__ vtb,
                                                  int N, int Kd, int mode) {
    constexpr int BN = NI * 64;
    __shared__ __align__(16) u16 lds[2][4][8192];   // [buf][A0,A1,B0,B1][16KB region]
    const int tid = threadIdx.x;
    const int wave = tid >> 6, lane = tid & 63;
    const int l16 = lane & 15, quad = lane >> 4;
    const int wr = wave >> 2, wc = wave & 3;

    // XCD-aware block remap: chunk per XCD, col-major inside (requires nwg%8==0, cpx%nx==0)
    const int nx = gridDim.x;
    const int nwg = nx * gridDim.y;
    const int lin = (int)blockIdx.y * nx + (int)blockIdx.x;
    const int cpx = nwg >> 3;
    const int rpc = cpx / nx;
    const int xcd = lin & 7, loc = lin >> 3;
    const int by = xcd * rpc + (loc % rpc);
    const int bx = loc / rpc;
    const int m0 = by * 256, n0 = bx * BN;

    // staging source (inverse-swizzled; same XOR as read side -> involution)
    const int rowc = tid >> 3;                             // row within 64-row chunk
    const int cb = ((tid & 7) * 16) ^ ((rowc & 7) << 4);   // swizzled byte col in 128B row
    const int cu = cb >> 1;
    const int x2 = tid * 8;                                // u16 dest idx within chunk
    const u16* pA[4];
#pragma unroll
    for (int c = 0; c < 4; c++) pA[c] = A + (size_t)(m0 + c * 64 + rowc) * Kd + cu;
    const u16* pB[NI];
#pragma unroll
    for (int c = 0; c < NI; c++) pB[c] = Bt + (size_t)(n0 + c * 64 + rowc) * Kd + cu;

    // A chunk c (rows c*64..): region c>>1, slot c&1. B chunk c: region 2+(c>>1), slot c&1.
    auto STGA = [&](int buf, int c, int kt) {
        async_ld16(&lds[buf][c >> 1][(c & 1) * 4096 + x2], pA[c] + kt * 64);
    };
    auto STGB = [&](int buf, int c, int kt) {
        async_ld16(&lds[buf][2 + (c >> 1)][(c & 1) * 4096 + x2], pB[c] + kt * 64);
    };

    const f32x4 fz = {0.f, 0.f, 0.f, 0.f};
    f32x4 acc[8][NI];
#pragma unroll
    for (int i = 0; i < 8; i++)
#pragma unroll
        for (int j = 0; j < NI; j++) acc[i][j] = fz;

    bf16x8 afr[2][2], bfr[NI][2];
    auto LDB_ALL = [&](int buf) {
#pragma unroll
        for (int ni = 0; ni < NI; ni++)
#pragma unroll
            for (int ks = 0; ks < 2; ks++) {
                int row = wc * (NI * 16) + ni * 16 + l16;
                int y = (row & 127) * 128 + ks * 64 + quad * 16;
                bfr[ni][ks] = *(const bf16x8*)&lds[buf][2 + (row >> 7)][(y ^ ((row & 7) << 4)) >> 1];
            }
    };
    auto LDA2 = [&](int buf, int mp) {
#pragma unroll
        for (int i = 0; i < 2; i++)
#pragma unroll
            for (int ks = 0; ks < 2; ks++) {
                int row = mp * 32 + i * 16 + l16;
                int y = row * 128 + ks * 64 + quad * 16;
                afr[i][ks] = *(const bf16x8*)&lds[buf][wr][(y ^ ((row & 7) << 4)) >> 1];
            }
    };
    auto MFMA2 = [&](int mp) {
        __builtin_amdgcn_s_setprio(1);
#pragma unroll
        for (int i = 0; i < 2; i++)
#pragma unroll
            for (int ni = 0; ni < NI; ni++)
#pragma unroll
                for (int ks = 0; ks < 2; ks++)
                    acc[mp * 2 + i][ni] = __builtin_amdgcn_mfma_f32_16x16x32_bf16(
                        afr[i][ks], bfr[ni][ks], acc[mp * 2 + i][ni], 0, 0, 0);
        __builtin_amdgcn_s_setprio(0);
    };

#define VMC_WAIT() asm volatile("s_waitcnt vmcnt(%0)" :: "i"(NI + 2) : "memory")

    // ---- prologue: E(kt0) fully (NI+4 loads) + O(kt1) B + Aa (NI+2 loads) ----
    STGB(0, 0, 0); STGB(0, 1, 0); STGB(0, 2, 0); if (NI == 4) STGB(0, 3, 0);
    STGA(0, 0, 0); STGA(0, 2, 0); STGA(0, 1, 0); STGA(0, 3, 0);
    STGB(1, 0, 1); STGB(1, 1, 1); STGB(1, 2, 1); if (NI == 4) STGB(1, 3, 1);
    STGA(1, 0, 1); STGA(1, 2, 1);
    VMC_WAIT();
    raw_barrier();

    const int NIT = Kd >> 7;   // 2 k-tiles (of 64) per iteration
    for (int j = 0; j < NIT; j++) {
        const int ktO = 2 * j + 1;
        const int ktE = (2 * j + 2) & (2 * NIT - 1);
        const int ktO2 = (2 * j + 3) & (2 * NIT - 1);
        // p1
        LDB_ALL(0); LDA2(0, 0); STGA(1, 1, ktO); STGA(1, 3, ktO);   // O's Ab
        raw_barrier(); MFMA2(0); raw_barrier();
        // p2
        LDA2(0, 1); STGB(0, 0, ktE); STGB(0, 1, ktE);
        raw_barrier(); MFMA2(1); raw_barrier();
        // p3
        LDA2(0, 2); STGB(0, 2, ktE); if (NI == 4) STGB(0, 3, ktE);
        raw_barrier(); MFMA2(2); raw_barrier();
        // p4
        LDA2(0, 3); STGA(0, 0, ktE); STGA(0, 2, ktE);               // E's Aa
        raw_barrier(); MFMA2(3);
        VMC_WAIT(); raw_barrier();
        // p5
        LDB_ALL(1); LDA2(1, 0); STGA(0, 1, ktE); STGA(0, 3, ktE);   // E's Ab
        raw_barrier(); MFMA2(0); raw_barrier();
        // p6
        LDA2(1, 1); STGB(1, 0, ktO2); STGB(1, 1, ktO2);
        raw_barrier(); MFMA2(1); raw_barrier();
        // p7
        LDA2(1, 2); STGB(1, 2, ktO2); if (NI == 4) STGB(1, 3, ktO2);
        raw_barrier(); MFMA2(2); raw_barrier();
        // p8
        LDA2(1, 3); STGA(1, 0, ktO2); STGA(1, 2, ktO2);             // O's Aa
        raw_barrier(); MFMA2(3);
        VMC_WAIT(); raw_barrier();
    }
    asm volatile("s_waitcnt vmcnt(0)" ::: "memory");
#undef VMC_WAIT

    // ---- epilogue ----
    if (mode == 1) {
#pragma unroll
        for (int am = 0; am < 8; am++)
#pragma unroll
            for (int ni = 0; ni < NI; ni++)
#pragma unroll
                for (int r = 0; r < 4; r++) {
                    int row = m0 + wr * 128 + am * 16 + quad * 4 + r;
                    int col = n0 + wc * (NI * 16) + ni * 16 + l16;
                    Cf[(size_t)row * N + col] = acc[am][ni][r];
                }
    } else {
#pragma unroll
        for (int am = 0; am < 8; am++)
#pragma unroll
            for (int ni = 0; ni < NI; ni++) {
                int col = n0 + wc * (NI * 16) + ni * 16 + l16;
                int m = m0 + wr * 128 + am * 16 + quad * 4;
                if (col < 2048) {           // Q
#pragma unroll
                    for (int r = 0; r < 4; r++)
                        qb[(size_t)(m + r) * 2048 + col] = f2bf(acc[am][ni][r]);
                } else if (col < 2560) {    // K
#pragma unroll
                    for (int r = 0; r < 4; r++)
                        kb[(size_t)(m + r) * 512 + col - 2048] = f2bf(acc[am][ni][r]);
                } else {                    // V -> Vt[b][g][d][t]
                    int nv = col - 2560;
                    int g = nv >> 7, d = nv & 127;
                    int b = m >> 11, t = m & 2047;
                    u16 r4[4];
#pragma unroll
                    for (int r = 0; r < 4; r++) r4[r] = f2bf(acc[am][ni][r]);
                    *(uint2*)&vtb[(((size_t)b * Gc + g) * Kc + d) * Tc + t] = *(uint2*)r4;
                }
            }
    }
}

// ---------------- fused RMSNorm + RoPE, vectorized (u32 = 2 bf16 per lane) ----------------
__global__ __launch_bounds__(256) void rms_rope(u16* __restrict__ X,
                                                const float* __restrict__ sc,
                                                const int* __restrict__ pos, int NH,
                                                float smul) {
    int row = blockIdx.x * 4 + (threadIdx.x >> 6);   // one wave per (b,t,head) row
    int lane = threadIdx.x & 63;
    int bt = row / NH;
    u16* xp = X + (size_t)row * Kc;
    u32 w = *(const u32*)(xp + 2 * lane);
    float a0 = bf2f((u16)(w & 0xffffu)), a1 = bf2f((u16)(w >> 16));
    float ss = a0 * a0 + a1 * a1;
#pragma unroll
    for (int m = 1; m < 64; m <<= 1) ss += __shfl_xor(ss, m, 64);
    float rn = rsqrtf(ss * (1.f / 128.f) + EPSc) * smul;   // fold attn scale into q
    float2 scv = *(const float2*)(sc + 2 * lane);
    float y0 = a0 * rn * scv.x, y1 = a1 * rn * scv.y;
    float p0 = __shfl_xor(y0, 32, 64);   // rope partner's scaled value
    float p1 = __shfl_xor(y1, 32, 64);
    int j0 = (2 * lane) & 63;            // freq index (same for lane and partner)
    float pf = (float)pos[bt];
    const float nl2 = -0.20762050593046015f;   // -log2(10000)/64
    float inv0 = exp2f((float)j0 * nl2);
    float inv1 = exp2f((float)(j0 + 1) * nl2);
    float s0, c0, s1, c1;
    sincosf(pf * inv0, &s0, &c0);
    sincosf(pf * inv1, &s1, &c1);
    float sgn = (lane < 32) ? -1.f : 1.f;      // x1*c - x2*s  |  x2*c + x1*s
    float o0 = y0 * c0 + sgn * p0 * s0;
    float o1 = y1 * c1 + sgn * p1 * s1;
    u32 outw = (u32)f2bf(o0) | ((u32)f2bf(o1) << 16);
    *(u32*)(xp + 2 * lane) = outw;
}

// ---------------- flash attention v2: gload_lds double-buffer, 1 barrier/tile ----------------
__global__ __launch_bounds__(256, 2) void flash_attn(const u16* __restrict__ Qb,
                                                     const u16* __restrict__ Kb,
                                                     const u16* __restrict__ Vt,
                                                     const int* __restrict__ pos,
                                                     u16* __restrict__ Ob) {
    __shared__ __align__(16) u16 lK[2][64 * 128];
    __shared__ __align__(16) u16 lVt[2][128 * 64];   // [d][s] swizzled

    // XCD-aware + load-balanced decode: 1024 blocks = 8 xcd x (2 bg x 4 h x 16 q)
    const int lin = (int)blockIdx.x + 16 * ((int)blockIdx.y + 16 * (int)blockIdx.z);
    const int xcd = lin & 7, slot = lin >> 3;        // slot in [0,128)
    const int bg = xcd + 8 * (slot >> 6);            // [0,16)
    const int sub = slot & 63;
    const int b = bg >> 2, g = bg & 3;
    const int h = g * 4 + (sub >> 4);
    const int u = sub & 15;
    const int z = (u & 1) ? 15 - (u >> 1) : (u >> 1);   // zigzag: 0,15,1,14,...
    const int qi = (sub & 32) ? 15 - z : z;             // stride-32 flip
    const int q0 = qi * 128;
    const int tid = threadIdx.x;
    const int wave = tid >> 6, lane = tid & 63;
    const int l16 = lane & 15, quad = lane >> 4;

    bf16x8 qf[2][4];
#pragma unroll
    for (int gq = 0; gq < 2; gq++)
#pragma unroll
        for (int kk = 0; kk < 4; kk++)
            qf[gq][kk] = *(const bf16x8*)&Qb[((size_t)(b * Tc + q0 + gq * 64 + wave * 16 + l16) * Hc + h) * Kc + kk * 32 + quad * 8];

    int tg[2], tstart[2], tsmax[2];
#pragma unroll
    for (int gq = 0; gq < 2; gq++) {
        tg[gq] = q0 + gq * 64 + wave * 16 + l16;
        tstart[gq] = tg[gq] - pos[b * Tc + tg[gq]];
        int v = tstart[gq];   // wave-max over the 16 rows (l16 lanes)
        v = max(v, __shfl_xor(v, 1, 64));
        v = max(v, __shfl_xor(v, 2, 64));
        v = max(v, __shfl_xor(v, 4, 64));
        v = max(v, __shfl_xor(v, 8, 64));
        tsmax[gq] = v;
    }
    const int s_begin = ((q0 - pos[b * Tc + q0]) >> 6) << 6;

    // staging source pointers (inverse-swizzled). Per thread, 4 K + 4 V chunks.
    const u16* pK[4];
    const u16* pV[4];
#pragma unroll
    for (int i = 0; i < 4; i++) {
        int rowK = i * 16 + (tid >> 4);
        int cbK = ((tid & 15) * 16) ^ ((rowK & 7) << 4);
        pK[i] = Kb + ((size_t)(b * Tc + rowK) * Gc + g) * Kc + (cbK >> 1);
        int dV = i * 32 + (tid >> 3);
        int cbV = ((tid & 7) * 16) ^ ((dV & 7) << 4);
        pV[i] = Vt + (((size_t)b * Gc + g) * Kc + dV) * Tc + (cbV >> 1);
    }
    const int x2 = tid * 8;   // u16 dest idx within 4KB chunk region

    auto STAGE = [&](int buf, int s0) {
#pragma unroll
        for (int i = 0; i < 4; i++)
            async_ld16(&lK[buf][i * 2048 + x2], pK[i] + (size_t)s0 * (Gc * Kc));
#pragma unroll
        for (int i = 0; i < 4; i++)
            async_ld16(&lVt[buf][i * 2048 + x2], pV[i] + s0);
    };

    float m_i[2] = {-1e30f, -1e30f}, l_i[2] = {0.f, 0.f};
    const f32x4 fz = {0.f, 0.f, 0.f, 0.f};
    f32x4 oc[2][8];
#pragma unroll
    for (int gq = 0; gq < 2; gq++)
#pragma unroll
        for (int i = 0; i < 8; i++) oc[gq][i] = fz;

    // bpermute source addrs for the P^T quad-redistribution
    const int addrA = (l16 + ((quad & 1) << 5)) << 2;   // m' = 0,1
    const int addrB = addrA + 64;                       // m' = 2,3
    const bool hiq = quad >= 2;

    STAGE(0, s_begin);   // prologue

    const int s_end = q0 + 64;
    int buf = 0;
    for (int s0 = s_begin; s0 <= s_end; s0 += 64, buf ^= 1) {
        asm volatile("s_waitcnt vmcnt(0)" ::: "memory");   // this tile's loads landed
        raw_barrier();                                      // ... in all waves
        if (s0 + 64 <= s_end) STAGE(buf ^ 1, s0 + 64);      // next tile (post-barrier: WAR-safe)

        // S^T = K Q^T for both t-groups, sharing each bk read
        f32x4 sacc[2][4];
#pragma unroll
        for (int gq = 0; gq < 2; gq++)
#pragma unroll
            for (int mi = 0; mi < 4; mi++) sacc[gq][mi] = fz;
        __builtin_amdgcn_s_setprio(1);
#pragma unroll
        for (int kk = 0; kk < 4; kk++) {
#pragma unroll
            for (int mi = 0; mi < 4; mi++) {
                int row = mi * 16 + l16;
                int byt = row * 256 + ((kk * 64 + quad * 16) ^ ((row & 7) << 4));
                bf16x8 bk = *(const bf16x8*)&lK[buf][byt >> 1];
                sacc[0][mi] = __builtin_amdgcn_mfma_f32_16x16x32_bf16(bk, qf[0][kk], sacc[0][mi], 0, 0, 0);
                sacc[1][mi] = __builtin_amdgcn_mfma_f32_16x16x32_bf16(bk, qf[1][kk], sacc[1][mi], 0, 0, 0);
            }
        }
        __builtin_amdgcn_s_setprio(0);

        u32 W[2][4][2];
#pragma unroll
        for (int gq = 0; gq < 2; gq++) {
            const bool fast = (s0 >= tsmax[gq]) && (s0 + 64 <= q0 + gq * 64);
            float rmax = -1e30f;
            if (fast) {
#pragma unroll
                for (int mi = 0; mi < 4; mi++)
#pragma unroll
                    for (int r = 0; r < 4; r++) rmax = fmaxf(rmax, sacc[gq][mi][r]);
            } else {
#pragma unroll
                for (int mi = 0; mi < 4; mi++) {
                    int sl = s0 + mi * 16 + quad * 4;
#pragma unroll
                    for (int r = 0; r < 4; r++) {
                        bool ok = (sl + r <= tg[gq]) && (sl + r >= tstart[gq]);
                        float x = ok ? sacc[gq][mi][r] : -1e30f;
                        sacc[gq][mi][r] = x;
                        rmax = fmaxf(rmax, x);
                    }
                }
            }
            rmax = fmaxf(rmax, __shfl_xor(rmax, 16, 64));
            rmax = fmaxf(rmax, __shfl_xor(rmax, 32, 64));

            // defer-max: only rescale when some row's max grew past m + THR
            if (!__all(rmax <= m_i[gq] + 8.f)) {
                float mnew = fmaxf(m_i[gq], rmax);
                float alpha = __expf(m_i[gq] - mnew);
                m_i[gq] = mnew;
                l_i[gq] *= alpha;
#pragma unroll
                for (int ni = 0; ni < 8; ni++)
#pragma unroll
                    for (int r = 0; r < 4; r++) oc[gq][ni][r] *= alpha;
            }
            float psum = 0.f;
#pragma unroll
            for (int mi = 0; mi < 4; mi++) {
                float p[4];
#pragma unroll
                for (int r = 0; r < 4; r++) {
                    float x = sacc[gq][mi][r];
                    p[r] = (x > -1e29f) ? __expf(x - m_i[gq]) : 0.f;
                    psum += p[r];
                }
                W[gq][mi][0] = cvt_pk_bf16(p[0], p[1]);
                W[gq][mi][1] = cvt_pk_bf16(p[2], p[3]);
            }
            psum += __shfl_xor(psum, 16, 64);
            psum += __shfl_xor(psum, 32, 64);
            l_i[gq] += psum;
        }

        // O^T += V^T P^T for both groups, sharing each av read
#pragma unroll
        for (int kk = 0; kk < 2; kk++) {
            bf16x8 bu[2];
#pragma unroll
            for (int gq = 0; gq < 2; gq++) {
                u32 w0a = (u32)__builtin_amdgcn_ds_bpermute(addrA, (int)W[gq][2 * kk][0]);
                u32 w0b = (u32)__builtin_amdgcn_ds_bpermute(addrA, (int)W[gq][2 * kk + 1][0]);
                u32 w1a = (u32)__builtin_amdgcn_ds_bpermute(addrA, (int)W[gq][2 * kk][1]);
                u32 w1b = (u32)__builtin_amdgcn_ds_bpermute(addrA, (int)W[gq][2 * kk + 1][1]);
                u32 w2a = (u32)__builtin_amdgcn_ds_bpermute(addrB, (int)W[gq][2 * kk][0]);
                u32 w2b = (u32)__builtin_amdgcn_ds_bpermute(addrB, (int)W[gq][2 * kk + 1][0]);
                u32 w3a = (u32)__builtin_amdgcn_ds_bpermute(addrB, (int)W[gq][2 * kk][1]);
                u32 w3b = (u32)__builtin_amdgcn_ds_bpermute(addrB, (int)W[gq][2 * kk + 1][1]);
                union { u32 w[4]; bf16x8 v; } uu;
                uu.w[0] = hiq ? w0b : w0a;
                uu.w[1] = hiq ? w1b : w1a;
                uu.w[2] = hiq ? w2b : w2a;
                uu.w[3] = hiq ? w3b : w3a;
                bu[gq] = uu.v;
            }
            __builtin_amdgcn_s_setprio(1);
#pragma unroll
            for (int ni = 0; ni < 8; ni++) {
                int d = ni * 16 + l16;
                int byt = d * 128 + ((kk * 64 + quad * 16) ^ ((d & 7) << 4));
                bf16x8 av = *(const bf16x8*)&lVt[buf][byt >> 1];
                oc[0][ni] = __builtin_amdgcn_mfma_f32_16x16x32_bf16(av, bu[0], oc[0][ni], 0, 0, 0);
                oc[1][ni] = __builtin_amdgcn_mfma_f32_16x16x32_bf16(av, bu[1], oc[1][ni], 0, 0, 0);
            }
            __builtin_amdgcn_s_setprio(0);
        }
    }

    // ---- epilogue: O^T -> O transpose via LDS (reuse lK for grpA, lVt for grpB) ----
#define KSTR 136
    __syncthreads();
    float invl[2] = {1.f / l_i[0], 1.f / l_i[1]};
    const int tloc = wave * 16 + l16;
#pragma unroll
    for (int gq = 0; gq < 2; gq++) {
        u16* lO = gq ? (u16*)lVt : (u16*)lK;   // each region is 16384 u16 >= 64*KSTR
#pragma unroll
        for (int ni = 0; ni < 8; ni++) {
            u16 r4[4];
#pragma unroll
            for (int r = 0; r < 4; r++) r4[r] = f2bf(oc[gq][ni][r] * invl[gq]);
            *(uint2*)&lO[tloc * KSTR + ni * 16 + quad * 4] = *(uint2*)r4;
        }
    }
    __syncthreads();
#pragma unroll
    for (int gq = 0; gq < 2; gq++) {
        u16* lO = gq ? (u16*)lVt : (u16*)lK;
#pragma unroll
        for (int j = 0; j < 4; j++) {
            int t2 = wave * 16 + j * 4 + quad;
            uint4 vv = *(const uint4*)&lO[t2 * KSTR + l16 * 8];
            *(uint4*)&Ob[((size_t)(b * Tc + q0 + gq * 64 + t2) * Hc + h) * Kc + l16 * 8] = vv;
        }
    }
}

extern "C" void kernel_launch(void* const* d_in, const int* in_sizes, int n_in,
                              void* d_out, int out_size, void* d_ws, size_t ws_size,
                              hipStream_t stream) {
    const float* hidden  = (const float*)d_in[0];
    const float* wq      = (const float*)d_in[1];
    const float* wk      = (const float*)d_in[2];
    const float* wv      = (const float*)d_in[3];
    const float* wo      = (const float*)d_in[4];
    const float* q_scale = (const float*)d_in[5];
    const float* k_scale = (const float*)d_in[6];
    const int*   segids  = (const int*)d_in[7];
    float* out = (float*)d_out;

    char* ws = (char*)d_ws;
    size_t off = 0;
    auto alloc = [&](size_t bytes) -> void* {
        void* p = ws + off;
        off += (bytes + 255) & ~(size_t)255;
        return p;
    };
    u16* hbf  = (u16*)alloc((size_t)Bc * Tc * Dc * 2);        // hidden bf16
    u16* wqT  = (u16*)alloc((size_t)Hc * Kc * Dc * 2);        // (2048 x 2048) \  adjacent:
    u16* wkT  = (u16*)alloc((size_t)Gc * Kc * Dc * 2);        // (512 x 2048)   } one 3072-row B^T
    u16* wvT  = (u16*)alloc((size_t)Gc * Kc * Dc * 2);        // (512 x 2048)  /
    u16* woT  = (u16*)alloc((size_t)Dc * Hc * Kc * 2);        // (2048 x 2048)
    u16* qb   = (u16*)alloc((size_t)Bc * Tc * Hc * Kc * 2);
    u16* kb   = (u16*)alloc((size_t)Bc * Tc * Gc * Kc * 2);
    u16* vtb  = (u16*)alloc((size_t)Bc * Gc * Kc * Tc * 2);   // V^T [b][g][d][t]
    u16* attn = (u16*)alloc((size_t)Bc * Tc * Hc * Kc * 2);
    int* posb = (int*)alloc((size_t)Bc * Tc * 4);
    (void)ws_size; (void)in_sizes; (void)n_in; (void)out_size;
    (void)wkT; (void)wvT;

    const int M = Bc * Tc;   // 8192
    const float qsc = 0.08838834764831845f;   // K^-0.5 folded into q rms_rope

    cvt_f2bf<<<(Bc * Tc * Dc) / 1024, 256, 0, stream>>>(hidden, hbf, Bc * Tc * Dc);
    transpose_qkv_w<<<dim3(96, 64), 256, 0, stream>>>(wq, wk, wv, wqT);
    transpose_f2bf<<<dim3(64, 64), 256, 0, stream>>>(wo, woT, Hc * Kc, Dc);
    pos_kernel<<<(Bc * Tc) / 256, 256, 0, stream>>>(segids, posb);

    // merged Q+K+V projection: N = 3072, BN=192 -> 512 blocks = 2 full rounds
    gemm256<3><<<dim3(3072 / 192, M / 256), 512, 0, stream>>>(hbf, wqT, nullptr, qb, kb, vtb, 3072, Dc, 0);

    rms_rope<<<(M * Hc) / 4, 256, 0, stream>>>(qb, q_scale, posb, Hc, qsc);
    rms_rope<<<(M * Gc) / 4, 256, 0, stream>>>(kb, k_scale, posb, Gc, 1.0f);

    flash_attn<<<dim3(Tc / 128, Hc, Bc), 256, 0, stream>>>(qb, kb, vtb, posb, attn);

    // output projection: out = attn x woT^T (BN=256, 256 blocks = 1 round)
    gemm256<4><<<dim3(Dc / 256, M / 256), 512, 0, stream>>>(attn, woT, out, nullptr, nullptr, nullptr, Dc, Hc * Kc, 1);
}

// Round 10
// 416.172 us; speedup vs baseline: 1.6684x; 1.0518x over previous
//
#include <hip/hip_runtime.h>

typedef unsigned short u16;
typedef unsigned int u32;
using f32x4 = __attribute__((ext_vector_type(4))) float;
using bf16x8 = __attribute__((ext_vector_type(8))) __bf16;

constexpr int Bc = 4, Tc = 2048, Dc = 2048, Hc = 16, Gc = 4, Kc = 128;
constexpr float EPSc = 1e-6f;

__device__ __forceinline__ u16 f2bf(float f) {
    u32 u = __float_as_uint(f);
    u = (u + 0x7fffu + ((u >> 16) & 1u)) >> 16;
    return (u16)u;
}
__device__ __forceinline__ float bf2f(u16 h) {
    return __uint_as_float(((u32)h) << 16);
}

// async global->LDS, 16B per lane; LDS dest must be wave-uniform base + lane*16
__device__ __forceinline__ void async_ld16(void* lds, const void* g) {
    __builtin_amdgcn_global_load_lds(
        (const __attribute__((address_space(1))) unsigned int*)g,
        (__attribute__((address_space(3))) unsigned int*)lds, 16, 0, 0);
}

__device__ __forceinline__ void raw_barrier() {
    asm volatile("" ::: "memory");
    __builtin_amdgcn_s_barrier();
    asm volatile("" ::: "memory");
}

__device__ __forceinline__ u32 cvt_pk_bf16(float lo, float hi) {
    u32 r;
    asm("v_cvt_pk_bf16_f32 %0, %1, %2" : "=v"(r) : "v"(lo), "v"(hi));
    return r;
}

// ---------------- fp32 -> bf16 convert ----------------
__global__ __launch_bounds__(256) void cvt_f2bf(const float* __restrict__ in,
                                                u16* __restrict__ out, int n) {
    int i = (blockIdx.x * 256 + threadIdx.x) * 4;
    if (i >= n) return;
    float4 f = *(const float4*)(in + i);
    u16 r[4] = { f2bf(f.x), f2bf(f.y), f2bf(f.z), f2bf(f.w) };
    *(uint2*)(out + i) = *(uint2*)r;
}

// ------- transpose+convert: in (rows x cols) f32 -> out (cols x rows) bf16 -------
__global__ __launch_bounds__(256) void transpose_f2bf(const float* __restrict__ in,
                                                      u16* __restrict__ out,
                                                      int rows, int cols) {
    __shared__ float tile[32][33];
    int tx = threadIdx.x & 31, ty = threadIdx.x >> 5;
    int c0 = blockIdx.x * 32, r0 = blockIdx.y * 32;
#pragma unroll
    for (int j = 0; j < 4; j++)
        tile[ty + j * 8][tx] = in[(size_t)(r0 + ty + j * 8) * cols + c0 + tx];
    __syncthreads();
#pragma unroll
    for (int j = 0; j < 4; j++)
        out[(size_t)(c0 + ty + j * 8) * rows + r0 + tx] = f2bf(tile[tx][ty + j * 8]);
}

// ------- merged wq/wk/wv transpose: outputs contiguous [3072][2048] bf16 -------
__global__ __launch_bounds__(256) void transpose_qkv_w(const float* __restrict__ wq,
                                                       const float* __restrict__ wk,
                                                       const float* __restrict__ wv,
                                                       u16* __restrict__ out) {
    __shared__ float tile[32][33];
    int tx = threadIdx.x & 31, ty = threadIdx.x >> 5;
    int c0 = blockIdx.x * 32, r0 = blockIdx.y * 32;   // c0: combined col 0..3071
    const float* in;
    int stride, cc0;
    if (c0 < 2048)      { in = wq; stride = 2048; cc0 = c0; }
    else if (c0 < 2560) { in = wk; stride = 512;  cc0 = c0 - 2048; }
    else                { in = wv; stride = 512;  cc0 = c0 - 2560; }
#pragma unroll
    for (int j = 0; j < 4; j++)
        tile[ty + j * 8][tx] = in[(size_t)(r0 + ty + j * 8) * stride + cc0 + tx];
    __syncthreads();
#pragma unroll
    for (int j = 0; j < 4; j++)
        out[(size_t)(c0 + ty + j * 8) * 2048 + r0 + tx] = f2bf(tile[tx][ty + j * 8]);
}

// ---------------- positions from (sorted) segment ids ----------------
__global__ void pos_kernel(const int* __restrict__ seg, int* __restrict__ pos) {
    int idx = blockIdx.x * 256 + threadIdx.x;
    if (idx >= Bc * Tc) return;
    int b = idx / Tc, t = idx - b * Tc;
    const int* s = seg + b * Tc;
    int v = s[t];
    int lo = 0, hi = t;
    while (lo < hi) { int mid = (lo + hi) >> 1; if (s[mid] < v) lo = mid + 1; else hi = mid; }
    pos[idx] = t - lo;   // t - seg_start
}

// ======== 256xBN 8-phase GEMM (m201 structure): C(MxN) = A(MxKd)*Bt(NxKd)^T ========
// ONE barrier per phase: {LD; STG; MFMA; bar}. WAR (phase p+1 STG overwriting
// chunks read in p) needs only the end-of-p barrier; post-MFMA barrier was
// redundant (MFMA is reg-only, LD reads vmcnt-protected data). Counted-vmcnt
// accounting unchanged (re-derived: p4 wait covers O.A-hi before p7/p8; p8 wait
// drains all E-chunks before next p1).
template<int NI>
__global__ __launch_bounds__(512, 1) void gemm256(const u16* __restrict__ A,
                                                  const u16* __restrict__ Bt,
                                                  float* __restrict__ Cf,
                                                  u16* __restrict__ qb, u16* __restrict__ kb,
                                                  u16* __restrict__ vtb,
                                                  int N, int Kd, int mode) {
    constexpr int BN = NI * 64;
    __shared__ __align__(16) u16 lds[2][4][8192];   // [buf][A0,A1,B0,B1][16KB region]
    const int tid = threadIdx.x;
    const int wave = tid >> 6, lane = tid & 63;
    const int l16 = lane & 15, quad = lane >> 4;
    const int wr = wave >> 2, wc = wave & 3;

    // XCD-aware block remap: chunk per XCD, col-major inside (requires nwg%8==0, cpx%nx==0)
    const int nx = gridDim.x;
    const int nwg = nx * gridDim.y;
    const int lin = (int)blockIdx.y * nx + (int)blockIdx.x;
    const int cpx = nwg >> 3;
    const int rpc = cpx / nx;
    const int xcd = lin & 7, loc = lin >> 3;
    const int by = xcd * rpc + (loc % rpc);
    const int bx = loc / rpc;
    const int m0 = by * 256, n0 = bx * BN;

    // staging source (inverse-swizzled; same XOR as read side -> involution)
    const int rowc = tid >> 3;                             // row within 64-row chunk
    const int cb = ((tid & 7) * 16) ^ ((rowc & 7) << 4);   // swizzled byte col in 128B row
    const int cu = cb >> 1;
    const int x2 = tid * 8;                                // u16 dest idx within chunk
    const u16* pA[4];
#pragma unroll
    for (int c = 0; c < 4; c++) pA[c] = A + (size_t)(m0 + c * 64 + rowc) * Kd + cu;
    const u16* pB[NI];
#pragma unroll
    for (int c = 0; c < NI; c++) pB[c] = Bt + (size_t)(n0 + c * 64 + rowc) * Kd + cu;

    // A chunk c (rows c*64..): region c>>1, slot c&1. B chunk c: region 2+(c>>1), slot c&1.
    auto STGA = [&](int buf, int c, int kt) {
        async_ld16(&lds[buf][c >> 1][(c & 1) * 4096 + x2], pA[c] + kt * 64);
    };
    auto STGB = [&](int buf, int c, int kt) {
        async_ld16(&lds[buf][2 + (c >> 1)][(c & 1) * 4096 + x2], pB[c] + kt * 64);
    };

    const f32x4 fz = {0.f, 0.f, 0.f, 0.f};
    f32x4 acc[8][NI];
#pragma unroll
    for (int i = 0; i < 8; i++)
#pragma unroll
        for (int j = 0; j < NI; j++) acc[i][j] = fz;

    bf16x8 afr[2][2], bfr[NI][2];
    auto LDB_ALL = [&](int buf) {
#pragma unroll
        for (int ni = 0; ni < NI; ni++)
#pragma unroll
            for (int ks = 0; ks < 2; ks++) {
                int row = wc * (NI * 16) + ni * 16 + l16;
                int y = (row & 127) * 128 + ks * 64 + quad * 16;
                bfr[ni][ks] = *(const bf16x8*)&lds[buf][2 + (row >> 7)][(y ^ ((row & 7) << 4)) >> 1];
            }
    };
    auto LDA2 = [&](int buf, int mp) {
#pragma unroll
        for (int i = 0; i < 2; i++)
#pragma unroll
            for (int ks = 0; ks < 2; ks++) {
                int row = mp * 32 + i * 16 + l16;
                int y = row * 128 + ks * 64 + quad * 16;
                afr[i][ks] = *(const bf16x8*)&lds[buf][wr][(y ^ ((row & 7) << 4)) >> 1];
            }
    };
    auto MFMA2 = [&](int mp) {
        __builtin_amdgcn_s_setprio(1);
#pragma unroll
        for (int i = 0; i < 2; i++)
#pragma unroll
            for (int ni = 0; ni < NI; ni++)
#pragma unroll
                for (int ks = 0; ks < 2; ks++)
                    acc[mp * 2 + i][ni] = __builtin_amdgcn_mfma_f32_16x16x32_bf16(
                        afr[i][ks], bfr[ni][ks], acc[mp * 2 + i][ni], 0, 0, 0);
        __builtin_amdgcn_s_setprio(0);
    };

#define VMC_WAIT() asm volatile("s_waitcnt vmcnt(%0)" :: "i"(NI + 2) : "memory")

    // ---- prologue: E(kt0) fully (NI+4 loads) + O(kt1) B + Aa (NI+2 loads) ----
    STGB(0, 0, 0); STGB(0, 1, 0); STGB(0, 2, 0); if (NI == 4) STGB(0, 3, 0);
    STGA(0, 0, 0); STGA(0, 2, 0); STGA(0, 1, 0); STGA(0, 3, 0);
    STGB(1, 0, 1); STGB(1, 1, 1); STGB(1, 2, 1); if (NI == 4) STGB(1, 3, 1);
    STGA(1, 0, 1); STGA(1, 2, 1);
    VMC_WAIT();
    raw_barrier();

    const int NIT = Kd >> 7;   // 2 k-tiles (of 64) per iteration
    for (int j = 0; j < NIT; j++) {
        const int ktO = 2 * j + 1;
        const int ktE = (2 * j + 2) & (2 * NIT - 1);
        const int ktO2 = (2 * j + 3) & (2 * NIT - 1);
        // p1
        LDB_ALL(0); LDA2(0, 0); STGA(1, 1, ktO); STGA(1, 3, ktO);   // O's Ab
        MFMA2(0); raw_barrier();
        // p2
        LDA2(0, 1); STGB(0, 0, ktE); STGB(0, 1, ktE);
        MFMA2(1); raw_barrier();
        // p3
        LDA2(0, 2); STGB(0, 2, ktE); if (NI == 4) STGB(0, 3, ktE);
        MFMA2(2); raw_barrier();
        // p4
        LDA2(0, 3); STGA(0, 0, ktE); STGA(0, 2, ktE);               // E's Aa
        MFMA2(3);
        VMC_WAIT(); raw_barrier();
        // p5
        LDB_ALL(1); LDA2(1, 0); STGA(0, 1, ktE); STGA(0, 3, ktE);   // E's Ab
        MFMA2(0); raw_barrier();
        // p6
        LDA2(1, 1); STGB(1, 0, ktO2); STGB(1, 1, ktO2);
        MFMA2(1); raw_barrier();
        // p7
        LDA2(1, 2); STGB(1, 2, ktO2); if (NI == 4) STGB(1, 3, ktO2);
        MFMA2(2); raw_barrier();
        // p8
        LDA2(1, 3); STGA(1, 0, ktO2); STGA(1, 2, ktO2);             // O's Aa
        MFMA2(3);
        VMC_WAIT(); raw_barrier();
    }
    asm volatile("s_waitcnt vmcnt(0)" ::: "memory");
#undef VMC_WAIT

    // ---- epilogue ----
    if (mode == 1) {
#pragma unroll
        for (int am = 0; am < 8; am++)
#pragma unroll
            for (int ni = 0; ni < NI; ni++)
#pragma unroll
                for (int r = 0; r < 4; r++) {
                    int row = m0 + wr * 128 + am * 16 + quad * 4 + r;
                    int col = n0 + wc * (NI * 16) + ni * 16 + l16;
                    Cf[(size_t)row * N + col] = acc[am][ni][r];
                }
    } else {
#pragma unroll
        for (int am = 0; am < 8; am++)
#pragma unroll
            for (int ni = 0; ni < NI; ni++) {
                int col = n0 + wc * (NI * 16) + ni * 16 + l16;
                int m = m0 + wr * 128 + am * 16 + quad * 4;
                if (col < 2048) {           // Q
#pragma unroll
                    for (int r = 0; r < 4; r++)
                        qb[(size_t)(m + r) * 2048 + col] = f2bf(acc[am][ni][r]);
                } else if (col < 2560) {    // K
#pragma unroll
                    for (int r = 0; r < 4; r++)
                        kb[(size_t)(m + r) * 512 + col - 2048] = f2bf(acc[am][ni][r]);
                } else {                    // V -> Vt[b][g][d][t]
                    int nv = col - 2560;
                    int g = nv >> 7, d = nv & 127;
                    int b = m >> 11, t = m & 2047;
                    u16 r4[4];
#pragma unroll
                    for (int r = 0; r < 4; r++) r4[r] = f2bf(acc[am][ni][r]);
                    *(uint2*)&vtb[(((size_t)b * Gc + g) * Kc + d) * Tc + t] = *(uint2*)r4;
                }
            }
    }
}

// ------ fused RMSNorm + RoPE, vectorized; ONE launch over q (16 heads) + k (4) ------
// row id hh in [0,20): hh<16 -> qb head hh (scale q_scale, fold K^-0.5); else kb.
__global__ __launch_bounds__(256) void rms_rope2(u16* __restrict__ Q, u16* __restrict__ Kbuf,
                                                 const float* __restrict__ qsc,
                                                 const float* __restrict__ ksc,
                                                 const int* __restrict__ pos, float qmul) {
    int row = blockIdx.x * 4 + (threadIdx.x >> 6);   // one wave per (b,t,head) row
    int lane = threadIdx.x & 63;
    int bt = row / 20, hh = row % 20;
    u16* xp;
    const float* sc;
    float smul;
    if (hh < 16) { xp = Q + ((size_t)bt * 16 + hh) * Kc; sc = qsc; smul = qmul; }
    else         { xp = Kbuf + ((size_t)bt * 4 + (hh - 16)) * Kc; sc = ksc; smul = 1.f; }
    u32 w = *(const u32*)(xp + 2 * lane);
    float a0 = bf2f((u16)(w & 0xffffu)), a1 = bf2f((u16)(w >> 16));
    float ss = a0 * a0 + a1 * a1;
#pragma unroll
    for (int m = 1; m < 64; m <<= 1) ss += __shfl_xor(ss, m, 64);
    float rn = rsqrtf(ss * (1.f / 128.f) + EPSc) * smul;
    float2 scv = *(const float2*)(sc + 2 * lane);
    float y0 = a0 * rn * scv.x, y1 = a1 * rn * scv.y;
    float p0 = __shfl_xor(y0, 32, 64);   // rope partner's scaled value
    float p1 = __shfl_xor(y1, 32, 64);
    int j0 = (2 * lane) & 63;            // freq index (same for lane and partner)
    float pf = (float)pos[bt];
    const float nl2 = -0.20762050593046015f;   // -log2(10000)/64
    float inv0 = exp2f((float)j0 * nl2);
    float inv1 = exp2f((float)(j0 + 1) * nl2);
    float s0, c0, s1, c1;
    sincosf(pf * inv0, &s0, &c0);
    sincosf(pf * inv1, &s1, &c1);
    float sgn = (lane < 32) ? -1.f : 1.f;      // x1*c - x2*s  |  x2*c + x1*s
    float o0 = y0 * c0 + sgn * p0 * s0;
    float o1 = y1 * c1 + sgn * p1 * s1;
    u32 outw = (u32)f2bf(o0) | ((u32)f2bf(o1) << 16);
    *(u32*)(xp + 2 * lane) = outw;
}

// ---------------- flash attention v2: gload_lds double-buffer, 1 barrier/tile ----------------
__global__ __launch_bounds__(256, 2) void flash_attn(const u16* __restrict__ Qb,
                                                     const u16* __restrict__ Kb,
                                                     const u16* __restrict__ Vt,
                                                     const int* __restrict__ pos,
                                                     u16* __restrict__ Ob) {
    __shared__ __align__(16) u16 lK[2][64 * 128];
    __shared__ __align__(16) u16 lVt[2][128 * 64];   // [d][s] swizzled

    // XCD-aware + load-balanced decode: 1024 blocks = 8 xcd x (2 bg x 4 h x 16 q)
    const int lin = (int)blockIdx.x + 16 * ((int)blockIdx.y + 16 * (int)blockIdx.z);
    const int xcd = lin & 7, slot = lin >> 3;        // slot in [0,128)
    const int bg = xcd + 8 * (slot >> 6);            // [0,16)
    const int sub = slot & 63;
    const int b = bg >> 2, g = bg & 3;
    const int h = g * 4 + (sub >> 4);
    const int u = sub & 15;
    const int z = (u & 1) ? 15 - (u >> 1) : (u >> 1);   // zigzag: 0,15,1,14,...
    const int qi = (sub & 32) ? 15 - z : z;             // stride-32 flip
    const int q0 = qi * 128;
    const int tid = threadIdx.x;
    const int wave = tid >> 6, lane = tid & 63;
    const int l16 = lane & 15, quad = lane >> 4;

    bf16x8 qf[2][4];
#pragma unroll
    for (int gq = 0; gq < 2; gq++)
#pragma unroll
        for (int kk = 0; kk < 4; kk++)
            qf[gq][kk] = *(const bf16x8*)&Qb[((size_t)(b * Tc + q0 + gq * 64 + wave * 16 + l16) * Hc + h) * Kc + kk * 32 + quad * 8];

    int tg[2], tstart[2], tsmax[2];
#pragma unroll
    for (int gq = 0; gq < 2; gq++) {
        tg[gq] = q0 + gq * 64 + wave * 16 + l16;
        tstart[gq] = tg[gq] - pos[b * Tc + tg[gq]];
        int v = tstart[gq];   // wave-max over the 16 rows (l16 lanes)
        v = max(v, __shfl_xor(v, 1, 64));
        v = max(v, __shfl_xor(v, 2, 64));
        v = max(v, __shfl_xor(v, 4, 64));
        v = max(v, __shfl_xor(v, 8, 64));
        tsmax[gq] = v;
    }
    const int s_begin = ((q0 - pos[b * Tc + q0]) >> 6) << 6;

    // staging source pointers (inverse-swizzled). Per thread, 4 K + 4 V chunks.
    const u16* pK[4];
    const u16* pV[4];
#pragma unroll
    for (int i = 0; i < 4; i++) {
        int rowK = i * 16 + (tid >> 4);
        int cbK = ((tid & 15) * 16) ^ ((rowK & 7) << 4);
        pK[i] = Kb + ((size_t)(b * Tc + rowK) * Gc + g) * Kc + (cbK >> 1);
        int dV = i * 32 + (tid >> 3);
        int cbV = ((tid & 7) * 16) ^ ((dV & 7) << 4);
        pV[i] = Vt + (((size_t)b * Gc + g) * Kc + dV) * Tc + (cbV >> 1);
    }
    const int x2 = tid * 8;   // u16 dest idx within 4KB chunk region

    auto STAGE = [&](int buf, int s0) {
#pragma unroll
        for (int i = 0; i < 4; i++)
            async_ld16(&lK[buf][i * 2048 + x2], pK[i] + (size_t)s0 * (Gc * Kc));
#pragma unroll
        for (int i = 0; i < 4; i++)
            async_ld16(&lVt[buf][i * 2048 + x2], pV[i] + s0);
    };

    float m_i[2] = {-1e30f, -1e30f}, l_i[2] = {0.f, 0.f};
    const f32x4 fz = {0.f, 0.f, 0.f, 0.f};
    f32x4 oc[2][8];
#pragma unroll
    for (int gq = 0; gq < 2; gq++)
#pragma unroll
        for (int i = 0; i < 8; i++) oc[gq][i] = fz;

    // bpermute source addrs for the P^T quad-redistribution
    const int addrA = (l16 + ((quad & 1) << 5)) << 2;   // m' = 0,1
    const int addrB = addrA + 64;                       // m' = 2,3
    const bool hiq = quad >= 2;

    STAGE(0, s_begin);   // prologue

    const int s_end = q0 + 64;
    int buf = 0;
    for (int s0 = s_begin; s0 <= s_end; s0 += 64, buf ^= 1) {
        asm volatile("s_waitcnt vmcnt(0)" ::: "memory");   // this tile's loads landed
        raw_barrier();                                      // ... in all waves
        if (s0 + 64 <= s_end) STAGE(buf ^ 1, s0 + 64);      // next tile (post-barrier: WAR-safe)

        // S^T = K Q^T for both t-groups, sharing each bk read
        f32x4 sacc[2][4];
#pragma unroll
        for (int gq = 0; gq < 2; gq++)
#pragma unroll
            for (int mi = 0; mi < 4; mi++) sacc[gq][mi] = fz;
        __builtin_amdgcn_s_setprio(1);
#pragma unroll
        for (int kk = 0; kk < 4; kk++) {
#pragma unroll
            for (int mi = 0; mi < 4; mi++) {
                int row = mi * 16 + l16;
                int byt = row * 256 + ((kk * 64 + quad * 16) ^ ((row & 7) << 4));
                bf16x8 bk = *(const bf16x8*)&lK[buf][byt >> 1];
                sacc[0][mi] = __builtin_amdgcn_mfma_f32_16x16x32_bf16(bk, qf[0][kk], sacc[0][mi], 0, 0, 0);
                sacc[1][mi] = __builtin_amdgcn_mfma_f32_16x16x32_bf16(bk, qf[1][kk], sacc[1][mi], 0, 0, 0);
            }
        }
        __builtin_amdgcn_s_setprio(0);

        u32 W[2][4][2];
#pragma unroll
        for (int gq = 0; gq < 2; gq++) {
            const bool fast = (s0 >= tsmax[gq]) && (s0 + 64 <= q0 + gq * 64);
            float rmax = -1e30f;
            if (fast) {
#pragma unroll
                for (int mi = 0; mi < 4; mi++)
#pragma unroll
                    for (int r = 0; r < 4; r++) rmax = fmaxf(rmax, sacc[gq][mi][r]);
            } else {
#pragma unroll
                for (int mi = 0; mi < 4; mi++) {
                    int sl = s0 + mi * 16 + quad * 4;
#pragma unroll
                    for (int r = 0; r < 4; r++) {
                        bool ok = (sl + r <= tg[gq]) && (sl + r >= tstart[gq]);
                        float x = ok ? sacc[gq][mi][r] : -1e30f;
                        sacc[gq][mi][r] = x;
                        rmax = fmaxf(rmax, x);
                    }
                }
            }
            rmax = fmaxf(rmax, __shfl_xor(rmax, 16, 64));
            rmax = fmaxf(rmax, __shfl_xor(rmax, 32, 64));

            // defer-max: only rescale when some row's max grew past m + THR
            if (!__all(rmax <= m_i[gq] + 8.f)) {
                float mnew = fmaxf(m_i[gq], rmax);
                float alpha = __expf(m_i[gq] - mnew);
                m_i[gq] = mnew;
                l_i[gq] *= alpha;
#pragma unroll
                for (int ni = 0; ni < 8; ni++)
#pragma unroll
                    for (int r = 0; r < 4; r++) oc[gq][ni][r] *= alpha;
            }
            float psum = 0.f;
#pragma unroll
            for (int mi = 0; mi < 4; mi++) {
                float p[4];
#pragma unroll
                for (int r = 0; r < 4; r++) {
                    float x = sacc[gq][mi][r];
                    p[r] = (x > -1e29f) ? __expf(x - m_i[gq]) : 0.f;
                    psum += p[r];
                }
                W[gq][mi][0] = cvt_pk_bf16(p[0], p[1]);
                W[gq][mi][1] = cvt_pk_bf16(p[2], p[3]);
            }
            psum += __shfl_xor(psum, 16, 64);
            psum += __shfl_xor(psum, 32, 64);
            l_i[gq] += psum;
        }

        // O^T += V^T P^T for both groups, sharing each av read
#pragma unroll
        for (int kk = 0; kk < 2; kk++) {
            bf16x8 bu[2];
#pragma unroll
            for (int gq = 0; gq < 2; gq++) {
                u32 w0a = (u32)__builtin_amdgcn_ds_bpermute(addrA, (int)W[gq][2 * kk][0]);
                u32 w0b = (u32)__builtin_amdgcn_ds_bpermute(addrA, (int)W[gq][2 * kk + 1][0]);
                u32 w1a = (u32)__builtin_amdgcn_ds_bpermute(addrA, (int)W[gq][2 * kk][1]);
                u32 w1b = (u32)__builtin_amdgcn_ds_bpermute(addrA, (int)W[gq][2 * kk + 1][1]);
                u32 w2a = (u32)__builtin_amdgcn_ds_bpermute(addrB, (int)W[gq][2 * kk][0]);
                u32 w2b = (u32)__builtin_amdgcn_ds_bpermute(addrB, (int)W[gq][2 * kk + 1][0]);
                u32 w3a = (u32)__builtin_amdgcn_ds_bpermute(addrB, (int)W[gq][2 * kk][1]);
                u32 w3b = (u32)__builtin_amdgcn_ds_bpermute(addrB, (int)W[gq][2 * kk + 1][1]);
                union { u32 w[4]; bf16x8 v; } uu;
                uu.w[0] = hiq ? w0b : w0a;
                uu.w[1] = hiq ? w1b : w1a;
                uu.w[2] = hiq ? w2b : w2a;
                uu.w[3] = hiq ? w3b : w3a;
                bu[gq] = uu.v;
            }
            __builtin_amdgcn_s_setprio(1);
#pragma unroll
            for (int ni = 0; ni < 8; ni++) {
                int d = ni * 16 + l16;
                int byt = d * 128 + ((kk * 64 + quad * 16) ^ ((d & 7) << 4));
                bf16x8 av = *(const bf16x8*)&lVt[buf][byt >> 1];
                oc[0][ni] = __builtin_amdgcn_mfma_f32_16x16x32_bf16(av, bu[0], oc[0][ni], 0, 0, 0);
                oc[1][ni] = __builtin_amdgcn_mfma_f32_16x16x32_bf16(av, bu[1], oc[1][ni], 0, 0, 0);
            }
            __builtin_amdgcn_s_setprio(0);
        }
    }

    // ---- epilogue: O^T -> O transpose via LDS (reuse lK for grpA, lVt for grpB) ----
#define KSTR 136
    __syncthreads();
    float invl[2] = {1.f / l_i[0], 1.f / l_i[1]};
    const int tloc = wave * 16 + l16;
#pragma unroll
    for (int gq = 0; gq < 2; gq++) {
        u16* lO = gq ? (u16*)lVt : (u16*)lK;   // each region is 16384 u16 >= 64*KSTR
#pragma unroll
        for (int ni = 0; ni < 8; ni++) {
            u16 r4[4];
#pragma unroll
            for (int r = 0; r < 4; r++) r4[r] = f2bf(oc[gq][ni][r] * invl[gq]);
            *(uint2*)&lO[tloc * KSTR + ni * 16 + quad * 4] = *(uint2*)r4;
        }
    }
    __syncthreads();
#pragma unroll
    for (int gq = 0; gq < 2; gq++) {
        u16* lO = gq ? (u16*)lVt : (u16*)lK;
#pragma unroll
        for (int j = 0; j < 4; j++) {
            int t2 = wave * 16 + j * 4 + quad;
            uint4 vv = *(const uint4*)&lO[t2 * KSTR + l16 * 8];
            *(uint4*)&Ob[((size_t)(b * Tc + q0 + gq * 64 + t2) * Hc + h) * Kc + l16 * 8] = vv;
        }
    }
}

extern "C" void kernel_launch(void* const* d_in, const int* in_sizes, int n_in,
                              void* d_out, int out_size, void* d_ws, size_t ws_size,
                              hipStream_t stream) {
    const float* hidden  = (const float*)d_in[0];
    const float* wq      = (const float*)d_in[1];
    const float* wk      = (const float*)d_in[2];
    const float* wv      = (const float*)d_in[3];
    const float* wo      = (const float*)d_in[4];
    const float* q_scale = (const float*)d_in[5];
    const float* k_scale = (const float*)d_in[6];
    const int*   segids  = (const int*)d_in[7];
    float* out = (float*)d_out;

    char* ws = (char*)d_ws;
    size_t off = 0;
    auto alloc = [&](size_t bytes) -> void* {
        void* p = ws + off;
        off += (bytes + 255) & ~(size_t)255;
        return p;
    };
    u16* hbf  = (u16*)alloc((size_t)Bc * Tc * Dc * 2);        // hidden bf16
    u16* wqT  = (u16*)alloc((size_t)Hc * Kc * Dc * 2);        // (2048 x 2048) \  adjacent:
    u16* wkT  = (u16*)alloc((size_t)Gc * Kc * Dc * 2);        // (512 x 2048)   } one 3072-row B^T
    u16* wvT  = (u16*)alloc((size_t)Gc * Kc * Dc * 2);        // (512 x 2048)  /
    u16* woT  = (u16*)alloc((size_t)Dc * Hc * Kc * 2);        // (2048 x 2048)
    u16* qb   = (u16*)alloc((size_t)Bc * Tc * Hc * Kc * 2);
    u16* kb   = (u16*)alloc((size_t)Bc * Tc * Gc * Kc * 2);
    u16* vtb  = (u16*)alloc((size_t)Bc * Gc * Kc * Tc * 2);   // V^T [b][g][d][t]
    u16* attn = (u16*)alloc((size_t)Bc * Tc * Hc * Kc * 2);
    int* posb = (int*)alloc((size_t)Bc * Tc * 4);
    (void)ws_size; (void)in_sizes; (void)n_in; (void)out_size;
    (void)wkT; (void)wvT;

    const int M = Bc * Tc;   // 8192
    const float qsc = 0.08838834764831845f;   // K^-0.5 folded into q rms_rope

    cvt_f2bf<<<(Bc * Tc * Dc) / 1024, 256, 0, stream>>>(hidden, hbf, Bc * Tc * Dc);
    transpose_qkv_w<<<dim3(96, 64), 256, 0, stream>>>(wq, wk, wv, wqT);
    transpose_f2bf<<<dim3(64, 64), 256, 0, stream>>>(wo, woT, Hc * Kc, Dc);
    pos_kernel<<<(Bc * Tc) / 256, 256, 0, stream>>>(segids, posb);

    // merged Q+K+V projection: N = 3072, BN=192 -> 512 blocks = 2 full rounds
    gemm256<3><<<dim3(3072 / 192, M / 256), 512, 0, stream>>>(hbf, wqT, nullptr, qb, kb, vtb, 3072, Dc, 0);

    // fused rms+rope over q (16 heads) and k (4 heads) in one launch
    rms_rope2<<<(M * 20) / 4, 256, 0, stream>>>(qb, kb, q_scale, k_scale, posb, qsc);

    flash_attn<<<dim3(Tc / 128, Hc, Bc), 256, 0, stream>>>(qb, kb, vtb, posb, attn);

    // output projection: out = attn x woT^T (BN=256, 256 blocks = 1 round)
    gemm256<4><<<dim3(Dc / 256, M / 256), 512, 0, stream>>>(attn, woT, out, nullptr, nullptr, nullptr, Dc, Hc * Kc, 1);
}